// Round 11
// baseline (346.530 us; speedup 1.0000x reference)
//
#include <hip/hip_runtime.h>

#define B_ 4
#define C_ 256
#define N_ 4096

typedef unsigned short u16;
typedef __attribute__((ext_vector_type(8))) short short8_t;
typedef __attribute__((ext_vector_type(4))) float f32x4;

__device__ __forceinline__ u16 bf16r(float f) {
  unsigned u = __float_as_uint(f);
  return (u16)((u + 0x7FFFu + ((u >> 16) & 1u)) >> 16);
}
__device__ __forceinline__ float bf2f(u16 u) {
  return __uint_as_float(((unsigned)u) << 16);
}

__device__ __forceinline__ void g2l16(const u16* g, u16* l) {
  __builtin_amdgcn_global_load_lds((const __attribute__((address_space(1))) void*)g,
                                   (__attribute__((address_space(3))) void*)l, 16, 0, 0);
}

__device__ __forceinline__ int f4(int x) { return (x ^ (x >> 2)) & 3; }

// ---------------- merged: prepack (blocks 0..1087) + LayerNorm (1088..1599) + zerofill (1600) ----------------
__global__ __launch_bounds__(256) void k_pre_ln(const float* __restrict__ x,
                                                const float* __restrict__ ln_w,
                                                const float* __restrict__ ln_b,
                                                const float* __restrict__ qkvv_w,
                                                const float* __restrict__ conv8_w,
                                                const float* __restrict__ op1_w,
                                                const float* __restrict__ op2_w,
                                                const float* __restrict__ ef_w,
                                                const float* __restrict__ conv1_w,
                                                const float* __restrict__ conv2_w,
                                                u16* __restrict__ xnb,
                                                u16* __restrict__ qpack,
                                                u16* __restrict__ w8pack,
                                                u16* __restrict__ oppack,
                                                u16* __restrict__ efpack,
                                                u16* __restrict__ apack1,
                                                u16* __restrict__ apack2,
                                                float* __restrict__ zbuf) {
  __shared__ float tile[32][260];
  __shared__ float s_mu[32], s_rs[32];
  int bid = blockIdx.x, tid = threadIdx.x;
  if (bid < 96) {
    const float* w; u16* dst; int tile_;
    if (bid < 64)      { w = qkvv_w;  dst = qpack;          tile_ = bid; }
    else if (bid < 80) { w = conv8_w; dst = w8pack;         tile_ = bid - 64; }
    else if (bid < 88) { w = op1_w;   dst = oppack;         tile_ = bid - 80; }
    else               { w = op2_w;   dst = oppack + 32768; tile_ = bid - 88; }
    int k0 = tile_ & 7, ot = tile_ >> 3;
    u16* td = dst + (size_t)tile_ * 4096;
    int m = tid >> 1, kb = (tid & 1) * 16, fm = f4(m);
    #pragma unroll
    for (int j = 0; j < 16; ++j) {
      int k = kb + j;
      float v = w[(size_t)(ot * 128 + m) * 256 + k0 * 32 + k];
      td[m * 32 + (((k >> 3) ^ fm) << 3) + (k & 7)] = bf16r(v);
    }
  } else if (bid < 224) {
    int k0 = bid - 96;
    int m = tid & 63, kq = tid >> 6, fm = f4(m);
    u16* td = efpack + (size_t)k0 * 2048;
    #pragma unroll
    for (int kk = 0; kk < 8; ++kk) {
      int k = kq * 8 + kk;
      td[m * 32 + (((k >> 3) ^ fm) << 3) + (k & 7)] = bf16r(ef_w[(size_t)m * 4096 + k0 * 32 + k]);
    }
  } else if (bid < 1088) {
    int t = bid - 224;
    const float* w = (t < 432) ? conv1_w : conv2_w;
    u16* dst = (t < 432) ? apack1 : apack2;
    int tile_ = (t < 432) ? t : t - 432;
    int tap = tile_ % 27; int tmp = tile_ / 27;
    int k0 = tmp & 7; int ot = tmp >> 3;
    u16* td = dst + (size_t)tile_ * 4096;
    int m = tid >> 1, kb = (tid & 1) * 16;
    #pragma unroll
    for (int j = 0; j < 16; ++j) {
      int k = kb + j;
      float v = w[((size_t)(ot * 128 + m) * 256 + k0 * 32 + k) * 27 + tap];
      td[m * 32 + k] = bf16r(v);
    }
  } else if (bid < 1600) {
    int lb = bid - 1088;
    int b = lb >> 7, n0 = (lb & 127) * 32;
    for (int idx = tid; idx < 32 * 256; idx += 256) {
      int nl = idx & 31, c = idx >> 5;
      tile[nl][c] = x[((size_t)(b * C_ + c)) * N_ + n0 + nl];
    }
    __syncthreads();
    int token = tid >> 3, sub = tid & 7;
    float s = 0.f, sq = 0.f;
    for (int j = 0; j < 32; ++j) {
      float v = tile[token][sub + j * 8];
      s += v; sq += v * v;
    }
    for (int o = 1; o < 8; o <<= 1) { s += __shfl_xor(s, o); sq += __shfl_xor(sq, o); }
    if (sub == 0) {
      float mu = s * (1.f / 256.f);
      float var = sq * (1.f / 256.f) - mu * mu;
      s_mu[token] = mu;
      s_rs[token] = rsqrtf(var + 1e-5f);
    }
    __syncthreads();
    int c = tid;
    float lw = ln_w[c], lb2 = ln_b[c];
    for (int k = 0; k < 32; ++k) {
      float v = (tile[k][c] - s_mu[k]) * s_rs[k] * lw + lb2;
      xnb[((size_t)(b * N_ + n0 + k)) * 256 + c] = bf16r(v);
    }
  } else {
    for (int i = tid; i < 3200; i += 256) zbuf[i] = 0.f;
  }
}

// ---------------- qkvv GEMM -> qct bf16 [b][cc][n] (LDS-transposed write) + sumsq ----------------
__global__ __launch_bounds__(256) void k_gemm(const u16* __restrict__ xnb,
                                              const u16* __restrict__ qpack,
                                              u16* __restrict__ qct,
                                              float* __restrict__ sbuf) {
  __shared__ alignas(16) u16 At[4096];
  __shared__ alignas(16) u16 Bt[4096];
  __shared__ alignas(16) u16 Tt[128 * 136];  // transpose staging, 34.8 KB
  int tid = threadIdx.x, l = tid & 63, w = tid >> 6;
  int wm = w >> 1, wn = w & 1;
  int kg = l >> 4;
  int tok0 = blockIdx.x * 128, oct = blockIdx.y;
  int b = tok0 >> 12;
  int aoff[4], boff[4];
  #pragma unroll
  for (int r = 0; r < 4; ++r) {
    int m = wm * 64 + r * 16 + (l & 15);
    aoff[r] = m * 32 + ((kg ^ f4(m)) << 3);
    int o = wn * 64 + r * 16 + (l & 15);
    boff[r] = o * 32 + ((kg ^ f4(o)) << 3);
  }
  f32x4 acc[4][4];
  #pragma unroll
  for (int r = 0; r < 4; ++r)
    #pragma unroll
    for (int jt = 0; jt < 4; ++jt)
      acc[r][jt] = (f32x4){0.f, 0.f, 0.f, 0.f};
  for (int k0 = 0; k0 < 8; ++k0) {
    __syncthreads();
    #pragma unroll
    for (int it = 0; it < 2; ++it) {
      int slot = it * 256 + tid;
      int row = slot >> 2, cp = slot & 3;
      int cig = cp ^ f4(row);
      g2l16(xnb + ((size_t)(tok0 + row) * 256 + k0 * 32 + cig * 8),
            &At[(it * 256 + (tid & 192)) * 8]);
    }
    const u16* qb = qpack + ((size_t)(oct * 8 + k0) << 12);
    #pragma unroll
    for (int it = 0; it < 2; ++it)
      g2l16(qb + (it * 256 + tid) * 8, &Bt[(it * 256 + (tid & 192)) * 8]);
    __syncthreads();
    short8_t av[4], bv[4];
    #pragma unroll
    for (int r = 0; r < 4; ++r) av[r] = *(const short8_t*)&At[aoff[r]];
    #pragma unroll
    for (int jt = 0; jt < 4; ++jt) bv[jt] = *(const short8_t*)&Bt[boff[jt]];
    #pragma unroll
    for (int r = 0; r < 4; ++r)
      #pragma unroll
      for (int jt = 0; jt < 4; ++jt)
        acc[r][jt] = __builtin_amdgcn_mfma_f32_16x16x32_bf16(av[r], bv[jt], acc[r][jt], 0, 0, 0);
  }
  // sumsq for q,k (oct<4)
  if (oct < 4) {
    #pragma unroll
    for (int jt = 0; jt < 4; ++jt) {
      float ss = 0.f;
      #pragma unroll
      for (int r = 0; r < 4; ++r)
        #pragma unroll
        for (int reg = 0; reg < 4; ++reg)
          ss += acc[r][jt][reg] * acc[r][jt][reg];
      ss += __shfl_xor(ss, 16);
      ss += __shfl_xor(ss, 32);
      if ((l >> 4) == 0) {
        int oc = oct * 128 + wn * 64 + jt * 16 + (l & 15);
        atomicAdd(&sbuf[(oc >> 8) * 1024 + b * 256 + (oc & 255)], ss);
      }
    }
  }
  // transpose via LDS: Tt[ocl][tokl]
  #pragma unroll
  for (int r = 0; r < 4; ++r) {
    int tokl = wm * 64 + r * 16 + ((l >> 4) << 2);
    #pragma unroll
    for (int jt = 0; jt < 4; ++jt) {
      int ocl = wn * 64 + jt * 16 + (l & 15);
      ushort4 h4;
      h4.x = bf16r(acc[r][jt][0]);
      h4.y = bf16r(acc[r][jt][1]);
      h4.z = bf16r(acc[r][jt][2]);
      h4.w = bf16r(acc[r][jt][3]);
      *(ushort4*)&Tt[ocl * 136 + tokl] = h4;
    }
  }
  __syncthreads();
  int n0 = tok0 & 4095;
  #pragma unroll
  for (int i = 0; i < 8; ++i) {
    int s = i * 256 + tid;
    int row = s >> 4;
    int col = (s & 15) * 8;
    *(int4*)&qct[((size_t)(b * 1024 + oct * 128 + row)) * 4096 + n0 + col] =
        *(const int4*)&Tt[row * 136 + col];
  }
}

// ---------------- merged: channel-attn partials (blocks 0..255) + kvproj GEMM (256..319) ----------------
__global__ __launch_bounds__(256) void k_ca_kv(const u16* __restrict__ qct,
                                               const u16* __restrict__ efp,
                                               float* __restrict__ kvpart,
                                               float* __restrict__ Spp) {
  __shared__ alignas(16) char smem[66560];
  int bid = blockIdx.x, tid = threadIdx.x;
  if (bid < 256) {
    // ---- attnca partials ----
    u16 (*Qs)[520] = (u16(*)[520])smem;
    u16 (*Ks)[520] = (u16(*)[520])(smem + 33280);
    int bh = bid & 31, ns = bid >> 5;
    int b = bh >> 3, h = bh & 7;
    int n0 = ns * 512;
    for (int idx = tid; idx < 2048; idx += 256) {
      int r = idx >> 6, ch = (idx & 63) * 8;
      *(int4*)&Qs[r][ch] = *(const int4*)&qct[((size_t)(b * 1024 + h * 32 + r)) * 4096 + n0 + ch];
      *(int4*)&Ks[r][ch] = *(const int4*)&qct[((size_t)(b * 1024 + 256 + h * 32 + r)) * 4096 + n0 + ch];
    }
    __syncthreads();
    int r = tid >> 3, sub = tid & 7;
    float a0 = 0.f, a1 = 0.f, a2 = 0.f, a3 = 0.f;
    for (int nb = 0; nb < 512; nb += 8) {
      short8_t q8 = *(const short8_t*)&Qs[r][nb];
      short8_t k0 = *(const short8_t*)&Ks[sub][nb];
      short8_t k1 = *(const short8_t*)&Ks[sub + 8][nb];
      short8_t k2 = *(const short8_t*)&Ks[sub + 16][nb];
      short8_t k3 = *(const short8_t*)&Ks[sub + 24][nb];
      #pragma unroll
      for (int j = 0; j < 8; ++j) {
        float qv = bf2f((u16)q8[j]);
        a0 += qv * bf2f((u16)k0[j]);
        a1 += qv * bf2f((u16)k1[j]);
        a2 += qv * bf2f((u16)k2[j]);
        a3 += qv * bf2f((u16)k3[j]);
      }
    }
    float* sp = Spp + (size_t)ns * 32768 + (size_t)bh * 1024 + r * 32;
    sp[sub] = a0;
    sp[sub + 8] = a1;
    sp[sub + 16] = a2;
    sp[sub + 24] = a3;
  } else {
    // ---- kvproj GEMM ----
    u16* At = (u16*)smem;
    u16* Bt = (u16*)(smem + 32768);
    int t = bid - 256;
    int mt = t & 3, b = (t >> 2) & 3, kz = t >> 4;
    int l = tid & 63, w = tid >> 6;
    int ccb = (mt < 2) ? (256 + mt * 128) : (768 + (mt - 2) * 128);
    int kg = l >> 4;
    int aoff[2], boff[4];
    #pragma unroll
    for (int r = 0; r < 2; ++r) {
      int m = w * 32 + r * 16 + (l & 15);
      aoff[r] = m * 32 + ((kg ^ f4(m)) << 3);
    }
    #pragma unroll
    for (int jt = 0; jt < 4; ++jt) {
      int o = jt * 16 + (l & 15);
      boff[jt] = o * 32 + ((kg ^ f4(o)) << 3);
    }
    f32x4 acc[2][4];
    #pragma unroll
    for (int r = 0; r < 2; ++r)
      #pragma unroll
      for (int jt = 0; jt < 4; ++jt) acc[r][jt] = (f32x4){0.f, 0.f, 0.f, 0.f};
    for (int k0 = kz * 8; k0 < kz * 8 + 8; ++k0) {
      __syncthreads();
      #pragma unroll
      for (int it = 0; it < 8; ++it) {
        int slot = it * 256 + tid;
        int sub = slot >> 9, r = (slot >> 2) & 127, cp = slot & 3;
        g2l16(qct + ((size_t)(b * 1024 + ccb + r)) * 4096 + k0 * 128 + sub * 32 + ((cp ^ f4(r)) << 3),
              &At[(it * 256 + (tid & 192)) * 8]);
      }
      #pragma unroll
      for (int it = 0; it < 4; ++it) {
        int slot = it * 256 + tid;
        g2l16(efp + (size_t)k0 * 8192 + slot * 8, &Bt[(it * 256 + (tid & 192)) * 8]);
      }
      __syncthreads();
      #pragma unroll
      for (int sub = 0; sub < 4; ++sub) {
        short8_t av[2], bv[4];
        #pragma unroll
        for (int r = 0; r < 2; ++r) av[r] = *(const short8_t*)&At[sub * 4096 + aoff[r]];
        #pragma unroll
        for (int jt = 0; jt < 4; ++jt) bv[jt] = *(const short8_t*)&Bt[sub * 2048 + boff[jt]];
        #pragma unroll
        for (int r = 0; r < 2; ++r)
          #pragma unroll
          for (int jt = 0; jt < 4; ++jt)
            acc[r][jt] = __builtin_amdgcn_mfma_f32_16x16x32_bf16(av[r], bv[jt], acc[r][jt], 0, 0, 0);
      }
    }
    int kv = mt >> 1;
    float* outd = kvpart + (size_t)kv * 524288 + (size_t)kz * 131072;
    #pragma unroll
    for (int r = 0; r < 2; ++r) {
      int cbase = (mt & 1) * 128 + w * 32 + r * 16 + ((l >> 4) << 2);
      #pragma unroll
      for (int jt = 0; jt < 4; ++jt) {
        int p = jt * 16 + (l & 15);
        #pragma unroll
        for (int reg = 0; reg < 4; ++reg) {
          int cc = cbase + reg;
          outd[((size_t)(b * 8 + (cc >> 5))) * 2048 + (cc & 31) * 64 + p] = acc[r][jt][reg];
        }
      }
    }
  }
}

// ---------------- merged: x_ca (blocks 0..1023) + spatial attention (1024..1535) ----------------
__global__ __launch_bounds__(256) void k_xca_sa(const u16* __restrict__ qct,
                                                const float* __restrict__ Spp,
                                                const float* __restrict__ kvpart,
                                                const float* __restrict__ ef_b,
                                                const float* __restrict__ sbuf,
                                                const float* __restrict__ temp,
                                                const float* __restrict__ temp2,
                                                u16* __restrict__ xca_b,
                                                u16* __restrict__ xsa_b) {
  __shared__ alignas(16) char smem[66048];
  int bid = blockIdx.x, tid = threadIdx.x;
  if (bid < 1024) {
    // ---- xca (casm fused) ----
    float (*A)[33] = (float(*)[33])smem;
    float (*vt)[129] = (float(*)[129])(smem + 4224);
    int n0 = (bid & 31) * 128;
    int h = (bid >> 5) & 7, b = bid >> 8;
    int bh = b * 8 + h;
    if (tid < 32) {
      float qiv = 1.f / fmaxf(sqrtf(sbuf[b * 256 + h * 32 + tid]), 1e-12f);
      float tmp = temp[h];
      float vals[32];
      #pragma unroll
      for (int e = 0; e < 32; ++e) vals[e] = 0.f;
      for (int ns = 0; ns < 8; ++ns) {
        const float* sp = Spp + (size_t)ns * 32768 + (size_t)bh * 1024 + tid * 32;
        #pragma unroll
        for (int e4 = 0; e4 < 32; e4 += 4) {
          float4 v4 = *(const float4*)&sp[e4];
          vals[e4] += v4.x; vals[e4 + 1] += v4.y;
          vals[e4 + 2] += v4.z; vals[e4 + 3] += v4.w;
        }
      }
      float mx = -1e30f;
      #pragma unroll
      for (int e = 0; e < 32; ++e) {
        float kiv = 1.f / fmaxf(sqrtf(sbuf[1024 + b * 256 + h * 32 + e]), 1e-12f);
        float s = vals[e] * qiv * kiv * tmp;
        vals[e] = s;
        mx = fmaxf(mx, s);
      }
      float ssum = 0.f;
      #pragma unroll
      for (int e = 0; e < 32; ++e) { vals[e] = __expf(vals[e] - mx); ssum += vals[e]; }
      float is = 1.f / ssum;
      #pragma unroll
      for (int e = 0; e < 32; ++e) A[tid][e] = vals[e] * is;
    }
    int e = tid >> 3, ns = (tid & 7) * 16;
    const u16* src = qct + ((size_t)(b * 1024 + 512 + h * 32 + e)) * 4096 + n0 + ns;
    #pragma unroll
    for (int j4 = 0; j4 < 16; j4 += 4) {
      ushort4 u = *(const ushort4*)&src[j4];
      vt[e][ns + j4] = bf2f(u.x);
      vt[e][ns + j4 + 1] = bf2f(u.y);
      vt[e][ns + j4 + 2] = bf2f(u.z);
      vt[e][ns + j4 + 3] = bf2f(u.w);
    }
    __syncthreads();
    int nl = tid & 127, dg = (tid >> 7) * 16;
    float acc[16] = {};
    for (int ee = 0; ee < 32; ++ee) {
      float v = vt[ee][nl];
      #pragma unroll
      for (int j = 0; j < 16; ++j) acc[j] += A[dg + j][ee] * v;
    }
    u16* outp = xca_b + ((size_t)(b * N_ + n0 + nl)) * 256 + h * 32 + dg;
    #pragma unroll
    for (int j = 0; j < 16; ++j) outp[j] = bf16r(acc[j]);
  } else {
    // ---- attnsa (kvred + rsq fused) ----
    float (*kp)[64] = (float(*)[64])smem;
    float (*vp)[64] = (float(*)[64])(smem + 8192);
    float* qi = (float*)(smem + 16384);
    u16 (*qt)[260] = (u16(*)[260])(smem + 16512);
    float (*ot)[257] = (float(*)[257])(smem + 33152);
    int t = bid - 1024;
    int bx = t & 15, h = (t >> 4) & 7, b = t >> 7;
    int bh = b * 8 + h;
    for (int idx = tid; idx < 2048; idx += 256) {
      float bias = ef_b[idx & 63];
      float kpv = bias, vpv = bias;
      size_t base = (size_t)bh * 2048 + idx;
      #pragma unroll
      for (int kz = 0; kz < 4; ++kz) {
        kpv += kvpart[(size_t)kz * 131072 + base];
        vpv += kvpart[524288 + (size_t)kz * 131072 + base];
      }
      kp[idx >> 6][idx & 63] = kpv;
      vp[idx >> 6][idx & 63] = vpv;
    }
    if (tid < 32) qi[tid] = 1.f / fmaxf(sqrtf(sbuf[b * 256 + h * 32 + tid]), 1e-12f);
    {
      int row = tid >> 3, ch = (tid & 7) * 32;
      const u16* src = qct + ((size_t)(b * 1024 + h * 32 + row)) * 4096 + bx * 256 + ch;
      *(int4*)&qt[row][ch] = *(const int4*)&src[0];
      *(int4*)&qt[row][ch + 8] = *(const int4*)&src[8];
      *(int4*)&qt[row][ch + 16] = *(const int4*)&src[16];
      *(int4*)&qt[row][ch + 24] = *(const int4*)&src[24];
    }
    __syncthreads();
    float q[32];
    #pragma unroll
    for (int d = 0; d < 32; ++d) q[d] = bf2f(qt[d][tid]) * qi[d];
    float t2 = temp2[h];
    float l[64];
    #pragma unroll
    for (int p = 0; p < 64; ++p) {
      float s = 0;
      #pragma unroll
      for (int d = 0; d < 32; ++d) s += q[d] * kp[d][p];
      l[p] = s * t2;
    }
    float m = -1e30f;
    #pragma unroll
    for (int p = 0; p < 64; ++p) m = fmaxf(m, l[p]);
    float ssum = 0;
    #pragma unroll
    for (int p = 0; p < 64; ++p) { l[p] = __expf(l[p] - m); ssum += l[p]; }
    float is = 1.f / ssum;
    float o[32] = {};
    #pragma unroll
    for (int p = 0; p < 64; ++p) {
      float wv = l[p] * is;
      #pragma unroll
      for (int d = 0; d < 32; ++d) o[d] += wv * vp[d][p];
    }
    #pragma unroll
    for (int d = 0; d < 32; ++d) ot[d][tid] = o[d];
    __syncthreads();
    #pragma unroll
    for (int i = 0; i < 4; ++i) {
      int s = i * 256 + tid;
      int d = s >> 5;
      int c0 = (s & 31) * 8;
      ushort4 u0, u1;
      u0.x = bf16r(ot[d][c0]);     u0.y = bf16r(ot[d][c0 + 1]);
      u0.z = bf16r(ot[d][c0 + 2]); u0.w = bf16r(ot[d][c0 + 3]);
      u1.x = bf16r(ot[d][c0 + 4]); u1.y = bf16r(ot[d][c0 + 5]);
      u1.z = bf16r(ot[d][c0 + 6]); u1.w = bf16r(ot[d][c0 + 7]);
      u16* dst = xsa_b + (size_t)b * N_ * 256 + (size_t)(d * 128 + h * 16 + bx) * 256 + c0;
      *(ushort4*)&dst[0] = u0;
      *(ushort4*)&dst[4] = u1;
    }
  }
}

// ---------------- op1/op2 MFMA GEMM + gamma residual -> askip CF f32 + xt1 CL bf16 ----------------
__global__ __launch_bounds__(256) void k_opcatm(const u16* __restrict__ xsa_b,
                                                const u16* __restrict__ xca_b,
                                                const float* __restrict__ x,
                                                const float* __restrict__ gamma,
                                                const u16* __restrict__ oppack,
                                                const float* __restrict__ op1_b,
                                                const float* __restrict__ op2_b,
                                                float* __restrict__ attn_skip,
                                                u16* __restrict__ xt1) {
  __shared__ alignas(16) u16 At[4096];
  __shared__ alignas(16) u16 Bt[4096];
  __shared__ alignas(16) float Ttf[128 * 133];
  __shared__ alignas(16) u16 rb[128 * 136];
  int tid = threadIdx.x, l = tid & 63, w = tid >> 6;
  int wm = w >> 1, wn = w & 1;
  int kg = l >> 4;
  int tok0 = blockIdx.x * 128, oct = blockIdx.y;
  int b = tok0 >> 12;
  const u16* src = oct ? xca_b : xsa_b;
  int aoff[4], boff[4];
  #pragma unroll
  for (int r = 0; r < 4; ++r) {
    int m = wm * 64 + r * 16 + (l & 15);
    aoff[r] = m * 32 + ((kg ^ f4(m)) << 3);
    int o = wn * 64 + r * 16 + (l & 15);
    boff[r] = o * 32 + ((kg ^ f4(o)) << 3);
  }
  f32x4 acc[4][4];
  #pragma unroll
  for (int r = 0; r < 4; ++r)
    #pragma unroll
    for (int jt = 0; jt < 4; ++jt)
      acc[r][jt] = (f32x4){0.f, 0.f, 0.f, 0.f};
  for (int k0 = 0; k0 < 8; ++k0) {
    __syncthreads();
    #pragma unroll
    for (int it = 0; it < 2; ++it) {
      int slot = it * 256 + tid;
      int row = slot >> 2, cp = slot & 3;
      int cig = cp ^ f4(row);
      g2l16(src + ((size_t)(tok0 + row) * 256 + k0 * 32 + cig * 8),
            &At[(it * 256 + (tid & 192)) * 8]);
    }
    const u16* qb = oppack + ((size_t)(oct * 8 + k0) << 12);
    #pragma unroll
    for (int it = 0; it < 2; ++it)
      g2l16(qb + (it * 256 + tid) * 8, &Bt[(it * 256 + (tid & 192)) * 8]);
    __syncthreads();
    short8_t av[4], bv[4];
    #pragma unroll
    for (int r = 0; r < 4; ++r) av[r] = *(const short8_t*)&At[aoff[r]];
    #pragma unroll
    for (int jt = 0; jt < 4; ++jt) bv[jt] = *(const short8_t*)&Bt[boff[jt]];
    #pragma unroll
    for (int r = 0; r < 4; ++r)
      #pragma unroll
      for (int jt = 0; jt < 4; ++jt)
        acc[r][jt] = __builtin_amdgcn_mfma_f32_16x16x32_bf16(av[r], bv[jt], acc[r][jt], 0, 0, 0);
  }
  // epilogue 1: acc -> Ttf[ocl][tokl] (f32, stride 133)
  #pragma unroll
  for (int r = 0; r < 4; ++r) {
    int tokl = wm * 64 + r * 16 + ((l >> 4) << 2);
    #pragma unroll
    for (int jt = 0; jt < 4; ++jt) {
      int ocl = wn * 64 + jt * 16 + (l & 15);
      float* tp = &Ttf[ocl * 133 + tokl];
      tp[0] = acc[r][jt][0];
      tp[1] = acc[r][jt][1];
      tp[2] = acc[r][jt][2];
      tp[3] = acc[r][jt][3];
    }
  }
  __syncthreads();
  // epilogue 2a: coalesced x read + residual + coalesced askip write; store v back into Ttf
  {
    int n0l = tok0 & 4095;
    #pragma unroll
    for (int i = 0; i < 16; ++i) {
      int s = i * 256 + tid;
      int cl = s >> 5;
      int t4 = (s & 31) * 4;
      int c = oct * 128 + cl;
      float g = gamma[c];
      float bias = oct ? op2_b[cl] : op1_b[cl];
      size_t base = ((size_t)(b * 256 + c)) * 4096 + n0l + t4;
      float4 x4 = *(const float4*)&x[base];
      float* tp = &Ttf[cl * 133 + t4];
      float4 o4;
      o4.x = x4.x + g * (tp[0] + bias);
      o4.y = x4.y + g * (tp[1] + bias);
      o4.z = x4.z + g * (tp[2] + bias);
      o4.w = x4.w + g * (tp[3] + bias);
      *(float4*)&attn_skip[base] = o4;
      tp[0] = o4.x; tp[1] = o4.y; tp[2] = o4.z; tp[3] = o4.w;
    }
  }
  __syncthreads();
  // epilogue 2b: stage bf16 from Ttf -> rb (lane = channel; stride-133 banks distinct)
  {
    int cl = tid & 127, th = tid >> 7;
    const float* tp = &Ttf[cl * 133 + th * 64];
    #pragma unroll
    for (int t = 0; t < 64; ++t)
      rb[(th * 64 + t) * 136 + cl] = bf16r(tp[t]);
  }
  __syncthreads();
  // epilogue 3: xt1 coalesced int4
  {
    int n0l = tok0 & 4095;
    #pragma unroll
    for (int i = 0; i < 8; ++i) {
      int s = i * 256 + tid;
      int row = s >> 4;
      int c0 = (s & 15) * 8;
      *(int4*)&xt1[((size_t)(b * N_ + n0l + row)) * 256 + oct * 128 + c0] =
          *(const int4*)&rb[row * 136 + c0];
    }
  }
}

// ---------------- split-K MFMA conv 3x3x3 (channels-last output), deep-ring + dbuf ----------------
// Frozen structure: conflicts/ILP/occupancy-x2 all proven null; setprio kept (R6: removal +15%).
__global__ __launch_bounds__(256, 2) void k_conv3m(const u16* __restrict__ xt,
                                                   const u16* __restrict__ apack,
                                                   const u16* __restrict__ zg,
                                                   u16* __restrict__ out,
                                                   float* __restrict__ bnsum,
                                                   float* __restrict__ bnsq) {
  __shared__ alignas(16) u16 Xs[2][2][8192];   // [ks][dbuf][16KB]
  int tid = threadIdx.x, l = tid & 63, w = tid >> 6;
  int wm = w & 1, ks = w >> 1;
  int kg = l >> 4;
  int bid = blockIdx.x;
  int cot = bid & 1;
  int sb = (bid >> 1) & 63;
  int b = bid >> 7;
  int h0 = ((sb >> 4) & 3) << 2, w0 = ((sb >> 2) & 3) << 2, d0 = (sb & 3) << 2;

  int cellc[4];
  {
    int cl = l & 15;
    int wv = (cl >> 2) & 3, dv = cl & 3;
    #pragma unroll
    for (int jt = 0; jt < 4; ++jt)
      cellc[jt] = (jt + 1) * 168 + (wv + 1) * 28 + kg * 6 + (dv + 1);
  }
  const int alane = (wm * 64 + (l & 15)) * 32 + kg * 8;

  const u16* xp[4];
  unsigned okm = 0;
  #pragma unroll
  for (int i = 0; i < 4; ++i) {
    int slot = i * 256 + tid;
    int hh = slot / 168;
    int r = slot - hh * 168;
    int ww = r / 28;
    int r2 = r - ww * 28;
    int kk = r2 / 6;
    int dd = r2 - kk * 6;
    int gh = h0 + hh - 1, gw = w0 + ww - 1, gd = d0 + dd - 1;
    bool ok = (hh < 6) && (kk < 4) &&
              ((unsigned)gh < 16u) && ((unsigned)gw < 16u) && ((unsigned)gd < 16u);
    xp[i] = ok ? (xt + ((size_t)(b * N_ + gh * 256 + gw * 16 + gd)) * 256 + kk * 8) : zg;
    okm |= ((unsigned)ok) << i;
  }

  f32x4 acc[4][4];
  #pragma unroll
  for (int r = 0; r < 4; ++r)
    #pragma unroll
    for (int jt = 0; jt < 4; ++jt)
      acc[r][jt] = (f32x4){0.f, 0.f, 0.f, 0.f};

  #pragma unroll
  for (int bk = 0; bk < 2; ++bk)
    #pragma unroll
    for (int i = 0; i < 4; ++i) {
      const u16* p = ((okm >> i) & 1) ? (xp[i] + ((bk * 4) << 5)) : zg;
      g2l16(p, &Xs[bk][0][(i * 256 + (tid & 192)) * 8]);
    }
  __syncthreads();

  short8_t av[4][4], bv[3][4];

#define CONV_TAP(t)                                                                   \
  do {                                                                                \
    if ((t) < 24) {                                                                   \
      const int tnA = (t) + 3;                                                        \
      _Pragma("unroll")                                                               \
      for (int r = 0; r < 4; ++r)                                                     \
        av[tnA & 3][r] = *(const short8_t*)(at + tnA * 4096 + r * 512);               \
    }                                                                                 \
    if ((t) < 25) {                                                                   \
      const int tnB = (t) + 2;                                                        \
      const int dh = tnB / 9, rr_ = tnB - dh * 9, dw = rr_ / 3, dd2 = rr_ - dw * 3;   \
      const int OFF = (dh - 1) * 168 + (dw - 1) * 28 + (dd2 - 1);                     \
      _Pragma("unroll")                                                               \
      for (int jt = 0; jt < 4; ++jt)                                                  \
        bv[tnB % 3][jt] = *(const short8_t*)&Xb[(cellc[jt] + OFF) * 8];               \
    }                                                                                 \
    __builtin_amdgcn_s_setprio(1);                                                    \
    _Pragma("unroll")                                                                 \
    for (int r = 0; r < 4; ++r)                                                       \
      _Pragma("unroll")                                                               \
      for (int jt = 0; jt < 4; ++jt)                                                  \
        acc[r][jt] = __builtin_amdgcn_mfma_f32_16x16x32_bf16(av[(t) & 3][r],          \
                         bv[(t) % 3][jt], acc[r][jt], 0, 0, 0);                       \
    __builtin_amdgcn_s_setprio(0);                                                    \
  } while (0)

  #pragma unroll 1
  for (int step = 0; step < 4; ++step) {
    const int cur = step & 1;
    const u16* Xb = &Xs[ks][cur][0];
    const int ci0 = ks * 4 + step;
    const u16* at = apack + ((size_t)((cot * 8 + ci0) * 27)) * 4096 + alane;
    #pragma unroll
    for (int r = 0; r < 4; ++r) av[0][r] = *(const short8_t*)(at + r * 512);
    #pragma unroll
    for (int r = 0; r < 4; ++r) av[1][r] = *(const short8_t*)(at + 4096 + r * 512);
    #pragma unroll
    for (int r = 0; r < 4; ++r) av[2][r] = *(const short8_t*)(at + 8192 + r * 512);
    #pragma unroll
    for (int jt = 0; jt < 4; ++jt) {
      bv[0][jt] = *(const short8_t*)&Xb[(cellc[jt] - 197) * 8];
      bv[1][jt] = *(const short8_t*)&Xb[(cellc[jt] - 196) * 8];
    }
    #pragma unroll
    for (int t = 0; t < 4; ++t) CONV_TAP(t);
    if (step < 3) {
      const int nd = (step + 1) & 1;
      #pragma unroll
      for (int bk = 0; bk < 2; ++bk)
        #pragma unroll
        for (int i = 0; i < 4; ++i) {
          const u16* p = ((okm >> i) & 1) ? (xp[i] + ((bk * 4 + step + 1) << 5)) : zg;
          g2l16(p, &Xs[bk][nd][(i * 256 + (tid & 192)) * 8]);
        }
    }
    #pragma unroll
    for (int t = 4; t < 27; ++t) CONV_TAP(t);
    __syncthreads();
  }
#undef CONV_TAP

  f32x4* red = (f32x4*)&Xs[0][0][0];
  if (ks == 1) {
    #pragma unroll
    for (int r = 0; r < 4; ++r)
      #pragma unroll
      for (int jt = 0; jt < 4; ++jt)
        red[(r * 4 + jt) * 128 + wm * 64 + l] = acc[r][jt];
  }
  __syncthreads();
  if (ks == 0) {
    #pragma unroll
    for (int r = 0; r < 4; ++r)
      #pragma unroll
      for (int jt = 0; jt < 4; ++jt) {
        f32x4 o = red[(r * 4 + jt) * 128 + wm * 64 + l];
        acc[r][jt][0] += o[0]; acc[r][jt][1] += o[1];
        acc[r][jt][2] += o[2]; acc[r][jt][3] += o[3];
      }
    #pragma unroll
    for (int r = 0; r < 4; ++r) {
      int co = cot * 128 + wm * 64 + r * 16 + ((l >> 4) << 2);
      #pragma unroll
      for (int reg = 0; reg < 4; ++reg) {
        float sv = 0.f, qv = 0.f;
        #pragma unroll
        for (int jt = 0; jt < 4; ++jt) {
          float v = acc[r][jt][reg];
          sv += v; qv += v * v;
        }
        #pragma unroll
        for (int o = 1; o < 16; o <<= 1) {
          sv += __shfl_xor(sv, o);
          qv += __shfl_xor(qv, o);
        }
        if ((l & 15) == 0) {
          atomicAdd(&bnsum[co + reg], sv);
          atomicAdd(&bnsq[co + reg], qv);
        }
      }
      #pragma unroll
      for (int jt = 0; jt < 4; ++jt) {
        int c = jt * 16 + (l & 15);
        int n = (h0 + (c >> 4)) * 256 + (w0 + ((c >> 2) & 3)) * 16 + (d0 + (c & 3));
        ushort4 h4;
        h4.x = bf16r(acc[r][jt][0]);
        h4.y = bf16r(acc[r][jt][1]);
        h4.z = bf16r(acc[r][jt][2]);
        h4.w = bf16r(acc[r][jt][3]);
        *(ushort4*)&out[((size_t)(b * N_ + n)) * 256 + co] = h4;
      }
    }
  }
}

// ---------------- BN apply + LeakyReLU, CL elementwise (bnfin fused) ----------------
__global__ __launch_bounds__(256) void k_bnelt(const u16* __restrict__ src,
                                               const float* __restrict__ bnsum,
                                               const float* __restrict__ bnsq,
                                               const float* __restrict__ w,
                                               const float* __restrict__ bb,
                                               u16* __restrict__ dst) {
  __shared__ float sc[256], sh[256];
  int tid = threadIdx.x;
  float m = bnsum[tid] * (1.f / 16384.f);
  float var = bnsq[tid] * (1.f / 16384.f) - m * m;
  float rstd = rsqrtf(var + 1e-5f);
  float scv = rstd * w[tid];
  sc[tid] = scv;
  sh[tid] = bb[tid] - m * scv;
  __syncthreads();
  size_t base = (size_t)blockIdx.x * 64 * 256;
  #pragma unroll
  for (int i = 0; i < 8; ++i) {
    int s = i * 256 + tid;
    int c0 = (s & 31) * 8;
    size_t off = base + (size_t)(s >> 5) * 256 + c0;
    int4 v4 = *(const int4*)&src[off];
    u16* pu = (u16*)&v4;
    #pragma unroll
    for (int j = 0; j < 8; ++j) {
      float v = bf2f(pu[j]) * sc[c0 + j] + sh[c0 + j];
      pu[j] = bf16r(v >= 0.f ? v : 0.01f * v);
    }
    *(int4*)&dst[off] = v4;
  }
}

// ---------------- BN2 + skip + lrelu -> cvo bf16 CL (bnfin fused; askip staged cooperatively) ----------------
__global__ __launch_bounds__(256) void k_bn2fuse(const u16* __restrict__ c2o,
                                                 const float* __restrict__ askip,
                                                 const float* __restrict__ bnsum,
                                                 const float* __restrict__ bnsq,
                                                 const float* __restrict__ bnw,
                                                 const float* __restrict__ bnb,
                                                 u16* __restrict__ cvo) {
  __shared__ float sc[256], sh[256];
  __shared__ float at_[32][260];
  int n0 = blockIdx.x * 32, b = blockIdx.y, tid = threadIdx.x;
  float m = bnsum[tid] * (1.f / 16384.f);
  float var = bnsq[tid] * (1.f / 16384.f) - m * m;
  float rstd = rsqrtf(var + 1e-5f);
  float scv = rstd * bnw[tid];
  sc[tid] = scv;
  sh[tid] = bnb[tid] - m * scv;
  // askip staging in 128B segments: 8 lanes per channel row (float4 each)
  #pragma unroll
  for (int i = 0; i < 8; ++i) {
    int s = i * 256 + tid;
    int c = s >> 3;
    int t4 = (s & 7) * 4;
    float4 a4 = *(const float4*)&askip[((size_t)(b * 256 + c)) * 4096 + n0 + t4];
    at_[t4 + 0][c] = a4.x;
    at_[t4 + 1][c] = a4.y;
    at_[t4 + 2][c] = a4.z;
    at_[t4 + 3][c] = a4.w;
  }
  __syncthreads();
  #pragma unroll
  for (int i = 0; i < 4; ++i) {
    int s = i * 256 + tid;
    int row = s >> 5, c0 = (s & 31) * 8;
    size_t off = ((size_t)(b * N_ + n0 + row)) * 256 + c0;
    int4 v4 = *(const int4*)&c2o[off];
    u16* pu = (u16*)&v4;
    #pragma unroll
    for (int j = 0; j < 8; ++j) {
      int c = c0 + j;
      float v = bf2f(pu[j]) * sc[c] + sh[c] + at_[row][c];
      pu[j] = bf16r(v >= 0.f ? v : 0.01f * v);
    }
    *(int4*)&cvo[off] = v4;
  }
}

// ---------------- conv8 MFMA GEMM + bias + skip -> d_out CF, LDS-transposed coalesced epilogue ----------------
__global__ __launch_bounds__(256) void k_conv8m(const u16* __restrict__ cvo,
                                                const u16* __restrict__ w8p,
                                                const float* __restrict__ b8,
                                                const float* __restrict__ skip,
                                                float* __restrict__ out) {
  __shared__ alignas(16) u16 At[4096];
  __shared__ alignas(16) u16 Bt[4096];
  __shared__ alignas(16) float Ts[128 * 132];
  int tid = threadIdx.x, l = tid & 63, w = tid >> 6;
  int wm = w >> 1, wn = w & 1;
  int kg = l >> 4;
  int tok0 = blockIdx.x * 128, oct = blockIdx.y;
  int b = tok0 >> 12;
  int aoff[4], boff[4];
  #pragma unroll
  for (int r = 0; r < 4; ++r) {
    int m = wm * 64 + r * 16 + (l & 15);
    aoff[r] = m * 32 + ((kg ^ f4(m)) << 3);
    int o = wn * 64 + r * 16 + (l & 15);
    boff[r] = o * 32 + ((kg ^ f4(o)) << 3);
  }
  f32x4 acc[4][4];
  #pragma unroll
  for (int r = 0; r < 4; ++r)
    #pragma unroll
    for (int jt = 0; jt < 4; ++jt)
      acc[r][jt] = (f32x4){0.f, 0.f, 0.f, 0.f};
  for (int k0 = 0; k0 < 8; ++k0) {
    __syncthreads();
    #pragma unroll
    for (int it = 0; it < 2; ++it) {
      int slot = it * 256 + tid;
      int row = slot >> 2, cp = slot & 3;
      int cig = cp ^ f4(row);
      g2l16(cvo + ((size_t)(tok0 + row) * 256 + k0 * 32 + cig * 8),
            &At[(it * 256 + (tid & 192)) * 8]);
    }
    const u16* qb = w8p + ((size_t)(oct * 8 + k0) << 12);
    #pragma unroll
    for (int it = 0; it < 2; ++it)
      g2l16(qb + (it * 256 + tid) * 8, &Bt[(it * 256 + (tid & 192)) * 8]);
    __syncthreads();
    short8_t av[4], bv[4];
    #pragma unroll
    for (int r = 0; r < 4; ++r) av[r] = *(const short8_t*)&At[aoff[r]];
    #pragma unroll
    for (int jt = 0; jt < 4; ++jt) bv[jt] = *(const short8_t*)&Bt[boff[jt]];
    #pragma unroll
    for (int r = 0; r < 4; ++r)
      #pragma unroll
      for (int jt = 0; jt < 4; ++jt)
        acc[r][jt] = __builtin_amdgcn_mfma_f32_16x16x32_bf16(av[r], bv[jt], acc[r][jt], 0, 0, 0);
  }
  #pragma unroll
  for (int r = 0; r < 4; ++r) {
    int tokl = wm * 64 + r * 16 + ((l >> 4) << 2);
    #pragma unroll
    for (int jt = 0; jt < 4; ++jt) {
      int ocl = wn * 64 + jt * 16 + (l & 15);
      *(float4*)&Ts[ocl * 132 + tokl] =
          (float4){acc[r][jt][0], acc[r][jt][1], acc[r][jt][2], acc[r][jt][3]};
    }
  }
  __syncthreads();
  int n0l = tok0 & 4095;
  #pragma unroll
  for (int i = 0; i < 16; ++i) {
    int s = i * 256 + tid;
    int row = s >> 5;
    int c4 = (s & 31) * 4;
    int oc = oct * 128 + row;
    size_t base = ((size_t)(b * 256 + oc)) * 4096 + n0l + c4;
    float4 s4 = *(const float4*)&skip[base];
    float bias = b8[oc];
    const float* tp = &Ts[row * 132 + c4];
    float4 o4;
    o4.x = s4.x + bias + tp[0];
    o4.y = s4.y + bias + tp[1];
    o4.z = s4.z + bias + tp[2];
    o4.w = s4.w + bias + tp[3];
    *(float4*)&out[base] = o4;
  }
}

extern "C" void kernel_launch(void* const* d_in, const int* in_sizes, int n_in,
                              void* d_out, int out_size, void* d_ws, size_t ws_size,
                              hipStream_t stream) {
  const float* x       = (const float*)d_in[0];
  const float* gamma   = (const float*)d_in[1];
  const float* ln_w    = (const float*)d_in[2];
  const float* ln_b    = (const float*)d_in[3];
  const float* qkvv_w  = (const float*)d_in[4];
  const float* ef_w    = (const float*)d_in[5];
  const float* ef_b    = (const float*)d_in[6];
  const float* temp    = (const float*)d_in[7];
  const float* temp2   = (const float*)d_in[8];
  const float* op1_w   = (const float*)d_in[9];
  const float* op1_b   = (const float*)d_in[10];
  const float* op2_w   = (const float*)d_in[11];
  const float* op2_b   = (const float*)d_in[12];
  const float* conv1_w = (const float*)d_in[13];
  const float* bn1_w   = (const float*)d_in[14];
  const float* bn1_b   = (const float*)d_in[15];
  const float* conv2_w = (const float*)d_in[16];
  const float* bn2_w   = (const float*)d_in[17];
  const float* bn2_b   = (const float*)d_in[18];
  const float* conv8_w = (const float*)d_in[19];
  const float* conv8_b = (const float*)d_in[20];

  float* ws = (float*)d_ws;
  const size_t M1 = 1u << 20;
  float* askip  = ws;                        // 0..4M f32 CF (4M..8M free)
  u16*   apack1 = (u16*)(ws + 8 * M1);       // 3.54MB (prepack..conv2; no alias)
  u16*   apack2 = (u16*)(ws + 10 * M1);      // 3.54MB
  u16*   xt1    = (u16*)(ws + 16 * M1);      // CL bf16 (2M floats)
  u16*   xnb    = (u16*)(ws + 18 * M1);      // ln..gemm (ends 20M)
  u16*   xsa_b  = (u16*)(ws + 18 * M1);      // attnsa..opcatm (aliases dead xnb)
  float* Spp    = ws + 19 * M1;              // attnca..xca
  float* kvpart = ws + 20 * M1;              // kvproj..attnsa (1M floats)
  u16*   xca_b  = (u16*)(ws + 22 * M1);      // xca..opcatm
  u16*   cvo    = (u16*)(ws + 22 * M1);      // bn2fuse..conv8m (xca_b dead)
  u16*   qct    = (u16*)(ws + 24 * M1);      // gemm..attnsa
  u16*   c1o    = (u16*)(ws + 26 * M1);      // conv phase (qct dead)
  u16*   ht     = (u16*)(ws + 28 * M1);
  u16*   c2o    = (u16*)(ws + 30 * M1);
  float* sm     = ws + 32 * M1;
  float* sbuf   = sm;                        // 2048 (zeroed; gemm atomics)
  float* bnacc  = sm + 2048;                 // 1024 (zeroed; conv BN atomics)
  float* zgu_f  = sm + 3072;                 // 128 (zeroed; conv halo guard)
  u16*   zgu    = (u16*)zgu_f;
  u16*   qpack  = (u16*)(sm + 3200);                   // 512KB
  u16*   efpack = (u16*)(sm + 3200 + 131072);          // 512KB
  u16*   w8pack = (u16*)(sm + 3200 + 262144);          // 128KB
  u16*   oppack = (u16*)(sm + 3200 + 294912);          // 128KB

  k_pre_ln<<<dim3(1601), 256, 0, stream>>>(x, ln_w, ln_b, qkvv_w, conv8_w, op1_w, op2_w,
                                           ef_w, conv1_w, conv2_w,
                                           xnb, qpack, w8pack, oppack, efpack,
                                           apack1, apack2, sm);
  k_gemm<<<dim3(128, 8), 256, 0, stream>>>(xnb, qpack, qct, sbuf);
  k_ca_kv<<<dim3(320), 256, 0, stream>>>(qct, efpack, kvpart, Spp);
  k_xca_sa<<<dim3(1536), 256, 0, stream>>>(qct, Spp, kvpart, ef_b, sbuf, temp, temp2,
                                           xca_b, xsa_b);
  k_opcatm<<<dim3(128, 2), 256, 0, stream>>>(xsa_b, xca_b, x, gamma, oppack, op1_b, op2_b, askip, xt1);
  k_conv3m<<<dim3(512), 256, 0, stream>>>(xt1, apack1, zgu, c1o, bnacc, bnacc + 256);
  k_bnelt<<<dim3(256), 256, 0, stream>>>(c1o, bnacc, bnacc + 256, bn1_w, bn1_b, ht);
  k_conv3m<<<dim3(512), 256, 0, stream>>>(ht, apack2, zgu, c2o, bnacc + 512, bnacc + 768);
  k_bn2fuse<<<dim3(128, 4), 256, 0, stream>>>(c2o, askip, bnacc + 512, bnacc + 768, bn2_w, bn2_b, cvo);
  k_conv8m<<<dim3(128, 2), 256, 0, stream>>>(cvo, w8pack, conv8_b, askip, (float*)d_out);
}

// Round 12
// 323.933 us; speedup vs baseline: 1.0698x; 1.0698x over previous
//
#include <hip/hip_runtime.h>

#define B_ 4
#define C_ 256
#define N_ 4096

typedef unsigned short u16;
typedef __attribute__((ext_vector_type(8))) short short8_t;
typedef __attribute__((ext_vector_type(4))) float f32x4;

__device__ __forceinline__ u16 bf16r(float f) {
  unsigned u = __float_as_uint(f);
  return (u16)((u + 0x7FFFu + ((u >> 16) & 1u)) >> 16);
}
__device__ __forceinline__ float bf2f(u16 u) {
  return __uint_as_float(((unsigned)u) << 16);
}

__device__ __forceinline__ void g2l16(const u16* g, u16* l) {
  __builtin_amdgcn_global_load_lds((const __attribute__((address_space(1))) void*)g,
                                   (__attribute__((address_space(3))) void*)l, 16, 0, 0);
}

__device__ __forceinline__ int f4(int x) { return (x ^ (x >> 2)) & 3; }

// ---------------- merged: prepack (blocks 0..1087) + LayerNorm (1088..1599) + zerofill (1600) ----------------
// Safe merge: prepack branches use no LDS; LN's 33.6 KB leaves 4 blk/CU for every branch.
__global__ __launch_bounds__(256) void k_pre_ln(const float* __restrict__ x,
                                                const float* __restrict__ ln_w,
                                                const float* __restrict__ ln_b,
                                                const float* __restrict__ qkvv_w,
                                                const float* __restrict__ conv8_w,
                                                const float* __restrict__ op1_w,
                                                const float* __restrict__ op2_w,
                                                const float* __restrict__ ef_w,
                                                const float* __restrict__ conv1_w,
                                                const float* __restrict__ conv2_w,
                                                u16* __restrict__ xnb,
                                                u16* __restrict__ qpack,
                                                u16* __restrict__ w8pack,
                                                u16* __restrict__ oppack,
                                                u16* __restrict__ efpack,
                                                u16* __restrict__ apack1,
                                                u16* __restrict__ apack2,
                                                float* __restrict__ zbuf) {
  __shared__ float tile[32][260];
  __shared__ float s_mu[32], s_rs[32];
  int bid = blockIdx.x, tid = threadIdx.x;
  if (bid < 96) {
    const float* w; u16* dst; int tile_;
    if (bid < 64)      { w = qkvv_w;  dst = qpack;          tile_ = bid; }
    else if (bid < 80) { w = conv8_w; dst = w8pack;         tile_ = bid - 64; }
    else if (bid < 88) { w = op1_w;   dst = oppack;         tile_ = bid - 80; }
    else               { w = op2_w;   dst = oppack + 32768; tile_ = bid - 88; }
    int k0 = tile_ & 7, ot = tile_ >> 3;
    u16* td = dst + (size_t)tile_ * 4096;
    int m = tid >> 1, kb = (tid & 1) * 16, fm = f4(m);
    #pragma unroll
    for (int j = 0; j < 16; ++j) {
      int k = kb + j;
      float v = w[(size_t)(ot * 128 + m) * 256 + k0 * 32 + k];
      td[m * 32 + (((k >> 3) ^ fm) << 3) + (k & 7)] = bf16r(v);
    }
  } else if (bid < 224) {
    int k0 = bid - 96;
    int m = tid & 63, kq = tid >> 6, fm = f4(m);
    u16* td = efpack + (size_t)k0 * 2048;
    #pragma unroll
    for (int kk = 0; kk < 8; ++kk) {
      int k = kq * 8 + kk;
      td[m * 32 + (((k >> 3) ^ fm) << 3) + (k & 7)] = bf16r(ef_w[(size_t)m * 4096 + k0 * 32 + k]);
    }
  } else if (bid < 1088) {
    int t = bid - 224;
    const float* w = (t < 432) ? conv1_w : conv2_w;
    u16* dst = (t < 432) ? apack1 : apack2;
    int tile_ = (t < 432) ? t : t - 432;
    int tap = tile_ % 27; int tmp = tile_ / 27;
    int k0 = tmp & 7; int ot = tmp >> 3;
    u16* td = dst + (size_t)tile_ * 4096;
    int m = tid >> 1, kb = (tid & 1) * 16;
    #pragma unroll
    for (int j = 0; j < 16; ++j) {
      int k = kb + j;
      float v = w[((size_t)(ot * 128 + m) * 256 + k0 * 32 + k) * 27 + tap];
      td[m * 32 + k] = bf16r(v);
    }
  } else if (bid < 1600) {
    int lb = bid - 1088;
    int b = lb >> 7, n0 = (lb & 127) * 32;
    for (int idx = tid; idx < 32 * 256; idx += 256) {
      int nl = idx & 31, c = idx >> 5;
      tile[nl][c] = x[((size_t)(b * C_ + c)) * N_ + n0 + nl];
    }
    __syncthreads();
    int token = tid >> 3, sub = tid & 7;
    float s = 0.f, sq = 0.f;
    for (int j = 0; j < 32; ++j) {
      float v = tile[token][sub + j * 8];
      s += v; sq += v * v;
    }
    for (int o = 1; o < 8; o <<= 1) { s += __shfl_xor(s, o); sq += __shfl_xor(sq, o); }
    if (sub == 0) {
      float mu = s * (1.f / 256.f);
      float var = sq * (1.f / 256.f) - mu * mu;
      s_mu[token] = mu;
      s_rs[token] = rsqrtf(var + 1e-5f);
    }
    __syncthreads();
    int c = tid;
    float lw = ln_w[c], lb2 = ln_b[c];
    for (int k = 0; k < 32; ++k) {
      float v = (tile[k][c] - s_mu[k]) * s_rs[k] * lw + lb2;
      xnb[((size_t)(b * N_ + n0 + k)) * 256 + c] = bf16r(v);
    }
  } else {
    for (int i = tid; i < 3200; i += 256) zbuf[i] = 0.f;
  }
}

// ---------------- qkvv GEMM -> qct bf16 [b][cc][n] (LDS-transposed write) + sumsq ----------------
__global__ __launch_bounds__(256) void k_gemm(const u16* __restrict__ xnb,
                                              const u16* __restrict__ qpack,
                                              u16* __restrict__ qct,
                                              float* __restrict__ sbuf) {
  __shared__ alignas(16) u16 At[4096];
  __shared__ alignas(16) u16 Bt[4096];
  __shared__ alignas(16) u16 Tt[128 * 136];  // transpose staging, 34.8 KB
  int tid = threadIdx.x, l = tid & 63, w = tid >> 6;
  int wm = w >> 1, wn = w & 1;
  int kg = l >> 4;
  int tok0 = blockIdx.x * 128, oct = blockIdx.y;
  int b = tok0 >> 12;
  int aoff[4], boff[4];
  #pragma unroll
  for (int r = 0; r < 4; ++r) {
    int m = wm * 64 + r * 16 + (l & 15);
    aoff[r] = m * 32 + ((kg ^ f4(m)) << 3);
    int o = wn * 64 + r * 16 + (l & 15);
    boff[r] = o * 32 + ((kg ^ f4(o)) << 3);
  }
  f32x4 acc[4][4];
  #pragma unroll
  for (int r = 0; r < 4; ++r)
    #pragma unroll
    for (int jt = 0; jt < 4; ++jt)
      acc[r][jt] = (f32x4){0.f, 0.f, 0.f, 0.f};
  for (int k0 = 0; k0 < 8; ++k0) {
    __syncthreads();
    #pragma unroll
    for (int it = 0; it < 2; ++it) {
      int slot = it * 256 + tid;
      int row = slot >> 2, cp = slot & 3;
      int cig = cp ^ f4(row);
      g2l16(xnb + ((size_t)(tok0 + row) * 256 + k0 * 32 + cig * 8),
            &At[(it * 256 + (tid & 192)) * 8]);
    }
    const u16* qb = qpack + ((size_t)(oct * 8 + k0) << 12);
    #pragma unroll
    for (int it = 0; it < 2; ++it)
      g2l16(qb + (it * 256 + tid) * 8, &Bt[(it * 256 + (tid & 192)) * 8]);
    __syncthreads();
    short8_t av[4], bv[4];
    #pragma unroll
    for (int r = 0; r < 4; ++r) av[r] = *(const short8_t*)&At[aoff[r]];
    #pragma unroll
    for (int jt = 0; jt < 4; ++jt) bv[jt] = *(const short8_t*)&Bt[boff[jt]];
    #pragma unroll
    for (int r = 0; r < 4; ++r)
      #pragma unroll
      for (int jt = 0; jt < 4; ++jt)
        acc[r][jt] = __builtin_amdgcn_mfma_f32_16x16x32_bf16(av[r], bv[jt], acc[r][jt], 0, 0, 0);
  }
  // sumsq for q,k (oct<4)
  if (oct < 4) {
    #pragma unroll
    for (int jt = 0; jt < 4; ++jt) {
      float ss = 0.f;
      #pragma unroll
      for (int r = 0; r < 4; ++r)
        #pragma unroll
        for (int reg = 0; reg < 4; ++reg)
          ss += acc[r][jt][reg] * acc[r][jt][reg];
      ss += __shfl_xor(ss, 16);
      ss += __shfl_xor(ss, 32);
      if ((l >> 4) == 0) {
        int oc = oct * 128 + wn * 64 + jt * 16 + (l & 15);
        atomicAdd(&sbuf[(oc >> 8) * 1024 + b * 256 + (oc & 255)], ss);
      }
    }
  }
  // transpose via LDS: Tt[ocl][tokl]
  #pragma unroll
  for (int r = 0; r < 4; ++r) {
    int tokl = wm * 64 + r * 16 + ((l >> 4) << 2);
    #pragma unroll
    for (int jt = 0; jt < 4; ++jt) {
      int ocl = wn * 64 + jt * 16 + (l & 15);
      ushort4 h4;
      h4.x = bf16r(acc[r][jt][0]);
      h4.y = bf16r(acc[r][jt][1]);
      h4.z = bf16r(acc[r][jt][2]);
      h4.w = bf16r(acc[r][jt][3]);
      *(ushort4*)&Tt[ocl * 136 + tokl] = h4;
    }
  }
  __syncthreads();
  int n0 = tok0 & 4095;
  #pragma unroll
  for (int i = 0; i < 8; ++i) {
    int s = i * 256 + tid;
    int row = s >> 4;
    int col = (s & 15) * 8;
    *(int4*)&qct[((size_t)(b * 1024 + oct * 128 + row)) * 4096 + n0 + col] =
        *(const int4*)&Tt[row * 136 + col];
  }
}

// ---------------- kproj/vproj MFMA GEMM, K-split x4, NON-ATOMIC partials ----------------
__global__ __launch_bounds__(256) void k_kvproj_m(const u16* __restrict__ qct,
                                                  const u16* __restrict__ efp,
                                                  float* __restrict__ kvpart) {
  __shared__ alignas(16) u16 At[16384];
  __shared__ alignas(16) u16 Bt[8192];
  int tid = threadIdx.x, l = tid & 63, w = tid >> 6;
  int mt = blockIdx.x, b = blockIdx.y, kz = blockIdx.z;
  int ccb = (mt < 2) ? (256 + mt * 128) : (768 + (mt - 2) * 128);
  int kg = l >> 4;
  int aoff[2], boff[4];
  #pragma unroll
  for (int r = 0; r < 2; ++r) {
    int m = w * 32 + r * 16 + (l & 15);
    aoff[r] = m * 32 + ((kg ^ f4(m)) << 3);
  }
  #pragma unroll
  for (int jt = 0; jt < 4; ++jt) {
    int o = jt * 16 + (l & 15);
    boff[jt] = o * 32 + ((kg ^ f4(o)) << 3);
  }
  f32x4 acc[2][4];
  #pragma unroll
  for (int r = 0; r < 2; ++r)
    #pragma unroll
    for (int jt = 0; jt < 4; ++jt) acc[r][jt] = (f32x4){0.f, 0.f, 0.f, 0.f};
  for (int k0 = kz * 8; k0 < kz * 8 + 8; ++k0) {
    __syncthreads();
    #pragma unroll
    for (int it = 0; it < 8; ++it) {
      int slot = it * 256 + tid;
      int sub = slot >> 9, r = (slot >> 2) & 127, cp = slot & 3;
      g2l16(qct + ((size_t)(b * 1024 + ccb + r)) * 4096 + k0 * 128 + sub * 32 + ((cp ^ f4(r)) << 3),
            &At[(it * 256 + (tid & 192)) * 8]);
    }
    #pragma unroll
    for (int it = 0; it < 4; ++it) {
      int slot = it * 256 + tid;
      g2l16(efp + (size_t)k0 * 8192 + slot * 8, &Bt[(it * 256 + (tid & 192)) * 8]);
    }
    __syncthreads();
    #pragma unroll
    for (int sub = 0; sub < 4; ++sub) {
      short8_t av[2], bv[4];
      #pragma unroll
      for (int r = 0; r < 2; ++r) av[r] = *(const short8_t*)&At[sub * 4096 + aoff[r]];
      #pragma unroll
      for (int jt = 0; jt < 4; ++jt) bv[jt] = *(const short8_t*)&Bt[sub * 2048 + boff[jt]];
      #pragma unroll
      for (int r = 0; r < 2; ++r)
        #pragma unroll
        for (int jt = 0; jt < 4; ++jt)
          acc[r][jt] = __builtin_amdgcn_mfma_f32_16x16x32_bf16(av[r], bv[jt], acc[r][jt], 0, 0, 0);
    }
  }
  int kv = mt >> 1;
  float* outd = kvpart + (size_t)kv * 524288 + (size_t)kz * 131072;
  #pragma unroll
  for (int r = 0; r < 2; ++r) {
    int cbase = (mt & 1) * 128 + w * 32 + r * 16 + ((l >> 4) << 2);
    #pragma unroll
    for (int jt = 0; jt < 4; ++jt) {
      int p = jt * 16 + (l & 15);
      #pragma unroll
      for (int reg = 0; reg < 4; ++reg) {
        int cc = cbase + reg;
        outd[((size_t)(b * 8 + (cc >> 5))) * 2048 + (cc & 31) * 64 + p] = acc[r][jt][reg];
      }
    }
  }
}

// ---------------- channel attention pass 1: partial S slices (non-atomic) ----------------
__global__ __launch_bounds__(256) void k_attnca_p(const u16* __restrict__ qct,
                                                  float* __restrict__ Spp) {
  __shared__ u16 Qs[32][520], Ks[32][520];
  int bh = blockIdx.x, ns = blockIdx.y;
  int b = bh >> 3, h = bh & 7;
  int tid = threadIdx.x;
  int n0 = ns * 512;
  for (int idx = tid; idx < 2048; idx += 256) {
    int r = idx >> 6, ch = (idx & 63) * 8;
    *(int4*)&Qs[r][ch] = *(const int4*)&qct[((size_t)(b * 1024 + h * 32 + r)) * 4096 + n0 + ch];
    *(int4*)&Ks[r][ch] = *(const int4*)&qct[((size_t)(b * 1024 + 256 + h * 32 + r)) * 4096 + n0 + ch];
  }
  __syncthreads();
  int r = tid >> 3, sub = tid & 7;
  float a0 = 0.f, a1 = 0.f, a2 = 0.f, a3 = 0.f;
  for (int nb = 0; nb < 512; nb += 8) {
    short8_t q8 = *(const short8_t*)&Qs[r][nb];
    short8_t k0 = *(const short8_t*)&Ks[sub][nb];
    short8_t k1 = *(const short8_t*)&Ks[sub + 8][nb];
    short8_t k2 = *(const short8_t*)&Ks[sub + 16][nb];
    short8_t k3 = *(const short8_t*)&Ks[sub + 24][nb];
    #pragma unroll
    for (int j = 0; j < 8; ++j) {
      float qv = bf2f((u16)q8[j]);
      a0 += qv * bf2f((u16)k0[j]);
      a1 += qv * bf2f((u16)k1[j]);
      a2 += qv * bf2f((u16)k2[j]);
      a3 += qv * bf2f((u16)k3[j]);
    }
  }
  float* sp = Spp + (size_t)ns * 32768 + (size_t)bh * 1024 + r * 32;
  sp[sub] = a0;
  sp[sub + 8] = a1;
  sp[sub + 16] = a2;
  sp[sub + 24] = a3;
}

// ---------------- x_ca = softmax(S) @ v_ca -> xca_b bf16 CL (casm fused) ----------------
__global__ __launch_bounds__(256) void k_xca(const u16* __restrict__ qct,
                                             const float* __restrict__ Spp,
                                             const float* __restrict__ sbuf,
                                             const float* __restrict__ temp,
                                             u16* __restrict__ xca_b) {
  __shared__ float A[32][33];
  __shared__ float vt[32][129];
  int n0 = blockIdx.x * 128;
  int h = blockIdx.y, b = blockIdx.z;
  int bh = b * 8 + h;
  int tid = threadIdx.x;
  if (tid < 32) {
    float qiv = 1.f / fmaxf(sqrtf(sbuf[b * 256 + h * 32 + tid]), 1e-12f);
    float tmp = temp[h];
    float vals[32];
    #pragma unroll
    for (int e = 0; e < 32; ++e) vals[e] = 0.f;
    for (int ns = 0; ns < 8; ++ns) {
      const float* sp = Spp + (size_t)ns * 32768 + (size_t)bh * 1024 + tid * 32;
      #pragma unroll
      for (int e4 = 0; e4 < 32; e4 += 4) {
        float4 v4 = *(const float4*)&sp[e4];
        vals[e4] += v4.x; vals[e4 + 1] += v4.y;
        vals[e4 + 2] += v4.z; vals[e4 + 3] += v4.w;
      }
    }
    float mx = -1e30f;
    #pragma unroll
    for (int e = 0; e < 32; ++e) {
      float kiv = 1.f / fmaxf(sqrtf(sbuf[1024 + b * 256 + h * 32 + e]), 1e-12f);
      float s = vals[e] * qiv * kiv * tmp;
      vals[e] = s;
      mx = fmaxf(mx, s);
    }
    float ssum = 0.f;
    #pragma unroll
    for (int e = 0; e < 32; ++e) { vals[e] = __expf(vals[e] - mx); ssum += vals[e]; }
    float is = 1.f / ssum;
    #pragma unroll
    for (int e = 0; e < 32; ++e) A[tid][e] = vals[e] * is;
  }
  int e = tid >> 3, ns = (tid & 7) * 16;
  const u16* src = qct + ((size_t)(b * 1024 + 512 + h * 32 + e)) * 4096 + n0 + ns;
  #pragma unroll
  for (int j4 = 0; j4 < 16; j4 += 4) {
    ushort4 u = *(const ushort4*)&src[j4];
    vt[e][ns + j4] = bf2f(u.x);
    vt[e][ns + j4 + 1] = bf2f(u.y);
    vt[e][ns + j4 + 2] = bf2f(u.z);
    vt[e][ns + j4 + 3] = bf2f(u.w);
  }
  __syncthreads();
  int nl = tid & 127, dg = (tid >> 7) * 16;
  float acc[16] = {};
  for (int ee = 0; ee < 32; ++ee) {
    float v = vt[ee][nl];
    #pragma unroll
    for (int j = 0; j < 16; ++j) acc[j] += A[dg + j][ee] * v;
  }
  u16* outp = xca_b + ((size_t)(b * N_ + n0 + nl)) * 256 + h * 32 + dg;
  #pragma unroll
  for (int j = 0; j < 16; ++j) outp[j] = bf16r(acc[j]);
}

// ---------------- spatial attention -> xsa bf16 (kvred + rsq fused into staging) ----------------
__global__ __launch_bounds__(256) void k_attnsa(const u16* __restrict__ qct,
                                                const float* __restrict__ kvpart,
                                                const float* __restrict__ ef_b,
                                                const float* __restrict__ sbuf,
                                                const float* __restrict__ temp2,
                                                u16* __restrict__ xsa_b) {
  __shared__ float kp[32][64], vp[32][64], qi[32];
  __shared__ u16 qt[32][260];
  __shared__ float ot[32][257];
  int bx = blockIdx.x;
  int h = blockIdx.y, b = blockIdx.z;
  int bh = b * 8 + h;
  int tid = threadIdx.x;
  for (int idx = tid; idx < 2048; idx += 256) {
    float bias = ef_b[idx & 63];
    float kpv = bias, vpv = bias;
    size_t base = (size_t)bh * 2048 + idx;
    #pragma unroll
    for (int kz = 0; kz < 4; ++kz) {
      kpv += kvpart[(size_t)kz * 131072 + base];
      vpv += kvpart[524288 + (size_t)kz * 131072 + base];
    }
    kp[idx >> 6][idx & 63] = kpv;
    vp[idx >> 6][idx & 63] = vpv;
  }
  if (tid < 32) qi[tid] = 1.f / fmaxf(sqrtf(sbuf[b * 256 + h * 32 + tid]), 1e-12f);
  {
    int row = tid >> 3, ch = (tid & 7) * 32;
    const u16* src = qct + ((size_t)(b * 1024 + h * 32 + row)) * 4096 + bx * 256 + ch;
    *(int4*)&qt[row][ch] = *(const int4*)&src[0];
    *(int4*)&qt[row][ch + 8] = *(const int4*)&src[8];
    *(int4*)&qt[row][ch + 16] = *(const int4*)&src[16];
    *(int4*)&qt[row][ch + 24] = *(const int4*)&src[24];
  }
  __syncthreads();
  float q[32];
  #pragma unroll
  for (int d = 0; d < 32; ++d) q[d] = bf2f(qt[d][tid]) * qi[d];
  float t2 = temp2[h];
  float l[64];
  #pragma unroll
  for (int p = 0; p < 64; ++p) {
    float s = 0;
    #pragma unroll
    for (int d = 0; d < 32; ++d) s += q[d] * kp[d][p];
    l[p] = s * t2;
  }
  float m = -1e30f;
  #pragma unroll
  for (int p = 0; p < 64; ++p) m = fmaxf(m, l[p]);
  float ssum = 0;
  #pragma unroll
  for (int p = 0; p < 64; ++p) { l[p] = __expf(l[p] - m); ssum += l[p]; }
  float is = 1.f / ssum;
  float o[32] = {};
  #pragma unroll
  for (int p = 0; p < 64; ++p) {
    float wv = l[p] * is;
    #pragma unroll
    for (int d = 0; d < 32; ++d) o[d] += wv * vp[d][p];
  }
  #pragma unroll
  for (int d = 0; d < 32; ++d) ot[d][tid] = o[d];
  __syncthreads();
  #pragma unroll
  for (int i = 0; i < 4; ++i) {
    int s = i * 256 + tid;
    int d = s >> 5;
    int c0 = (s & 31) * 8;
    ushort4 u0, u1;
    u0.x = bf16r(ot[d][c0]);     u0.y = bf16r(ot[d][c0 + 1]);
    u0.z = bf16r(ot[d][c0 + 2]); u0.w = bf16r(ot[d][c0 + 3]);
    u1.x = bf16r(ot[d][c0 + 4]); u1.y = bf16r(ot[d][c0 + 5]);
    u1.z = bf16r(ot[d][c0 + 6]); u1.w = bf16r(ot[d][c0 + 7]);
    u16* dst = xsa_b + (size_t)b * N_ * 256 + (size_t)(d * 128 + h * 16 + bx) * 256 + c0;
    *(ushort4*)&dst[0] = u0;
    *(ushort4*)&dst[4] = u1;
  }
}

// ---------------- op1/op2 MFMA GEMM + gamma residual -> askip CF f32 + xt1 CL bf16 ----------------
__global__ __launch_bounds__(256) void k_opcatm(const u16* __restrict__ xsa_b,
                                                const u16* __restrict__ xca_b,
                                                const float* __restrict__ x,
                                                const float* __restrict__ gamma,
                                                const u16* __restrict__ oppack,
                                                const float* __restrict__ op1_b,
                                                const float* __restrict__ op2_b,
                                                float* __restrict__ attn_skip,
                                                u16* __restrict__ xt1) {
  __shared__ alignas(16) u16 At[4096];
  __shared__ alignas(16) u16 Bt[4096];
  __shared__ alignas(16) float Ttf[128 * 133];
  __shared__ alignas(16) u16 rb[128 * 136];
  int tid = threadIdx.x, l = tid & 63, w = tid >> 6;
  int wm = w >> 1, wn = w & 1;
  int kg = l >> 4;
  int tok0 = blockIdx.x * 128, oct = blockIdx.y;
  int b = tok0 >> 12;
  const u16* src = oct ? xca_b : xsa_b;
  int aoff[4], boff[4];
  #pragma unroll
  for (int r = 0; r < 4; ++r) {
    int m = wm * 64 + r * 16 + (l & 15);
    aoff[r] = m * 32 + ((kg ^ f4(m)) << 3);
    int o = wn * 64 + r * 16 + (l & 15);
    boff[r] = o * 32 + ((kg ^ f4(o)) << 3);
  }
  f32x4 acc[4][4];
  #pragma unroll
  for (int r = 0; r < 4; ++r)
    #pragma unroll
    for (int jt = 0; jt < 4; ++jt)
      acc[r][jt] = (f32x4){0.f, 0.f, 0.f, 0.f};
  for (int k0 = 0; k0 < 8; ++k0) {
    __syncthreads();
    #pragma unroll
    for (int it = 0; it < 2; ++it) {
      int slot = it * 256 + tid;
      int row = slot >> 2, cp = slot & 3;
      int cig = cp ^ f4(row);
      g2l16(src + ((size_t)(tok0 + row) * 256 + k0 * 32 + cig * 8),
            &At[(it * 256 + (tid & 192)) * 8]);
    }
    const u16* qb = oppack + ((size_t)(oct * 8 + k0) << 12);
    #pragma unroll
    for (int it = 0; it < 2; ++it)
      g2l16(qb + (it * 256 + tid) * 8, &Bt[(it * 256 + (tid & 192)) * 8]);
    __syncthreads();
    short8_t av[4], bv[4];
    #pragma unroll
    for (int r = 0; r < 4; ++r) av[r] = *(const short8_t*)&At[aoff[r]];
    #pragma unroll
    for (int jt = 0; jt < 4; ++jt) bv[jt] = *(const short8_t*)&Bt[boff[jt]];
    #pragma unroll
    for (int r = 0; r < 4; ++r)
      #pragma unroll
      for (int jt = 0; jt < 4; ++jt)
        acc[r][jt] = __builtin_amdgcn_mfma_f32_16x16x32_bf16(av[r], bv[jt], acc[r][jt], 0, 0, 0);
  }
  // epilogue 1: acc -> Ttf[ocl][tokl] (f32, stride 133)
  #pragma unroll
  for (int r = 0; r < 4; ++r) {
    int tokl = wm * 64 + r * 16 + ((l >> 4) << 2);
    #pragma unroll
    for (int jt = 0; jt < 4; ++jt) {
      int ocl = wn * 64 + jt * 16 + (l & 15);
      float* tp = &Ttf[ocl * 133 + tokl];
      tp[0] = acc[r][jt][0];
      tp[1] = acc[r][jt][1];
      tp[2] = acc[r][jt][2];
      tp[3] = acc[r][jt][3];
    }
  }
  __syncthreads();
  // epilogue 2a: coalesced x read + residual + coalesced askip write; store v back into Ttf
  {
    int n0l = tok0 & 4095;
    #pragma unroll
    for (int i = 0; i < 16; ++i) {
      int s = i * 256 + tid;
      int cl = s >> 5;
      int t4 = (s & 31) * 4;
      int c = oct * 128 + cl;
      float g = gamma[c];
      float bias = oct ? op2_b[cl] : op1_b[cl];
      size_t base = ((size_t)(b * 256 + c)) * 4096 + n0l + t4;
      float4 x4 = *(const float4*)&x[base];
      float* tp = &Ttf[cl * 133 + t4];
      float4 o4;
      o4.x = x4.x + g * (tp[0] + bias);
      o4.y = x4.y + g * (tp[1] + bias);
      o4.z = x4.z + g * (tp[2] + bias);
      o4.w = x4.w + g * (tp[3] + bias);
      *(float4*)&attn_skip[base] = o4;
      tp[0] = o4.x; tp[1] = o4.y; tp[2] = o4.z; tp[3] = o4.w;
    }
  }
  __syncthreads();
  // epilogue 2b: stage bf16 from Ttf -> rb (lane = channel; stride-133 banks distinct)
  {
    int cl = tid & 127, th = tid >> 7;
    const float* tp = &Ttf[cl * 133 + th * 64];
    #pragma unroll
    for (int t = 0; t < 64; ++t)
      rb[(th * 64 + t) * 136 + cl] = bf16r(tp[t]);
  }
  __syncthreads();
  // epilogue 3: xt1 coalesced int4
  {
    int n0l = tok0 & 4095;
    #pragma unroll
    for (int i = 0; i < 8; ++i) {
      int s = i * 256 + tid;
      int row = s >> 4;
      int c0 = (s & 15) * 8;
      *(int4*)&xt1[((size_t)(b * N_ + n0l + row)) * 256 + oct * 128 + c0] =
          *(const int4*)&rb[row * 136 + c0];
    }
  }
}

// ---------------- split-K MFMA conv 3x3x3 (channels-last output), deep-ring + dbuf ----------------
// Frozen structure: conflicts/ILP/occupancy-x2 all proven null; setprio kept (R6: removal +15%).
__global__ __launch_bounds__(256, 2) void k_conv3m(const u16* __restrict__ xt,
                                                   const u16* __restrict__ apack,
                                                   const u16* __restrict__ zg,
                                                   u16* __restrict__ out,
                                                   float* __restrict__ bnsum,
                                                   float* __restrict__ bnsq) {
  __shared__ alignas(16) u16 Xs[2][2][8192];   // [ks][dbuf][16KB]
  int tid = threadIdx.x, l = tid & 63, w = tid >> 6;
  int wm = w & 1, ks = w >> 1;
  int kg = l >> 4;
  int bid = blockIdx.x;
  int cot = bid & 1;
  int sb = (bid >> 1) & 63;
  int b = bid >> 7;
  int h0 = ((sb >> 4) & 3) << 2, w0 = ((sb >> 2) & 3) << 2, d0 = (sb & 3) << 2;

  int cellc[4];
  {
    int cl = l & 15;
    int wv = (cl >> 2) & 3, dv = cl & 3;
    #pragma unroll
    for (int jt = 0; jt < 4; ++jt)
      cellc[jt] = (jt + 1) * 168 + (wv + 1) * 28 + kg * 6 + (dv + 1);
  }
  const int alane = (wm * 64 + (l & 15)) * 32 + kg * 8;

  const u16* xp[4];
  unsigned okm = 0;
  #pragma unroll
  for (int i = 0; i < 4; ++i) {
    int slot = i * 256 + tid;
    int hh = slot / 168;
    int r = slot - hh * 168;
    int ww = r / 28;
    int r2 = r - ww * 28;
    int kk = r2 / 6;
    int dd = r2 - kk * 6;
    int gh = h0 + hh - 1, gw = w0 + ww - 1, gd = d0 + dd - 1;
    bool ok = (hh < 6) && (kk < 4) &&
              ((unsigned)gh < 16u) && ((unsigned)gw < 16u) && ((unsigned)gd < 16u);
    xp[i] = ok ? (xt + ((size_t)(b * N_ + gh * 256 + gw * 16 + gd)) * 256 + kk * 8) : zg;
    okm |= ((unsigned)ok) << i;
  }

  f32x4 acc[4][4];
  #pragma unroll
  for (int r = 0; r < 4; ++r)
    #pragma unroll
    for (int jt = 0; jt < 4; ++jt)
      acc[r][jt] = (f32x4){0.f, 0.f, 0.f, 0.f};

  #pragma unroll
  for (int bk = 0; bk < 2; ++bk)
    #pragma unroll
    for (int i = 0; i < 4; ++i) {
      const u16* p = ((okm >> i) & 1) ? (xp[i] + ((bk * 4) << 5)) : zg;
      g2l16(p, &Xs[bk][0][(i * 256 + (tid & 192)) * 8]);
    }
  __syncthreads();

  short8_t av[4][4], bv[3][4];

#define CONV_TAP(t)                                                                   \
  do {                                                                                \
    if ((t) < 24) {                                                                   \
      const int tnA = (t) + 3;                                                        \
      _Pragma("unroll")                                                               \
      for (int r = 0; r < 4; ++r)                                                     \
        av[tnA & 3][r] = *(const short8_t*)(at + tnA * 4096 + r * 512);               \
    }                                                                                 \
    if ((t) < 25) {                                                                   \
      const int tnB = (t) + 2;                                                        \
      const int dh = tnB / 9, rr_ = tnB - dh * 9, dw = rr_ / 3, dd2 = rr_ - dw * 3;   \
      const int OFF = (dh - 1) * 168 + (dw - 1) * 28 + (dd2 - 1);                     \
      _Pragma("unroll")                                                               \
      for (int jt = 0; jt < 4; ++jt)                                                  \
        bv[tnB % 3][jt] = *(const short8_t*)&Xb[(cellc[jt] + OFF) * 8];               \
    }                                                                                 \
    __builtin_amdgcn_s_setprio(1);                                                    \
    _Pragma("unroll")                                                                 \
    for (int r = 0; r < 4; ++r)                                                       \
      _Pragma("unroll")                                                               \
      for (int jt = 0; jt < 4; ++jt)                                                  \
        acc[r][jt] = __builtin_amdgcn_mfma_f32_16x16x32_bf16(av[(t) & 3][r],          \
                         bv[(t) % 3][jt], acc[r][jt], 0, 0, 0);                       \
    __builtin_amdgcn_s_setprio(0);                                                    \
  } while (0)

  #pragma unroll 1
  for (int step = 0; step < 4; ++step) {
    const int cur = step & 1;
    const u16* Xb = &Xs[ks][cur][0];
    const int ci0 = ks * 4 + step;
    const u16* at = apack + ((size_t)((cot * 8 + ci0) * 27)) * 4096 + alane;
    #pragma unroll
    for (int r = 0; r < 4; ++r) av[0][r] = *(const short8_t*)(at + r * 512);
    #pragma unroll
    for (int r = 0; r < 4; ++r) av[1][r] = *(const short8_t*)(at + 4096 + r * 512);
    #pragma unroll
    for (int r = 0; r < 4; ++r) av[2][r] = *(const short8_t*)(at + 8192 + r * 512);
    #pragma unroll
    for (int jt = 0; jt < 4; ++jt) {
      bv[0][jt] = *(const short8_t*)&Xb[(cellc[jt] - 197) * 8];
      bv[1][jt] = *(const short8_t*)&Xb[(cellc[jt] - 196) * 8];
    }
    #pragma unroll
    for (int t = 0; t < 4; ++t) CONV_TAP(t);
    if (step < 3) {
      const int nd = (step + 1) & 1;
      #pragma unroll
      for (int bk = 0; bk < 2; ++bk)
        #pragma unroll
        for (int i = 0; i < 4; ++i) {
          const u16* p = ((okm >> i) & 1) ? (xp[i] + ((bk * 4 + step + 1) << 5)) : zg;
          g2l16(p, &Xs[bk][nd][(i * 256 + (tid & 192)) * 8]);
        }
    }
    #pragma unroll
    for (int t = 4; t < 27; ++t) CONV_TAP(t);
    __syncthreads();
  }
#undef CONV_TAP

  f32x4* red = (f32x4*)&Xs[0][0][0];
  if (ks == 1) {
    #pragma unroll
    for (int r = 0; r < 4; ++r)
      #pragma unroll
      for (int jt = 0; jt < 4; ++jt)
        red[(r * 4 + jt) * 128 + wm * 64 + l] = acc[r][jt];
  }
  __syncthreads();
  if (ks == 0) {
    #pragma unroll
    for (int r = 0; r < 4; ++r)
      #pragma unroll
      for (int jt = 0; jt < 4; ++jt) {
        f32x4 o = red[(r * 4 + jt) * 128 + wm * 64 + l];
        acc[r][jt][0] += o[0]; acc[r][jt][1] += o[1];
        acc[r][jt][2] += o[2]; acc[r][jt][3] += o[3];
      }
    #pragma unroll
    for (int r = 0; r < 4; ++r) {
      int co = cot * 128 + wm * 64 + r * 16 + ((l >> 4) << 2);
      #pragma unroll
      for (int reg = 0; reg < 4; ++reg) {
        float sv = 0.f, qv = 0.f;
        #pragma unroll
        for (int jt = 0; jt < 4; ++jt) {
          float v = acc[r][jt][reg];
          sv += v; qv += v * v;
        }
        #pragma unroll
        for (int o = 1; o < 16; o <<= 1) {
          sv += __shfl_xor(sv, o);
          qv += __shfl_xor(qv, o);
        }
        if ((l & 15) == 0) {
          atomicAdd(&bnsum[co + reg], sv);
          atomicAdd(&bnsq[co + reg], qv);
        }
      }
      #pragma unroll
      for (int jt = 0; jt < 4; ++jt) {
        int c = jt * 16 + (l & 15);
        int n = (h0 + (c >> 4)) * 256 + (w0 + ((c >> 2) & 3)) * 16 + (d0 + (c & 3));
        ushort4 h4;
        h4.x = bf16r(acc[r][jt][0]);
        h4.y = bf16r(acc[r][jt][1]);
        h4.z = bf16r(acc[r][jt][2]);
        h4.w = bf16r(acc[r][jt][3]);
        *(ushort4*)&out[((size_t)(b * N_ + n)) * 256 + co] = h4;
      }
    }
  }
}

// ---------------- BN apply + LeakyReLU, CL elementwise (bnfin fused) ----------------
__global__ __launch_bounds__(256) void k_bnelt(const u16* __restrict__ src,
                                               const float* __restrict__ bnsum,
                                               const float* __restrict__ bnsq,
                                               const float* __restrict__ w,
                                               const float* __restrict__ bb,
                                               u16* __restrict__ dst) {
  __shared__ float sc[256], sh[256];
  int tid = threadIdx.x;
  float m = bnsum[tid] * (1.f / 16384.f);
  float var = bnsq[tid] * (1.f / 16384.f) - m * m;
  float rstd = rsqrtf(var + 1e-5f);
  float scv = rstd * w[tid];
  sc[tid] = scv;
  sh[tid] = bb[tid] - m * scv;
  __syncthreads();
  size_t base = (size_t)blockIdx.x * 64 * 256;
  #pragma unroll
  for (int i = 0; i < 8; ++i) {
    int s = i * 256 + tid;
    int c0 = (s & 31) * 8;
    size_t off = base + (size_t)(s >> 5) * 256 + c0;
    int4 v4 = *(const int4*)&src[off];
    u16* pu = (u16*)&v4;
    #pragma unroll
    for (int j = 0; j < 8; ++j) {
      float v = bf2f(pu[j]) * sc[c0 + j] + sh[c0 + j];
      pu[j] = bf16r(v >= 0.f ? v : 0.01f * v);
    }
    *(int4*)&dst[off] = v4;
  }
}

// ---------------- BN2 + skip + lrelu -> cvo bf16 CL (bnfin fused; askip staged cooperatively) ----------------
__global__ __launch_bounds__(256) void k_bn2fuse(const u16* __restrict__ c2o,
                                                 const float* __restrict__ askip,
                                                 const float* __restrict__ bnsum,
                                                 const float* __restrict__ bnsq,
                                                 const float* __restrict__ bnw,
                                                 const float* __restrict__ bnb,
                                                 u16* __restrict__ cvo) {
  __shared__ float sc[256], sh[256];
  __shared__ float at_[32][260];
  int n0 = blockIdx.x * 32, b = blockIdx.y, tid = threadIdx.x;
  float m = bnsum[tid] * (1.f / 16384.f);
  float var = bnsq[tid] * (1.f / 16384.f) - m * m;
  float rstd = rsqrtf(var + 1e-5f);
  float scv = rstd * bnw[tid];
  sc[tid] = scv;
  sh[tid] = bnb[tid] - m * scv;
  // askip staging in 128B segments: 8 lanes per channel row (float4 each)
  #pragma unroll
  for (int i = 0; i < 8; ++i) {
    int s = i * 256 + tid;
    int c = s >> 3;
    int t4 = (s & 7) * 4;
    float4 a4 = *(const float4*)&askip[((size_t)(b * 256 + c)) * 4096 + n0 + t4];
    at_[t4 + 0][c] = a4.x;
    at_[t4 + 1][c] = a4.y;
    at_[t4 + 2][c] = a4.z;
    at_[t4 + 3][c] = a4.w;
  }
  __syncthreads();
  #pragma unroll
  for (int i = 0; i < 4; ++i) {
    int s = i * 256 + tid;
    int row = s >> 5, c0 = (s & 31) * 8;
    size_t off = ((size_t)(b * N_ + n0 + row)) * 256 + c0;
    int4 v4 = *(const int4*)&c2o[off];
    u16* pu = (u16*)&v4;
    #pragma unroll
    for (int j = 0; j < 8; ++j) {
      int c = c0 + j;
      float v = bf2f(pu[j]) * sc[c] + sh[c] + at_[row][c];
      pu[j] = bf16r(v >= 0.f ? v : 0.01f * v);
    }
    *(int4*)&cvo[off] = v4;
  }
}

// ---------------- conv8 MFMA GEMM + bias + skip -> d_out CF, LDS-transposed coalesced epilogue ----------------
__global__ __launch_bounds__(256) void k_conv8m(const u16* __restrict__ cvo,
                                                const u16* __restrict__ w8p,
                                                const float* __restrict__ b8,
                                                const float* __restrict__ skip,
                                                float* __restrict__ out) {
  __shared__ alignas(16) u16 At[4096];
  __shared__ alignas(16) u16 Bt[4096];
  __shared__ alignas(16) float Ts[128 * 132];
  int tid = threadIdx.x, l = tid & 63, w = tid >> 6;
  int wm = w >> 1, wn = w & 1;
  int kg = l >> 4;
  int tok0 = blockIdx.x * 128, oct = blockIdx.y;
  int b = tok0 >> 12;
  int aoff[4], boff[4];
  #pragma unroll
  for (int r = 0; r < 4; ++r) {
    int m = wm * 64 + r * 16 + (l & 15);
    aoff[r] = m * 32 + ((kg ^ f4(m)) << 3);
    int o = wn * 64 + r * 16 + (l & 15);
    boff[r] = o * 32 + ((kg ^ f4(o)) << 3);
  }
  f32x4 acc[4][4];
  #pragma unroll
  for (int r = 0; r < 4; ++r)
    #pragma unroll
    for (int jt = 0; jt < 4; ++jt)
      acc[r][jt] = (f32x4){0.f, 0.f, 0.f, 0.f};
  for (int k0 = 0; k0 < 8; ++k0) {
    __syncthreads();
    #pragma unroll
    for (int it = 0; it < 2; ++it) {
      int slot = it * 256 + tid;
      int row = slot >> 2, cp = slot & 3;
      int cig = cp ^ f4(row);
      g2l16(cvo + ((size_t)(tok0 + row) * 256 + k0 * 32 + cig * 8),
            &At[(it * 256 + (tid & 192)) * 8]);
    }
    const u16* qb = w8p + ((size_t)(oct * 8 + k0) << 12);
    #pragma unroll
    for (int it = 0; it < 2; ++it)
      g2l16(qb + (it * 256 + tid) * 8, &Bt[(it * 256 + (tid & 192)) * 8]);
    __syncthreads();
    short8_t av[4], bv[4];
    #pragma unroll
    for (int r = 0; r < 4; ++r) av[r] = *(const short8_t*)&At[aoff[r]];
    #pragma unroll
    for (int jt = 0; jt < 4; ++jt) bv[jt] = *(const short8_t*)&Bt[boff[jt]];
    #pragma unroll
    for (int r = 0; r < 4; ++r)
      #pragma unroll
      for (int jt = 0; jt < 4; ++jt)
        acc[r][jt] = __builtin_amdgcn_mfma_f32_16x16x32_bf16(av[r], bv[jt], acc[r][jt], 0, 0, 0);
  }
  #pragma unroll
  for (int r = 0; r < 4; ++r) {
    int tokl = wm * 64 + r * 16 + ((l >> 4) << 2);
    #pragma unroll
    for (int jt = 0; jt < 4; ++jt) {
      int ocl = wn * 64 + jt * 16 + (l & 15);
      *(float4*)&Ts[ocl * 132 + tokl] =
          (float4){acc[r][jt][0], acc[r][jt][1], acc[r][jt][2], acc[r][jt][3]};
    }
  }
  __syncthreads();
  int n0l = tok0 & 4095;
  #pragma unroll
  for (int i = 0; i < 16; ++i) {
    int s = i * 256 + tid;
    int row = s >> 5;
    int c4 = (s & 31) * 4;
    int oc = oct * 128 + row;
    size_t base = ((size_t)(b * 256 + oc)) * 4096 + n0l + c4;
    float4 s4 = *(const float4*)&skip[base];
    float bias = b8[oc];
    const float* tp = &Ts[row * 132 + c4];
    float4 o4;
    o4.x = s4.x + bias + tp[0];
    o4.y = s4.y + bias + tp[1];
    o4.z = s4.z + bias + tp[2];
    o4.w = s4.w + bias + tp[3];
    *(float4*)&out[base] = o4;
  }
}

extern "C" void kernel_launch(void* const* d_in, const int* in_sizes, int n_in,
                              void* d_out, int out_size, void* d_ws, size_t ws_size,
                              hipStream_t stream) {
  const float* x       = (const float*)d_in[0];
  const float* gamma   = (const float*)d_in[1];
  const float* ln_w    = (const float*)d_in[2];
  const float* ln_b    = (const float*)d_in[3];
  const float* qkvv_w  = (const float*)d_in[4];
  const float* ef_w    = (const float*)d_in[5];
  const float* ef_b    = (const float*)d_in[6];
  const float* temp    = (const float*)d_in[7];
  const float* temp2   = (const float*)d_in[8];
  const float* op1_w   = (const float*)d_in[9];
  const float* op1_b   = (const float*)d_in[10];
  const float* op2_w   = (const float*)d_in[11];
  const float* op2_b   = (const float*)d_in[12];
  const float* conv1_w = (const float*)d_in[13];
  const float* bn1_w   = (const float*)d_in[14];
  const float* bn1_b   = (const float*)d_in[15];
  const float* conv2_w = (const float*)d_in[16];
  const float* bn2_w   = (const float*)d_in[17];
  const float* bn2_b   = (const float*)d_in[18];
  const float* conv8_w = (const float*)d_in[19];
  const float* conv8_b = (const float*)d_in[20];

  float* ws = (float*)d_ws;
  const size_t M1 = 1u << 20;
  float* askip  = ws;                        // 0..4M f32 CF (4M..8M free)
  u16*   apack1 = (u16*)(ws + 8 * M1);       // 3.54MB (prepack..conv2; no alias)
  u16*   apack2 = (u16*)(ws + 10 * M1);      // 3.54MB
  u16*   xt1    = (u16*)(ws + 16 * M1);      // CL bf16 (2M floats)
  u16*   xnb    = (u16*)(ws + 18 * M1);      // ln..gemm (ends 20M)
  u16*   xsa_b  = (u16*)(ws + 18 * M1);      // attnsa..opcatm (aliases dead xnb)
  float* Spp    = ws + 19 * M1;              // attnca..xca
  float* kvpart = ws + 20 * M1;              // kvproj..attnsa (1M floats)
  u16*   xca_b  = (u16*)(ws + 22 * M1);      // xca..opcatm
  u16*   cvo    = (u16*)(ws + 22 * M1);      // bn2fuse..conv8m (xca_b dead)
  u16*   qct    = (u16*)(ws + 24 * M1);      // gemm..attnsa
  u16*   c1o    = (u16*)(ws + 26 * M1);      // conv phase (qct dead)
  u16*   ht     = (u16*)(ws + 28 * M1);
  u16*   c2o    = (u16*)(ws + 30 * M1);
  float* sm     = ws + 32 * M1;
  float* sbuf   = sm;                        // 2048 (zeroed; gemm atomics)
  float* bnacc  = sm + 2048;                 // 1024 (zeroed; conv BN atomics)
  float* zgu_f  = sm + 3072;                 // 128 (zeroed; conv halo guard)
  u16*   zgu    = (u16*)zgu_f;
  u16*   qpack  = (u16*)(sm + 3200);                   // 512KB
  u16*   efpack = (u16*)(sm + 3200 + 131072);          // 512KB
  u16*   w8pack = (u16*)(sm + 3200 + 262144);          // 128KB
  u16*   oppack = (u16*)(sm + 3200 + 294912);          // 128KB

  k_pre_ln<<<dim3(1601), 256, 0, stream>>>(x, ln_w, ln_b, qkvv_w, conv8_w, op1_w, op2_w,
                                           ef_w, conv1_w, conv2_w,
                                           xnb, qpack, w8pack, oppack, efpack,
                                           apack1, apack2, sm);
  k_gemm<<<dim3(128, 8), 256, 0, stream>>>(xnb, qpack, qct, sbuf);
  k_kvproj_m<<<dim3(4, 4, 4), 256, 0, stream>>>(qct, efpack, kvpart);
  k_attnca_p<<<dim3(32, 8), 256, 0, stream>>>(qct, Spp);
  k_xca<<<dim3(32, 8, 4), 256, 0, stream>>>(qct, Spp, sbuf, temp, xca_b);
  k_attnsa<<<dim3(16, 8, 4), 256, 0, stream>>>(qct, kvpart, ef_b, sbuf, temp2, xsa_b);
  k_opcatm<<<dim3(128, 2), 256, 0, stream>>>(xsa_b, xca_b, x, gamma, oppack, op1_b, op2_b, askip, xt1);
  k_conv3m<<<dim3(512), 256, 0, stream>>>(xt1, apack1, zgu, c1o, bnacc, bnacc + 256);
  k_bnelt<<<dim3(256), 256, 0, stream>>>(c1o, bnacc, bnacc + 256, bn1_w, bn1_b, ht);
  k_conv3m<<<dim3(512), 256, 0, stream>>>(ht, apack2, zgu, c2o, bnacc + 512, bnacc + 768);
  k_bn2fuse<<<dim3(128, 4), 256, 0, stream>>>(c2o, askip, bnacc + 512, bnacc + 768, bn2_w, bn2_b, cvo);
  k_conv8m<<<dim3(128, 2), 256, 0, stream>>>(cvo, w8pack, conv8_b, askip, (float*)d_out);
}

// Round 13
// 321.919 us; speedup vs baseline: 1.0765x; 1.0063x over previous
//
#include <hip/hip_runtime.h>

#define B_ 4
#define C_ 256
#define N_ 4096

typedef unsigned short u16;
typedef __attribute__((ext_vector_type(8))) short short8_t;
typedef __attribute__((ext_vector_type(4))) float f32x4;

__device__ __forceinline__ u16 bf16r(float f) {
  unsigned u = __float_as_uint(f);
  return (u16)((u + 0x7FFFu + ((u >> 16) & 1u)) >> 16);
}
__device__ __forceinline__ float bf2f(u16 u) {
  return __uint_as_float(((unsigned)u) << 16);
}

__device__ __forceinline__ void g2l16(const u16* g, u16* l) {
  __builtin_amdgcn_global_load_lds((const __attribute__((address_space(1))) void*)g,
                                   (__attribute__((address_space(3))) void*)l, 16, 0, 0);
}

__device__ __forceinline__ int f4(int x) { return (x ^ (x >> 2)) & 3; }

// ---------------- merged: prepack (blocks 0..1087) + LayerNorm (1088..1599) + zerofill (1600) ----------------
__global__ __launch_bounds__(256) void k_pre_ln(const float* __restrict__ x,
                                                const float* __restrict__ ln_w,
                                                const float* __restrict__ ln_b,
                                                const float* __restrict__ qkvv_w,
                                                const float* __restrict__ conv8_w,
                                                const float* __restrict__ op1_w,
                                                const float* __restrict__ op2_w,
                                                const float* __restrict__ ef_w,
                                                const float* __restrict__ conv1_w,
                                                const float* __restrict__ conv2_w,
                                                u16* __restrict__ xnb,
                                                u16* __restrict__ qpack,
                                                u16* __restrict__ w8pack,
                                                u16* __restrict__ oppack,
                                                u16* __restrict__ efpack,
                                                u16* __restrict__ apack1,
                                                u16* __restrict__ apack2,
                                                float* __restrict__ zbuf) {
  __shared__ float tile[32][260];
  __shared__ float s_mu[32], s_rs[32];
  int bid = blockIdx.x, tid = threadIdx.x;
  if (bid < 96) {
    const float* w; u16* dst; int tile_;
    if (bid < 64)      { w = qkvv_w;  dst = qpack;          tile_ = bid; }
    else if (bid < 80) { w = conv8_w; dst = w8pack;         tile_ = bid - 64; }
    else if (bid < 88) { w = op1_w;   dst = oppack;         tile_ = bid - 80; }
    else               { w = op2_w;   dst = oppack + 32768; tile_ = bid - 88; }
    int k0 = tile_ & 7, ot = tile_ >> 3;
    u16* td = dst + (size_t)tile_ * 4096;
    int m = tid >> 1, kb = (tid & 1) * 16, fm = f4(m);
    #pragma unroll
    for (int j = 0; j < 16; ++j) {
      int k = kb + j;
      float v = w[(size_t)(ot * 128 + m) * 256 + k0 * 32 + k];
      td[m * 32 + (((k >> 3) ^ fm) << 3) + (k & 7)] = bf16r(v);
    }
  } else if (bid < 224) {
    int k0 = bid - 96;
    int m = tid & 63, kq = tid >> 6, fm = f4(m);
    u16* td = efpack + (size_t)k0 * 2048;
    #pragma unroll
    for (int kk = 0; kk < 8; ++kk) {
      int k = kq * 8 + kk;
      td[m * 32 + (((k >> 3) ^ fm) << 3) + (k & 7)] = bf16r(ef_w[(size_t)m * 4096 + k0 * 32 + k]);
    }
  } else if (bid < 1088) {
    int t = bid - 224;
    const float* w = (t < 432) ? conv1_w : conv2_w;
    u16* dst = (t < 432) ? apack1 : apack2;
    int tile_ = (t < 432) ? t : t - 432;
    int tap = tile_ % 27; int tmp = tile_ / 27;
    int k0 = tmp & 7; int ot = tmp >> 3;
    u16* td = dst + (size_t)tile_ * 4096;
    int m = tid >> 1, kb = (tid & 1) * 16;
    #pragma unroll
    for (int j = 0; j < 16; ++j) {
      int k = kb + j;
      float v = w[((size_t)(ot * 128 + m) * 256 + k0 * 32 + k) * 27 + tap];
      td[m * 32 + k] = bf16r(v);
    }
  } else if (bid < 1600) {
    int lb = bid - 1088;
    int b = lb >> 7, n0 = (lb & 127) * 32;
    for (int idx = tid; idx < 32 * 256; idx += 256) {
      int nl = idx & 31, c = idx >> 5;
      tile[nl][c] = x[((size_t)(b * C_ + c)) * N_ + n0 + nl];
    }
    __syncthreads();
    int token = tid >> 3, sub = tid & 7;
    float s = 0.f, sq = 0.f;
    for (int j = 0; j < 32; ++j) {
      float v = tile[token][sub + j * 8];
      s += v; sq += v * v;
    }
    for (int o = 1; o < 8; o <<= 1) { s += __shfl_xor(s, o); sq += __shfl_xor(sq, o); }
    if (sub == 0) {
      float mu = s * (1.f / 256.f);
      float var = sq * (1.f / 256.f) - mu * mu;
      s_mu[token] = mu;
      s_rs[token] = rsqrtf(var + 1e-5f);
    }
    __syncthreads();
    int c = tid;
    float lw = ln_w[c], lb2 = ln_b[c];
    for (int k = 0; k < 32; ++k) {
      float v = (tile[k][c] - s_mu[k]) * s_rs[k] * lw + lb2;
      xnb[((size_t)(b * N_ + n0 + k)) * 256 + c] = bf16r(v);
    }
  } else {
    for (int i = tid; i < 3200; i += 256) zbuf[i] = 0.f;
  }
}

// ---------------- qkvv GEMM -> qct bf16 [b][cc][n] (LDS-transposed write) + sumsq ----------------
__global__ __launch_bounds__(256) void k_gemm(const u16* __restrict__ xnb,
                                              const u16* __restrict__ qpack,
                                              u16* __restrict__ qct,
                                              float* __restrict__ sbuf) {
  __shared__ alignas(16) u16 At[4096];
  __shared__ alignas(16) u16 Bt[4096];
  __shared__ alignas(16) u16 Tt[128 * 136];  // transpose staging, 34.8 KB
  int tid = threadIdx.x, l = tid & 63, w = tid >> 6;
  int wm = w >> 1, wn = w & 1;
  int kg = l >> 4;
  int tok0 = blockIdx.x * 128, oct = blockIdx.y;
  int b = tok0 >> 12;
  int aoff[4], boff[4];
  #pragma unroll
  for (int r = 0; r < 4; ++r) {
    int m = wm * 64 + r * 16 + (l & 15);
    aoff[r] = m * 32 + ((kg ^ f4(m)) << 3);
    int o = wn * 64 + r * 16 + (l & 15);
    boff[r] = o * 32 + ((kg ^ f4(o)) << 3);
  }
  f32x4 acc[4][4];
  #pragma unroll
  for (int r = 0; r < 4; ++r)
    #pragma unroll
    for (int jt = 0; jt < 4; ++jt)
      acc[r][jt] = (f32x4){0.f, 0.f, 0.f, 0.f};
  for (int k0 = 0; k0 < 8; ++k0) {
    __syncthreads();
    #pragma unroll
    for (int it = 0; it < 2; ++it) {
      int slot = it * 256 + tid;
      int row = slot >> 2, cp = slot & 3;
      int cig = cp ^ f4(row);
      g2l16(xnb + ((size_t)(tok0 + row) * 256 + k0 * 32 + cig * 8),
            &At[(it * 256 + (tid & 192)) * 8]);
    }
    const u16* qb = qpack + ((size_t)(oct * 8 + k0) << 12);
    #pragma unroll
    for (int it = 0; it < 2; ++it)
      g2l16(qb + (it * 256 + tid) * 8, &Bt[(it * 256 + (tid & 192)) * 8]);
    __syncthreads();
    short8_t av[4], bv[4];
    #pragma unroll
    for (int r = 0; r < 4; ++r) av[r] = *(const short8_t*)&At[aoff[r]];
    #pragma unroll
    for (int jt = 0; jt < 4; ++jt) bv[jt] = *(const short8_t*)&Bt[boff[jt]];
    #pragma unroll
    for (int r = 0; r < 4; ++r)
      #pragma unroll
      for (int jt = 0; jt < 4; ++jt)
        acc[r][jt] = __builtin_amdgcn_mfma_f32_16x16x32_bf16(av[r], bv[jt], acc[r][jt], 0, 0, 0);
  }
  // sumsq for q,k (oct<4)
  if (oct < 4) {
    #pragma unroll
    for (int jt = 0; jt < 4; ++jt) {
      float ss = 0.f;
      #pragma unroll
      for (int r = 0; r < 4; ++r)
        #pragma unroll
        for (int reg = 0; reg < 4; ++reg)
          ss += acc[r][jt][reg] * acc[r][jt][reg];
      ss += __shfl_xor(ss, 16);
      ss += __shfl_xor(ss, 32);
      if ((l >> 4) == 0) {
        int oc = oct * 128 + wn * 64 + jt * 16 + (l & 15);
        atomicAdd(&sbuf[(oc >> 8) * 1024 + b * 256 + (oc & 255)], ss);
      }
    }
  }
  // transpose via LDS: Tt[ocl][tokl]
  #pragma unroll
  for (int r = 0; r < 4; ++r) {
    int tokl = wm * 64 + r * 16 + ((l >> 4) << 2);
    #pragma unroll
    for (int jt = 0; jt < 4; ++jt) {
      int ocl = wn * 64 + jt * 16 + (l & 15);
      ushort4 h4;
      h4.x = bf16r(acc[r][jt][0]);
      h4.y = bf16r(acc[r][jt][1]);
      h4.z = bf16r(acc[r][jt][2]);
      h4.w = bf16r(acc[r][jt][3]);
      *(ushort4*)&Tt[ocl * 136 + tokl] = h4;
    }
  }
  __syncthreads();
  int n0 = tok0 & 4095;
  #pragma unroll
  for (int i = 0; i < 8; ++i) {
    int s = i * 256 + tid;
    int row = s >> 4;
    int col = (s & 15) * 8;
    *(int4*)&qct[((size_t)(b * 1024 + oct * 128 + row)) * 4096 + n0 + col] =
        *(const int4*)&Tt[row * 136 + col];
  }
}

// ---------------- kproj/vproj MFMA GEMM, K-split x4, NON-ATOMIC partials ----------------
__global__ __launch_bounds__(256) void k_kvproj_m(const u16* __restrict__ qct,
                                                  const u16* __restrict__ efp,
                                                  float* __restrict__ kvpart) {
  __shared__ alignas(16) u16 At[16384];
  __shared__ alignas(16) u16 Bt[8192];
  int tid = threadIdx.x, l = tid & 63, w = tid >> 6;
  int mt = blockIdx.x, b = blockIdx.y, kz = blockIdx.z;
  int ccb = (mt < 2) ? (256 + mt * 128) : (768 + (mt - 2) * 128);
  int kg = l >> 4;
  int aoff[2], boff[4];
  #pragma unroll
  for (int r = 0; r < 2; ++r) {
    int m = w * 32 + r * 16 + (l & 15);
    aoff[r] = m * 32 + ((kg ^ f4(m)) << 3);
  }
  #pragma unroll
  for (int jt = 0; jt < 4; ++jt) {
    int o = jt * 16 + (l & 15);
    boff[jt] = o * 32 + ((kg ^ f4(o)) << 3);
  }
  f32x4 acc[2][4];
  #pragma unroll
  for (int r = 0; r < 2; ++r)
    #pragma unroll
    for (int jt = 0; jt < 4; ++jt) acc[r][jt] = (f32x4){0.f, 0.f, 0.f, 0.f};
  for (int k0 = kz * 8; k0 < kz * 8 + 8; ++k0) {
    __syncthreads();
    #pragma unroll
    for (int it = 0; it < 8; ++it) {
      int slot = it * 256 + tid;
      int sub = slot >> 9, r = (slot >> 2) & 127, cp = slot & 3;
      g2l16(qct + ((size_t)(b * 1024 + ccb + r)) * 4096 + k0 * 128 + sub * 32 + ((cp ^ f4(r)) << 3),
            &At[(it * 256 + (tid & 192)) * 8]);
    }
    #pragma unroll
    for (int it = 0; it < 4; ++it) {
      int slot = it * 256 + tid;
      g2l16(efp + (size_t)k0 * 8192 + slot * 8, &Bt[(it * 256 + (tid & 192)) * 8]);
    }
    __syncthreads();
    #pragma unroll
    for (int sub = 0; sub < 4; ++sub) {
      short8_t av[2], bv[4];
      #pragma unroll
      for (int r = 0; r < 2; ++r) av[r] = *(const short8_t*)&At[sub * 4096 + aoff[r]];
      #pragma unroll
      for (int jt = 0; jt < 4; ++jt) bv[jt] = *(const short8_t*)&Bt[sub * 2048 + boff[jt]];
      #pragma unroll
      for (int r = 0; r < 2; ++r)
        #pragma unroll
        for (int jt = 0; jt < 4; ++jt)
          acc[r][jt] = __builtin_amdgcn_mfma_f32_16x16x32_bf16(av[r], bv[jt], acc[r][jt], 0, 0, 0);
    }
  }
  int kv = mt >> 1;
  float* outd = kvpart + (size_t)kv * 524288 + (size_t)kz * 131072;
  #pragma unroll
  for (int r = 0; r < 2; ++r) {
    int cbase = (mt & 1) * 128 + w * 32 + r * 16 + ((l >> 4) << 2);
    #pragma unroll
    for (int jt = 0; jt < 4; ++jt) {
      int p = jt * 16 + (l & 15);
      #pragma unroll
      for (int reg = 0; reg < 4; ++reg) {
        int cc = cbase + reg;
        outd[((size_t)(b * 8 + (cc >> 5))) * 2048 + (cc & 31) * 64 + p] = acc[r][jt][reg];
      }
    }
  }
}

// ---------------- channel attention pass 1: partial S slices (non-atomic) ----------------
__global__ __launch_bounds__(256) void k_attnca_p(const u16* __restrict__ qct,
                                                  float* __restrict__ Spp) {
  __shared__ u16 Qs[32][520], Ks[32][520];
  int bh = blockIdx.x, ns = blockIdx.y;
  int b = bh >> 3, h = bh & 7;
  int tid = threadIdx.x;
  int n0 = ns * 512;
  for (int idx = tid; idx < 2048; idx += 256) {
    int r = idx >> 6, ch = (idx & 63) * 8;
    *(int4*)&Qs[r][ch] = *(const int4*)&qct[((size_t)(b * 1024 + h * 32 + r)) * 4096 + n0 + ch];
    *(int4*)&Ks[r][ch] = *(const int4*)&qct[((size_t)(b * 1024 + 256 + h * 32 + r)) * 4096 + n0 + ch];
  }
  __syncthreads();
  int r = tid >> 3, sub = tid & 7;
  float a0 = 0.f, a1 = 0.f, a2 = 0.f, a3 = 0.f;
  for (int nb = 0; nb < 512; nb += 8) {
    short8_t q8 = *(const short8_t*)&Qs[r][nb];
    short8_t k0 = *(const short8_t*)&Ks[sub][nb];
    short8_t k1 = *(const short8_t*)&Ks[sub + 8][nb];
    short8_t k2 = *(const short8_t*)&Ks[sub + 16][nb];
    short8_t k3 = *(const short8_t*)&Ks[sub + 24][nb];
    #pragma unroll
    for (int j = 0; j < 8; ++j) {
      float qv = bf2f((u16)q8[j]);
      a0 += qv * bf2f((u16)k0[j]);
      a1 += qv * bf2f((u16)k1[j]);
      a2 += qv * bf2f((u16)k2[j]);
      a3 += qv * bf2f((u16)k3[j]);
    }
  }
  float* sp = Spp + (size_t)ns * 32768 + (size_t)bh * 1024 + r * 32;
  sp[sub] = a0;
  sp[sub + 8] = a1;
  sp[sub + 16] = a2;
  sp[sub + 24] = a3;
}

// ---------------- x_ca = softmax(S) @ v_ca -> xca_b bf16 CL (casm fused) ----------------
__global__ __launch_bounds__(256) void k_xca(const u16* __restrict__ qct,
                                             const float* __restrict__ Spp,
                                             const float* __restrict__ sbuf,
                                             const float* __restrict__ temp,
                                             u16* __restrict__ xca_b) {
  __shared__ float A[32][33];
  __shared__ float vt[32][129];
  int n0 = blockIdx.x * 128;
  int h = blockIdx.y, b = blockIdx.z;
  int bh = b * 8 + h;
  int tid = threadIdx.x;
  if (tid < 32) {
    float qiv = 1.f / fmaxf(sqrtf(sbuf[b * 256 + h * 32 + tid]), 1e-12f);
    float tmp = temp[h];
    float vals[32];
    #pragma unroll
    for (int e = 0; e < 32; ++e) vals[e] = 0.f;
    for (int ns = 0; ns < 8; ++ns) {
      const float* sp = Spp + (size_t)ns * 32768 + (size_t)bh * 1024 + tid * 32;
      #pragma unroll
      for (int e4 = 0; e4 < 32; e4 += 4) {
        float4 v4 = *(const float4*)&sp[e4];
        vals[e4] += v4.x; vals[e4 + 1] += v4.y;
        vals[e4 + 2] += v4.z; vals[e4 + 3] += v4.w;
      }
    }
    float mx = -1e30f;
    #pragma unroll
    for (int e = 0; e < 32; ++e) {
      float kiv = 1.f / fmaxf(sqrtf(sbuf[1024 + b * 256 + h * 32 + e]), 1e-12f);
      float s = vals[e] * qiv * kiv * tmp;
      vals[e] = s;
      mx = fmaxf(mx, s);
    }
    float ssum = 0.f;
    #pragma unroll
    for (int e = 0; e < 32; ++e) { vals[e] = __expf(vals[e] - mx); ssum += vals[e]; }
    float is = 1.f / ssum;
    #pragma unroll
    for (int e = 0; e < 32; ++e) A[tid][e] = vals[e] * is;
  }
  int e = tid >> 3, ns = (tid & 7) * 16;
  const u16* src = qct + ((size_t)(b * 1024 + 512 + h * 32 + e)) * 4096 + n0 + ns;
  #pragma unroll
  for (int j4 = 0; j4 < 16; j4 += 4) {
    ushort4 u = *(const ushort4*)&src[j4];
    vt[e][ns + j4] = bf2f(u.x);
    vt[e][ns + j4 + 1] = bf2f(u.y);
    vt[e][ns + j4 + 2] = bf2f(u.z);
    vt[e][ns + j4 + 3] = bf2f(u.w);
  }
  __syncthreads();
  int nl = tid & 127, dg = (tid >> 7) * 16;
  float acc[16] = {};
  for (int ee = 0; ee < 32; ++ee) {
    float v = vt[ee][nl];
    #pragma unroll
    for (int j = 0; j < 16; ++j) acc[j] += A[dg + j][ee] * v;
  }
  u16* outp = xca_b + ((size_t)(b * N_ + n0 + nl)) * 256 + h * 32 + dg;
  #pragma unroll
  for (int j = 0; j < 16; ++j) outp[j] = bf16r(acc[j]);
}

// ---------------- spatial attention -> xsa bf16 (kvred + rsq fused into staging) ----------------
__global__ __launch_bounds__(256) void k_attnsa(const u16* __restrict__ qct,
                                                const float* __restrict__ kvpart,
                                                const float* __restrict__ ef_b,
                                                const float* __restrict__ sbuf,
                                                const float* __restrict__ temp2,
                                                u16* __restrict__ xsa_b) {
  __shared__ float kp[32][64], vp[32][64], qi[32];
  __shared__ u16 qt[32][260];
  __shared__ float ot[32][257];
  int bx = blockIdx.x;
  int h = blockIdx.y, b = blockIdx.z;
  int bh = b * 8 + h;
  int tid = threadIdx.x;
  for (int idx = tid; idx < 2048; idx += 256) {
    float bias = ef_b[idx & 63];
    float kpv = bias, vpv = bias;
    size_t base = (size_t)bh * 2048 + idx;
    #pragma unroll
    for (int kz = 0; kz < 4; ++kz) {
      kpv += kvpart[(size_t)kz * 131072 + base];
      vpv += kvpart[524288 + (size_t)kz * 131072 + base];
    }
    kp[idx >> 6][idx & 63] = kpv;
    vp[idx >> 6][idx & 63] = vpv;
  }
  if (tid < 32) qi[tid] = 1.f / fmaxf(sqrtf(sbuf[b * 256 + h * 32 + tid]), 1e-12f);
  {
    int row = tid >> 3, ch = (tid & 7) * 32;
    const u16* src = qct + ((size_t)(b * 1024 + h * 32 + row)) * 4096 + bx * 256 + ch;
    *(int4*)&qt[row][ch] = *(const int4*)&src[0];
    *(int4*)&qt[row][ch + 8] = *(const int4*)&src[8];
    *(int4*)&qt[row][ch + 16] = *(const int4*)&src[16];
    *(int4*)&qt[row][ch + 24] = *(const int4*)&src[24];
  }
  __syncthreads();
  float q[32];
  #pragma unroll
  for (int d = 0; d < 32; ++d) q[d] = bf2f(qt[d][tid]) * qi[d];
  float t2 = temp2[h];
  float l[64];
  #pragma unroll
  for (int p = 0; p < 64; ++p) {
    float s = 0;
    #pragma unroll
    for (int d = 0; d < 32; ++d) s += q[d] * kp[d][p];
    l[p] = s * t2;
  }
  float m = -1e30f;
  #pragma unroll
  for (int p = 0; p < 64; ++p) m = fmaxf(m, l[p]);
  float ssum = 0;
  #pragma unroll
  for (int p = 0; p < 64; ++p) { l[p] = __expf(l[p] - m); ssum += l[p]; }
  float is = 1.f / ssum;
  float o[32] = {};
  #pragma unroll
  for (int p = 0; p < 64; ++p) {
    float wv = l[p] * is;
    #pragma unroll
    for (int d = 0; d < 32; ++d) o[d] += wv * vp[d][p];
  }
  #pragma unroll
  for (int d = 0; d < 32; ++d) ot[d][tid] = o[d];
  __syncthreads();
  #pragma unroll
  for (int i = 0; i < 4; ++i) {
    int s = i * 256 + tid;
    int d = s >> 5;
    int c0 = (s & 31) * 8;
    ushort4 u0, u1;
    u0.x = bf16r(ot[d][c0]);     u0.y = bf16r(ot[d][c0 + 1]);
    u0.z = bf16r(ot[d][c0 + 2]); u0.w = bf16r(ot[d][c0 + 3]);
    u1.x = bf16r(ot[d][c0 + 4]); u1.y = bf16r(ot[d][c0 + 5]);
    u1.z = bf16r(ot[d][c0 + 6]); u1.w = bf16r(ot[d][c0 + 7]);
    u16* dst = xsa_b + (size_t)b * N_ * 256 + (size_t)(d * 128 + h * 16 + bx) * 256 + c0;
    *(ushort4*)&dst[0] = u0;
    *(ushort4*)&dst[4] = u1;
  }
}

// ---------------- op1/op2 MFMA GEMM + gamma residual -> askip CF bf16 + xt1 CL bf16 ----------------
// askip now bf16 (halves its HBM write here and reads in bn2fuse/conv8m: 192->96 MB total).
__global__ __launch_bounds__(256) void k_opcatm(const u16* __restrict__ xsa_b,
                                                const u16* __restrict__ xca_b,
                                                const float* __restrict__ x,
                                                const float* __restrict__ gamma,
                                                const u16* __restrict__ oppack,
                                                const float* __restrict__ op1_b,
                                                const float* __restrict__ op2_b,
                                                u16* __restrict__ attn_skip,
                                                u16* __restrict__ xt1) {
  __shared__ alignas(16) u16 At[4096];
  __shared__ alignas(16) u16 Bt[4096];
  __shared__ alignas(16) float Ttf[128 * 133];
  __shared__ alignas(16) u16 rb[128 * 136];
  int tid = threadIdx.x, l = tid & 63, w = tid >> 6;
  int wm = w >> 1, wn = w & 1;
  int kg = l >> 4;
  int tok0 = blockIdx.x * 128, oct = blockIdx.y;
  int b = tok0 >> 12;
  const u16* src = oct ? xca_b : xsa_b;
  int aoff[4], boff[4];
  #pragma unroll
  for (int r = 0; r < 4; ++r) {
    int m = wm * 64 + r * 16 + (l & 15);
    aoff[r] = m * 32 + ((kg ^ f4(m)) << 3);
    int o = wn * 64 + r * 16 + (l & 15);
    boff[r] = o * 32 + ((kg ^ f4(o)) << 3);
  }
  f32x4 acc[4][4];
  #pragma unroll
  for (int r = 0; r < 4; ++r)
    #pragma unroll
    for (int jt = 0; jt < 4; ++jt)
      acc[r][jt] = (f32x4){0.f, 0.f, 0.f, 0.f};
  for (int k0 = 0; k0 < 8; ++k0) {
    __syncthreads();
    #pragma unroll
    for (int it = 0; it < 2; ++it) {
      int slot = it * 256 + tid;
      int row = slot >> 2, cp = slot & 3;
      int cig = cp ^ f4(row);
      g2l16(src + ((size_t)(tok0 + row) * 256 + k0 * 32 + cig * 8),
            &At[(it * 256 + (tid & 192)) * 8]);
    }
    const u16* qb = oppack + ((size_t)(oct * 8 + k0) << 12);
    #pragma unroll
    for (int it = 0; it < 2; ++it)
      g2l16(qb + (it * 256 + tid) * 8, &Bt[(it * 256 + (tid & 192)) * 8]);
    __syncthreads();
    short8_t av[4], bv[4];
    #pragma unroll
    for (int r = 0; r < 4; ++r) av[r] = *(const short8_t*)&At[aoff[r]];
    #pragma unroll
    for (int jt = 0; jt < 4; ++jt) bv[jt] = *(const short8_t*)&Bt[boff[jt]];
    #pragma unroll
    for (int r = 0; r < 4; ++r)
      #pragma unroll
      for (int jt = 0; jt < 4; ++jt)
        acc[r][jt] = __builtin_amdgcn_mfma_f32_16x16x32_bf16(av[r], bv[jt], acc[r][jt], 0, 0, 0);
  }
  // epilogue 1: acc -> Ttf[ocl][tokl] (f32, stride 133)
  #pragma unroll
  for (int r = 0; r < 4; ++r) {
    int tokl = wm * 64 + r * 16 + ((l >> 4) << 2);
    #pragma unroll
    for (int jt = 0; jt < 4; ++jt) {
      int ocl = wn * 64 + jt * 16 + (l & 15);
      float* tp = &Ttf[ocl * 133 + tokl];
      tp[0] = acc[r][jt][0];
      tp[1] = acc[r][jt][1];
      tp[2] = acc[r][jt][2];
      tp[3] = acc[r][jt][3];
    }
  }
  __syncthreads();
  // epilogue 2a: coalesced x read + residual; bf16 askip write (ushort4); store v back into Ttf
  {
    int n0l = tok0 & 4095;
    #pragma unroll
    for (int i = 0; i < 16; ++i) {
      int s = i * 256 + tid;
      int cl = s >> 5;
      int t4 = (s & 31) * 4;
      int c = oct * 128 + cl;
      float g = gamma[c];
      float bias = oct ? op2_b[cl] : op1_b[cl];
      size_t base = ((size_t)(b * 256 + c)) * 4096 + n0l + t4;
      float4 x4 = *(const float4*)&x[base];
      float* tp = &Ttf[cl * 133 + t4];
      float4 o4;
      o4.x = x4.x + g * (tp[0] + bias);
      o4.y = x4.y + g * (tp[1] + bias);
      o4.z = x4.z + g * (tp[2] + bias);
      o4.w = x4.w + g * (tp[3] + bias);
      ushort4 h4;
      h4.x = bf16r(o4.x); h4.y = bf16r(o4.y);
      h4.z = bf16r(o4.z); h4.w = bf16r(o4.w);
      *(ushort4*)&attn_skip[base] = h4;
      tp[0] = o4.x; tp[1] = o4.y; tp[2] = o4.z; tp[3] = o4.w;
    }
  }
  __syncthreads();
  // epilogue 2b: stage bf16 from Ttf -> rb (lane = channel; stride-133 banks distinct)
  {
    int cl = tid & 127, th = tid >> 7;
    const float* tp = &Ttf[cl * 133 + th * 64];
    #pragma unroll
    for (int t = 0; t < 64; ++t)
      rb[(th * 64 + t) * 136 + cl] = bf16r(tp[t]);
  }
  __syncthreads();
  // epilogue 3: xt1 coalesced int4
  {
    int n0l = tok0 & 4095;
    #pragma unroll
    for (int i = 0; i < 8; ++i) {
      int s = i * 256 + tid;
      int row = s >> 4;
      int c0 = (s & 15) * 8;
      *(int4*)&xt1[((size_t)(b * N_ + n0l + row)) * 256 + oct * 128 + c0] =
          *(const int4*)&rb[row * 136 + c0];
    }
  }
}

// ---------------- split-K MFMA conv 3x3x3 (channels-last output), deep-ring + dbuf ----------------
// Frozen structure: conflicts/ILP/occupancy-x2 all proven null; setprio kept (R6: removal +15%).
__global__ __launch_bounds__(256, 2) void k_conv3m(const u16* __restrict__ xt,
                                                   const u16* __restrict__ apack,
                                                   const u16* __restrict__ zg,
                                                   u16* __restrict__ out,
                                                   float* __restrict__ bnsum,
                                                   float* __restrict__ bnsq) {
  __shared__ alignas(16) u16 Xs[2][2][8192];   // [ks][dbuf][16KB]
  int tid = threadIdx.x, l = tid & 63, w = tid >> 6;
  int wm = w & 1, ks = w >> 1;
  int kg = l >> 4;
  int bid = blockIdx.x;
  int cot = bid & 1;
  int sb = (bid >> 1) & 63;
  int b = bid >> 7;
  int h0 = ((sb >> 4) & 3) << 2, w0 = ((sb >> 2) & 3) << 2, d0 = (sb & 3) << 2;

  int cellc[4];
  {
    int cl = l & 15;
    int wv = (cl >> 2) & 3, dv = cl & 3;
    #pragma unroll
    for (int jt = 0; jt < 4; ++jt)
      cellc[jt] = (jt + 1) * 168 + (wv + 1) * 28 + kg * 6 + (dv + 1);
  }
  const int alane = (wm * 64 + (l & 15)) * 32 + kg * 8;

  const u16* xp[4];
  unsigned okm = 0;
  #pragma unroll
  for (int i = 0; i < 4; ++i) {
    int slot = i * 256 + tid;
    int hh = slot / 168;
    int r = slot - hh * 168;
    int ww = r / 28;
    int r2 = r - ww * 28;
    int kk = r2 / 6;
    int dd = r2 - kk * 6;
    int gh = h0 + hh - 1, gw = w0 + ww - 1, gd = d0 + dd - 1;
    bool ok = (hh < 6) && (kk < 4) &&
              ((unsigned)gh < 16u) && ((unsigned)gw < 16u) && ((unsigned)gd < 16u);
    xp[i] = ok ? (xt + ((size_t)(b * N_ + gh * 256 + gw * 16 + gd)) * 256 + kk * 8) : zg;
    okm |= ((unsigned)ok) << i;
  }

  f32x4 acc[4][4];
  #pragma unroll
  for (int r = 0; r < 4; ++r)
    #pragma unroll
    for (int jt = 0; jt < 4; ++jt)
      acc[r][jt] = (f32x4){0.f, 0.f, 0.f, 0.f};

  #pragma unroll
  for (int bk = 0; bk < 2; ++bk)
    #pragma unroll
    for (int i = 0; i < 4; ++i) {
      const u16* p = ((okm >> i) & 1) ? (xp[i] + ((bk * 4) << 5)) : zg;
      g2l16(p, &Xs[bk][0][(i * 256 + (tid & 192)) * 8]);
    }
  __syncthreads();

  short8_t av[4][4], bv[3][4];

#define CONV_TAP(t)                                                                   \
  do {                                                                                \
    if ((t) < 24) {                                                                   \
      const int tnA = (t) + 3;                                                        \
      _Pragma("unroll")                                                               \
      for (int r = 0; r < 4; ++r)                                                     \
        av[tnA & 3][r] = *(const short8_t*)(at + tnA * 4096 + r * 512);               \
    }                                                                                 \
    if ((t) < 25) {                                                                   \
      const int tnB = (t) + 2;                                                        \
      const int dh = tnB / 9, rr_ = tnB - dh * 9, dw = rr_ / 3, dd2 = rr_ - dw * 3;   \
      const int OFF = (dh - 1) * 168 + (dw - 1) * 28 + (dd2 - 1);                     \
      _Pragma("unroll")                                                               \
      for (int jt = 0; jt < 4; ++jt)                                                  \
        bv[tnB % 3][jt] = *(const short8_t*)&Xb[(cellc[jt] + OFF) * 8];               \
    }                                                                                 \
    __builtin_amdgcn_s_setprio(1);                                                    \
    _Pragma("unroll")                                                                 \
    for (int r = 0; r < 4; ++r)                                                       \
      _Pragma("unroll")                                                               \
      for (int jt = 0; jt < 4; ++jt)                                                  \
        acc[r][jt] = __builtin_amdgcn_mfma_f32_16x16x32_bf16(av[(t) & 3][r],          \
                         bv[(t) % 3][jt], acc[r][jt], 0, 0, 0);                       \
    __builtin_amdgcn_s_setprio(0);                                                    \
  } while (0)

  #pragma unroll 1
  for (int step = 0; step < 4; ++step) {
    const int cur = step & 1;
    const u16* Xb = &Xs[ks][cur][0];
    const int ci0 = ks * 4 + step;
    const u16* at = apack + ((size_t)((cot * 8 + ci0) * 27)) * 4096 + alane;
    #pragma unroll
    for (int r = 0; r < 4; ++r) av[0][r] = *(const short8_t*)(at + r * 512);
    #pragma unroll
    for (int r = 0; r < 4; ++r) av[1][r] = *(const short8_t*)(at + 4096 + r * 512);
    #pragma unroll
    for (int r = 0; r < 4; ++r) av[2][r] = *(const short8_t*)(at + 8192 + r * 512);
    #pragma unroll
    for (int jt = 0; jt < 4; ++jt) {
      bv[0][jt] = *(const short8_t*)&Xb[(cellc[jt] - 197) * 8];
      bv[1][jt] = *(const short8_t*)&Xb[(cellc[jt] - 196) * 8];
    }
    #pragma unroll
    for (int t = 0; t < 4; ++t) CONV_TAP(t);
    if (step < 3) {
      const int nd = (step + 1) & 1;
      #pragma unroll
      for (int bk = 0; bk < 2; ++bk)
        #pragma unroll
        for (int i = 0; i < 4; ++i) {
          const u16* p = ((okm >> i) & 1) ? (xp[i] + ((bk * 4 + step + 1) << 5)) : zg;
          g2l16(p, &Xs[bk][nd][(i * 256 + (tid & 192)) * 8]);
        }
    }
    #pragma unroll
    for (int t = 4; t < 27; ++t) CONV_TAP(t);
    __syncthreads();
  }
#undef CONV_TAP

  f32x4* red = (f32x4*)&Xs[0][0][0];
  if (ks == 1) {
    #pragma unroll
    for (int r = 0; r < 4; ++r)
      #pragma unroll
      for (int jt = 0; jt < 4; ++jt)
        red[(r * 4 + jt) * 128 + wm * 64 + l] = acc[r][jt];
  }
  __syncthreads();
  if (ks == 0) {
    #pragma unroll
    for (int r = 0; r < 4; ++r)
      #pragma unroll
      for (int jt = 0; jt < 4; ++jt) {
        f32x4 o = red[(r * 4 + jt) * 128 + wm * 64 + l];
        acc[r][jt][0] += o[0]; acc[r][jt][1] += o[1];
        acc[r][jt][2] += o[2]; acc[r][jt][3] += o[3];
      }
    #pragma unroll
    for (int r = 0; r < 4; ++r) {
      int co = cot * 128 + wm * 64 + r * 16 + ((l >> 4) << 2);
      #pragma unroll
      for (int reg = 0; reg < 4; ++reg) {
        float sv = 0.f, qv = 0.f;
        #pragma unroll
        for (int jt = 0; jt < 4; ++jt) {
          float v = acc[r][jt][reg];
          sv += v; qv += v * v;
        }
        #pragma unroll
        for (int o = 1; o < 16; o <<= 1) {
          sv += __shfl_xor(sv, o);
          qv += __shfl_xor(qv, o);
        }
        if ((l & 15) == 0) {
          atomicAdd(&bnsum[co + reg], sv);
          atomicAdd(&bnsq[co + reg], qv);
        }
      }
      #pragma unroll
      for (int jt = 0; jt < 4; ++jt) {
        int c = jt * 16 + (l & 15);
        int n = (h0 + (c >> 4)) * 256 + (w0 + ((c >> 2) & 3)) * 16 + (d0 + (c & 3));
        ushort4 h4;
        h4.x = bf16r(acc[r][jt][0]);
        h4.y = bf16r(acc[r][jt][1]);
        h4.z = bf16r(acc[r][jt][2]);
        h4.w = bf16r(acc[r][jt][3]);
        *(ushort4*)&out[((size_t)(b * N_ + n)) * 256 + co] = h4;
      }
    }
  }
}

// ---------------- BN apply + LeakyReLU, CL elementwise (bnfin fused) ----------------
__global__ __launch_bounds__(256) void k_bnelt(const u16* __restrict__ src,
                                               const float* __restrict__ bnsum,
                                               const float* __restrict__ bnsq,
                                               const float* __restrict__ w,
                                               const float* __restrict__ bb,
                                               u16* __restrict__ dst) {
  __shared__ float sc[256], sh[256];
  int tid = threadIdx.x;
  float m = bnsum[tid] * (1.f / 16384.f);
  float var = bnsq[tid] * (1.f / 16384.f) - m * m;
  float rstd = rsqrtf(var + 1e-5f);
  float scv = rstd * w[tid];
  sc[tid] = scv;
  sh[tid] = bb[tid] - m * scv;
  __syncthreads();
  size_t base = (size_t)blockIdx.x * 64 * 256;
  #pragma unroll
  for (int i = 0; i < 8; ++i) {
    int s = i * 256 + tid;
    int c0 = (s & 31) * 8;
    size_t off = base + (size_t)(s >> 5) * 256 + c0;
    int4 v4 = *(const int4*)&src[off];
    u16* pu = (u16*)&v4;
    #pragma unroll
    for (int j = 0; j < 8; ++j) {
      float v = bf2f(pu[j]) * sc[c0 + j] + sh[c0 + j];
      pu[j] = bf16r(v >= 0.f ? v : 0.01f * v);
    }
    *(int4*)&dst[off] = v4;
  }
}

// ---------------- BN2 + skip + lrelu -> cvo bf16 CL (bnfin fused; bf16 askip staged) ----------------
__global__ __launch_bounds__(256) void k_bn2fuse(const u16* __restrict__ c2o,
                                                 const u16* __restrict__ askip,
                                                 const float* __restrict__ bnsum,
                                                 const float* __restrict__ bnsq,
                                                 const float* __restrict__ bnw,
                                                 const float* __restrict__ bnb,
                                                 u16* __restrict__ cvo) {
  __shared__ float sc[256], sh[256];
  __shared__ float at_[32][260];
  int n0 = blockIdx.x * 32, b = blockIdx.y, tid = threadIdx.x;
  float m = bnsum[tid] * (1.f / 16384.f);
  float var = bnsq[tid] * (1.f / 16384.f) - m * m;
  float rstd = rsqrtf(var + 1e-5f);
  float scv = rstd * bnw[tid];
  sc[tid] = scv;
  sh[tid] = bnb[tid] - m * scv;
  // bf16 askip staging: 8 lanes per channel row, ushort4 (8B) each
  #pragma unroll
  for (int i = 0; i < 8; ++i) {
    int s = i * 256 + tid;
    int c = s >> 3;
    int t4 = (s & 7) * 4;
    ushort4 a4 = *(const ushort4*)&askip[((size_t)(b * 256 + c)) * 4096 + n0 + t4];
    at_[t4 + 0][c] = bf2f(a4.x);
    at_[t4 + 1][c] = bf2f(a4.y);
    at_[t4 + 2][c] = bf2f(a4.z);
    at_[t4 + 3][c] = bf2f(a4.w);
  }
  __syncthreads();
  #pragma unroll
  for (int i = 0; i < 4; ++i) {
    int s = i * 256 + tid;
    int row = s >> 5, c0 = (s & 31) * 8;
    size_t off = ((size_t)(b * N_ + n0 + row)) * 256 + c0;
    int4 v4 = *(const int4*)&c2o[off];
    u16* pu = (u16*)&v4;
    #pragma unroll
    for (int j = 0; j < 8; ++j) {
      int c = c0 + j;
      float v = bf2f(pu[j]) * sc[c] + sh[c] + at_[row][c];
      pu[j] = bf16r(v >= 0.f ? v : 0.01f * v);
    }
    *(int4*)&cvo[off] = v4;
  }
}

// ---------------- conv8 MFMA GEMM + bias + bf16 skip -> d_out CF, LDS-transposed epilogue ----------------
__global__ __launch_bounds__(256) void k_conv8m(const u16* __restrict__ cvo,
                                                const u16* __restrict__ w8p,
                                                const float* __restrict__ b8,
                                                const u16* __restrict__ skip,
                                                float* __restrict__ out) {
  __shared__ alignas(16) u16 At[4096];
  __shared__ alignas(16) u16 Bt[4096];
  __shared__ alignas(16) float Ts[128 * 132];
  int tid = threadIdx.x, l = tid & 63, w = tid >> 6;
  int wm = w >> 1, wn = w & 1;
  int kg = l >> 4;
  int tok0 = blockIdx.x * 128, oct = blockIdx.y;
  int b = tok0 >> 12;
  int aoff[4], boff[4];
  #pragma unroll
  for (int r = 0; r < 4; ++r) {
    int m = wm * 64 + r * 16 + (l & 15);
    aoff[r] = m * 32 + ((kg ^ f4(m)) << 3);
    int o = wn * 64 + r * 16 + (l & 15);
    boff[r] = o * 32 + ((kg ^ f4(o)) << 3);
  }
  f32x4 acc[4][4];
  #pragma unroll
  for (int r = 0; r < 4; ++r)
    #pragma unroll
    for (int jt = 0; jt < 4; ++jt)
      acc[r][jt] = (f32x4){0.f, 0.f, 0.f, 0.f};
  for (int k0 = 0; k0 < 8; ++k0) {
    __syncthreads();
    #pragma unroll
    for (int it = 0; it < 2; ++it) {
      int slot = it * 256 + tid;
      int row = slot >> 2, cp = slot & 3;
      int cig = cp ^ f4(row);
      g2l16(cvo + ((size_t)(tok0 + row) * 256 + k0 * 32 + cig * 8),
            &At[(it * 256 + (tid & 192)) * 8]);
    }
    const u16* qb = w8p + ((size_t)(oct * 8 + k0) << 12);
    #pragma unroll
    for (int it = 0; it < 2; ++it)
      g2l16(qb + (it * 256 + tid) * 8, &Bt[(it * 256 + (tid & 192)) * 8]);
    __syncthreads();
    short8_t av[4], bv[4];
    #pragma unroll
    for (int r = 0; r < 4; ++r) av[r] = *(const short8_t*)&At[aoff[r]];
    #pragma unroll
    for (int jt = 0; jt < 4; ++jt) bv[jt] = *(const short8_t*)&Bt[boff[jt]];
    #pragma unroll
    for (int r = 0; r < 4; ++r)
      #pragma unroll
      for (int jt = 0; jt < 4; ++jt)
        acc[r][jt] = __builtin_amdgcn_mfma_f32_16x16x32_bf16(av[r], bv[jt], acc[r][jt], 0, 0, 0);
  }
  #pragma unroll
  for (int r = 0; r < 4; ++r) {
    int tokl = wm * 64 + r * 16 + ((l >> 4) << 2);
    #pragma unroll
    for (int jt = 0; jt < 4; ++jt) {
      int ocl = wn * 64 + jt * 16 + (l & 15);
      *(float4*)&Ts[ocl * 132 + tokl] =
          (float4){acc[r][jt][0], acc[r][jt][1], acc[r][jt][2], acc[r][jt][3]};
    }
  }
  __syncthreads();
  int n0l = tok0 & 4095;
  #pragma unroll
  for (int i = 0; i < 16; ++i) {
    int s = i * 256 + tid;
    int row = s >> 5;
    int c4 = (s & 31) * 4;
    int oc = oct * 128 + row;
    size_t base = ((size_t)(b * 256 + oc)) * 4096 + n0l + c4;
    ushort4 s4 = *(const ushort4*)&skip[base];
    float bias = b8[oc];
    const float* tp = &Ts[row * 132 + c4];
    float4 o4;
    o4.x = bf2f(s4.x) + bias + tp[0];
    o4.y = bf2f(s4.y) + bias + tp[1];
    o4.z = bf2f(s4.z) + bias + tp[2];
    o4.w = bf2f(s4.w) + bias + tp[3];
    *(float4*)&out[base] = o4;
  }
}

extern "C" void kernel_launch(void* const* d_in, const int* in_sizes, int n_in,
                              void* d_out, int out_size, void* d_ws, size_t ws_size,
                              hipStream_t stream) {
  const float* x       = (const float*)d_in[0];
  const float* gamma   = (const float*)d_in[1];
  const float* ln_w    = (const float*)d_in[2];
  const float* ln_b    = (const float*)d_in[3];
  const float* qkvv_w  = (const float*)d_in[4];
  const float* ef_w    = (const float*)d_in[5];
  const float* ef_b    = (const float*)d_in[6];
  const float* temp    = (const float*)d_in[7];
  const float* temp2   = (const float*)d_in[8];
  const float* op1_w   = (const float*)d_in[9];
  const float* op1_b   = (const float*)d_in[10];
  const float* op2_w   = (const float*)d_in[11];
  const float* op2_b   = (const float*)d_in[12];
  const float* conv1_w = (const float*)d_in[13];
  const float* bn1_w   = (const float*)d_in[14];
  const float* bn1_b   = (const float*)d_in[15];
  const float* conv2_w = (const float*)d_in[16];
  const float* bn2_w   = (const float*)d_in[17];
  const float* bn2_b   = (const float*)d_in[18];
  const float* conv8_w = (const float*)d_in[19];
  const float* conv8_b = (const float*)d_in[20];

  float* ws = (float*)d_ws;
  const size_t M1 = 1u << 20;
  u16*   askip  = (u16*)ws;                  // 0..2M floats as bf16 CF (4.19M elems = 8MB)
  u16*   apack1 = (u16*)(ws + 8 * M1);       // 3.54MB (prepack..conv2; no alias)
  u16*   apack2 = (u16*)(ws + 10 * M1);      // 3.54MB
  u16*   xt1    = (u16*)(ws + 16 * M1);      // CL bf16 (2M floats)
  u16*   xnb    = (u16*)(ws + 18 * M1);      // ln..gemm (ends 20M)
  u16*   xsa_b  = (u16*)(ws + 18 * M1);      // attnsa..opcatm (aliases dead xnb)
  float* Spp    = ws + 19 * M1;              // attnca..xca
  float* kvpart = ws + 20 * M1;              // kvproj..attnsa (1M floats)
  u16*   xca_b  = (u16*)(ws + 22 * M1);      // xca..opcatm
  u16*   cvo    = (u16*)(ws + 22 * M1);      // bn2fuse..conv8m (xca_b dead)
  u16*   qct    = (u16*)(ws + 24 * M1);      // gemm..attnsa
  u16*   c1o    = (u16*)(ws + 26 * M1);      // conv phase (qct dead)
  u16*   ht     = (u16*)(ws + 28 * M1);
  u16*   c2o    = (u16*)(ws + 30 * M1);
  float* sm     = ws + 32 * M1;
  float* sbuf   = sm;                        // 2048 (zeroed; gemm atomics)
  float* bnacc  = sm + 2048;                 // 1024 (zeroed; conv BN atomics)
  float* zgu_f  = sm + 3072;                 // 128 (zeroed; conv halo guard)
  u16*   zgu    = (u16*)zgu_f;
  u16*   qpack  = (u16*)(sm + 3200);                   // 512KB
  u16*   efpack = (u16*)(sm + 3200 + 131072);          // 512KB
  u16*   w8pack = (u16*)(sm + 3200 + 262144);          // 128KB
  u16*   oppack = (u16*)(sm + 3200 + 294912);          // 128KB

  k_pre_ln<<<dim3(1601), 256, 0, stream>>>(x, ln_w, ln_b, qkvv_w, conv8_w, op1_w, op2_w,
                                           ef_w, conv1_w, conv2_w,
                                           xnb, qpack, w8pack, oppack, efpack,
                                           apack1, apack2, sm);
  k_gemm<<<dim3(128, 8), 256, 0, stream>>>(xnb, qpack, qct, sbuf);
  k_kvproj_m<<<dim3(4, 4, 4), 256, 0, stream>>>(qct, efpack, kvpart);
  k_attnca_p<<<dim3(32, 8), 256, 0, stream>>>(qct, Spp);
  k_xca<<<dim3(32, 8, 4), 256, 0, stream>>>(qct, Spp, sbuf, temp, xca_b);
  k_attnsa<<<dim3(16, 8, 4), 256, 0, stream>>>(qct, kvpart, ef_b, sbuf, temp2, xsa_b);
  k_opcatm<<<dim3(128, 2), 256, 0, stream>>>(xsa_b, xca_b, x, gamma, oppack, op1_b, op2_b, askip, xt1);
  k_conv3m<<<dim3(512), 256, 0, stream>>>(xt1, apack1, zgu, c1o, bnacc, bnacc + 256);
  k_bnelt<<<dim3(256), 256, 0, stream>>>(c1o, bnacc, bnacc + 256, bn1_w, bn1_b, ht);
  k_conv3m<<<dim3(512), 256, 0, stream>>>(ht, apack2, zgu, c2o, bnacc + 512, bnacc + 768);
  k_bn2fuse<<<dim3(128, 4), 256, 0, stream>>>(c2o, askip, bnacc + 512, bnacc + 768, bn2_w, bn2_b, cvo);
  k_conv8m<<<dim3(128, 2), 256, 0, stream>>>(cvo, w8pack, conv8_b, askip, (float*)d_out);
}

// Round 14
// 307.723 us; speedup vs baseline: 1.1261x; 1.0461x over previous
//
#include <hip/hip_runtime.h>

#define B_ 4
#define C_ 256
#define N_ 4096

typedef unsigned short u16;
typedef __attribute__((ext_vector_type(8))) short short8_t;
typedef __attribute__((ext_vector_type(4))) float f32x4;

__device__ __forceinline__ u16 bf16r(float f) {
  unsigned u = __float_as_uint(f);
  return (u16)((u + 0x7FFFu + ((u >> 16) & 1u)) >> 16);
}
__device__ __forceinline__ float bf2f(u16 u) {
  return __uint_as_float(((unsigned)u) << 16);
}

__device__ __forceinline__ void g2l16(const u16* g, u16* l) {
  __builtin_amdgcn_global_load_lds((const __attribute__((address_space(1))) void*)g,
                                   (__attribute__((address_space(3))) void*)l, 16, 0, 0);
}

__device__ __forceinline__ int f4(int x) { return (x ^ (x >> 2)) & 3; }

// ---------------- merged: prepack (blocks 0..1087) + LayerNorm (1088..1599) + zerofill (1600) ----------------
__global__ __launch_bounds__(256) void k_pre_ln(const float* __restrict__ x,
                                                const float* __restrict__ ln_w,
                                                const float* __restrict__ ln_b,
                                                const float* __restrict__ qkvv_w,
                                                const float* __restrict__ conv8_w,
                                                const float* __restrict__ op1_w,
                                                const float* __restrict__ op2_w,
                                                const float* __restrict__ ef_w,
                                                const float* __restrict__ conv1_w,
                                                const float* __restrict__ conv2_w,
                                                u16* __restrict__ xnb,
                                                u16* __restrict__ qpack,
                                                u16* __restrict__ w8pack,
                                                u16* __restrict__ oppack,
                                                u16* __restrict__ efpack,
                                                u16* __restrict__ apack1,
                                                u16* __restrict__ apack2,
                                                float* __restrict__ zbuf) {
  __shared__ float tile[32][260];
  __shared__ float s_mu[32], s_rs[32];
  int bid = blockIdx.x, tid = threadIdx.x;
  if (bid < 96) {
    const float* w; u16* dst; int tile_;
    if (bid < 64)      { w = qkvv_w;  dst = qpack;          tile_ = bid; }
    else if (bid < 80) { w = conv8_w; dst = w8pack;         tile_ = bid - 64; }
    else if (bid < 88) { w = op1_w;   dst = oppack;         tile_ = bid - 80; }
    else               { w = op2_w;   dst = oppack + 32768; tile_ = bid - 88; }
    int k0 = tile_ & 7, ot = tile_ >> 3;
    u16* td = dst + (size_t)tile_ * 4096;
    int m = tid >> 1, kb = (tid & 1) * 16, fm = f4(m);
    #pragma unroll
    for (int j = 0; j < 16; ++j) {
      int k = kb + j;
      float v = w[(size_t)(ot * 128 + m) * 256 + k0 * 32 + k];
      td[m * 32 + (((k >> 3) ^ fm) << 3) + (k & 7)] = bf16r(v);
    }
  } else if (bid < 224) {
    int k0 = bid - 96;
    int m = tid & 63, kq = tid >> 6, fm = f4(m);
    u16* td = efpack + (size_t)k0 * 2048;
    #pragma unroll
    for (int kk = 0; kk < 8; ++kk) {
      int k = kq * 8 + kk;
      td[m * 32 + (((k >> 3) ^ fm) << 3) + (k & 7)] = bf16r(ef_w[(size_t)m * 4096 + k0 * 32 + k]);
    }
  } else if (bid < 1088) {
    int t = bid - 224;
    const float* w = (t < 432) ? conv1_w : conv2_w;
    u16* dst = (t < 432) ? apack1 : apack2;
    int tile_ = (t < 432) ? t : t - 432;
    int tap = tile_ % 27; int tmp = tile_ / 27;
    int k0 = tmp & 7; int ot = tmp >> 3;
    u16* td = dst + (size_t)tile_ * 4096;
    int m = tid >> 1, kb = (tid & 1) * 16;
    #pragma unroll
    for (int j = 0; j < 16; ++j) {
      int k = kb + j;
      float v = w[((size_t)(ot * 128 + m) * 256 + k0 * 32 + k) * 27 + tap];
      td[m * 32 + k] = bf16r(v);
    }
  } else if (bid < 1600) {
    int lb = bid - 1088;
    int b = lb >> 7, n0 = (lb & 127) * 32;
    for (int idx = tid; idx < 32 * 256; idx += 256) {
      int nl = idx & 31, c = idx >> 5;
      tile[nl][c] = x[((size_t)(b * C_ + c)) * N_ + n0 + nl];
    }
    __syncthreads();
    int token = tid >> 3, sub = tid & 7;
    float s = 0.f, sq = 0.f;
    for (int j = 0; j < 32; ++j) {
      float v = tile[token][sub + j * 8];
      s += v; sq += v * v;
    }
    for (int o = 1; o < 8; o <<= 1) { s += __shfl_xor(s, o); sq += __shfl_xor(sq, o); }
    if (sub == 0) {
      float mu = s * (1.f / 256.f);
      float var = sq * (1.f / 256.f) - mu * mu;
      s_mu[token] = mu;
      s_rs[token] = rsqrtf(var + 1e-5f);
    }
    __syncthreads();
    int c = tid;
    float lw = ln_w[c], lb2 = ln_b[c];
    for (int k = 0; k < 32; ++k) {
      float v = (tile[k][c] - s_mu[k]) * s_rs[k] * lw + lb2;
      xnb[((size_t)(b * N_ + n0 + k)) * 256 + c] = bf16r(v);
    }
  } else {
    for (int i = tid; i < 3200; i += 256) zbuf[i] = 0.f;
  }
}

// ---------------- qkvv GEMM -> qct bf16 [b][cc][n] (LDS-transposed write) + sumsq ----------------
__global__ __launch_bounds__(256) void k_gemm(const u16* __restrict__ xnb,
                                              const u16* __restrict__ qpack,
                                              u16* __restrict__ qct,
                                              float* __restrict__ sbuf) {
  __shared__ alignas(16) u16 At[4096];
  __shared__ alignas(16) u16 Bt[4096];
  __shared__ alignas(16) u16 Tt[128 * 136];  // transpose staging, 34.8 KB
  int tid = threadIdx.x, l = tid & 63, w = tid >> 6;
  int wm = w >> 1, wn = w & 1;
  int kg = l >> 4;
  int tok0 = blockIdx.x * 128, oct = blockIdx.y;
  int b = tok0 >> 12;
  int aoff[4], boff[4];
  #pragma unroll
  for (int r = 0; r < 4; ++r) {
    int m = wm * 64 + r * 16 + (l & 15);
    aoff[r] = m * 32 + ((kg ^ f4(m)) << 3);
    int o = wn * 64 + r * 16 + (l & 15);
    boff[r] = o * 32 + ((kg ^ f4(o)) << 3);
  }
  f32x4 acc[4][4];
  #pragma unroll
  for (int r = 0; r < 4; ++r)
    #pragma unroll
    for (int jt = 0; jt < 4; ++jt)
      acc[r][jt] = (f32x4){0.f, 0.f, 0.f, 0.f};
  for (int k0 = 0; k0 < 8; ++k0) {
    __syncthreads();
    #pragma unroll
    for (int it = 0; it < 2; ++it) {
      int slot = it * 256 + tid;
      int row = slot >> 2, cp = slot & 3;
      int cig = cp ^ f4(row);
      g2l16(xnb + ((size_t)(tok0 + row) * 256 + k0 * 32 + cig * 8),
            &At[(it * 256 + (tid & 192)) * 8]);
    }
    const u16* qb = qpack + ((size_t)(oct * 8 + k0) << 12);
    #pragma unroll
    for (int it = 0; it < 2; ++it)
      g2l16(qb + (it * 256 + tid) * 8, &Bt[(it * 256 + (tid & 192)) * 8]);
    __syncthreads();
    short8_t av[4], bv[4];
    #pragma unroll
    for (int r = 0; r < 4; ++r) av[r] = *(const short8_t*)&At[aoff[r]];
    #pragma unroll
    for (int jt = 0; jt < 4; ++jt) bv[jt] = *(const short8_t*)&Bt[boff[jt]];
    #pragma unroll
    for (int r = 0; r < 4; ++r)
      #pragma unroll
      for (int jt = 0; jt < 4; ++jt)
        acc[r][jt] = __builtin_amdgcn_mfma_f32_16x16x32_bf16(av[r], bv[jt], acc[r][jt], 0, 0, 0);
  }
  // sumsq for q,k (oct<4)
  if (oct < 4) {
    #pragma unroll
    for (int jt = 0; jt < 4; ++jt) {
      float ss = 0.f;
      #pragma unroll
      for (int r = 0; r < 4; ++r)
        #pragma unroll
        for (int reg = 0; reg < 4; ++reg)
          ss += acc[r][jt][reg] * acc[r][jt][reg];
      ss += __shfl_xor(ss, 16);
      ss += __shfl_xor(ss, 32);
      if ((l >> 4) == 0) {
        int oc = oct * 128 + wn * 64 + jt * 16 + (l & 15);
        atomicAdd(&sbuf[(oc >> 8) * 1024 + b * 256 + (oc & 255)], ss);
      }
    }
  }
  // transpose via LDS: Tt[ocl][tokl]
  #pragma unroll
  for (int r = 0; r < 4; ++r) {
    int tokl = wm * 64 + r * 16 + ((l >> 4) << 2);
    #pragma unroll
    for (int jt = 0; jt < 4; ++jt) {
      int ocl = wn * 64 + jt * 16 + (l & 15);
      ushort4 h4;
      h4.x = bf16r(acc[r][jt][0]);
      h4.y = bf16r(acc[r][jt][1]);
      h4.z = bf16r(acc[r][jt][2]);
      h4.w = bf16r(acc[r][jt][3]);
      *(ushort4*)&Tt[ocl * 136 + tokl] = h4;
    }
  }
  __syncthreads();
  int n0 = tok0 & 4095;
  #pragma unroll
  for (int i = 0; i < 8; ++i) {
    int s = i * 256 + tid;
    int row = s >> 4;
    int col = (s & 15) * 8;
    *(int4*)&qct[((size_t)(b * 1024 + oct * 128 + row)) * 4096 + n0 + col] =
        *(const int4*)&Tt[row * 136 + col];
  }
}

// ---------------- kproj/vproj MFMA GEMM, 64-row quarters, grid (8,4,4) = 256 blocks (1/CU) ----------------
// R13 used 64 blocks (75% of CUs idle). Same total work, same kvpart layout; rows split 128->64.
__global__ __launch_bounds__(256) void k_kvproj_m(const u16* __restrict__ qct,
                                                  const u16* __restrict__ efp,
                                                  float* __restrict__ kvpart) {
  __shared__ alignas(16) u16 At[8192];   // 64 rows x 128 k
  __shared__ alignas(16) u16 Bt[8192];
  int tid = threadIdx.x, l = tid & 63, w = tid >> 6;
  int mt = blockIdx.x, b = blockIdx.y, kz = blockIdx.z;
  int kv = mt >> 2, q = mt & 3;
  int ccb = (kv ? 768 : 256) + q * 64;
  int kg = l >> 4;
  int aoff, boff[4];
  {
    int m = w * 16 + (l & 15);
    aoff = m * 32 + ((kg ^ f4(m)) << 3);
  }
  #pragma unroll
  for (int jt = 0; jt < 4; ++jt) {
    int o = jt * 16 + (l & 15);
    boff[jt] = o * 32 + ((kg ^ f4(o)) << 3);
  }
  f32x4 acc[4];
  #pragma unroll
  for (int jt = 0; jt < 4; ++jt) acc[jt] = (f32x4){0.f, 0.f, 0.f, 0.f};
  for (int k0 = kz * 8; k0 < kz * 8 + 8; ++k0) {
    __syncthreads();
    // At: 64 rows x 128 k: 1024 slots; slot = sub*256 + r*4 + cp
    #pragma unroll
    for (int it = 0; it < 4; ++it) {
      int slot = it * 256 + tid;
      int sub = slot >> 8, r = (slot >> 2) & 63, cp = slot & 3;
      g2l16(qct + ((size_t)(b * 1024 + ccb + r)) * 4096 + k0 * 128 + sub * 32 + ((cp ^ f4(r)) << 3),
            &At[(it * 256 + (tid & 192)) * 8]);
    }
    #pragma unroll
    for (int it = 0; it < 4; ++it) {
      int slot = it * 256 + tid;
      g2l16(efp + (size_t)k0 * 8192 + slot * 8, &Bt[(it * 256 + (tid & 192)) * 8]);
    }
    __syncthreads();
    #pragma unroll
    for (int sub = 0; sub < 4; ++sub) {
      short8_t av = *(const short8_t*)&At[sub * 2048 + aoff];
      short8_t bv[4];
      #pragma unroll
      for (int jt = 0; jt < 4; ++jt) bv[jt] = *(const short8_t*)&Bt[sub * 2048 + boff[jt]];
      #pragma unroll
      for (int jt = 0; jt < 4; ++jt)
        acc[jt] = __builtin_amdgcn_mfma_f32_16x16x32_bf16(av, bv[jt], acc[jt], 0, 0, 0);
    }
  }
  float* outd = kvpart + (size_t)kv * 524288 + (size_t)kz * 131072;
  #pragma unroll
  for (int jt = 0; jt < 4; ++jt) {
    int p = jt * 16 + (l & 15);
    #pragma unroll
    for (int reg = 0; reg < 4; ++reg) {
      int cc = q * 64 + w * 16 + (kg << 2) + reg;
      outd[((size_t)(b * 8 + (cc >> 5))) * 2048 + (cc & 31) * 64 + p] = acc[jt][reg];
    }
  }
}

// ---------------- channel attention pass 1: MFMA S = Q.K^T partials (non-atomic) ----------------
// Replaces the VALU 512-deep dot-product version. Fragment conventions identical to k_gemm
// (A/B: lane&15=row, lane>>4=k-chunk of 8; D: col=lane&15, row=(lane>>4)*4+reg, m89-verified).
// Per block (bh,ns): 4 waves each cover 128 n (4 k-iters of 32); 4-wave reduce via LDS (stride 33).
__global__ __launch_bounds__(256) void k_attnca_p(const u16* __restrict__ qct,
                                                  float* __restrict__ Spp) {
  __shared__ float ld[4224];   // 4 waves x 32 x 33
  int bh = blockIdx.x, ns = blockIdx.y;
  int b = bh >> 3, h = bh & 7;
  int tid = threadIdx.x, l = tid & 63, w = tid >> 6;
  int row = l & 15, kg = l >> 4;
  int n0 = ns * 512 + w * 128;
  const u16* qbase = qct + ((size_t)(b * 1024 + h * 32 + row)) * 4096 + n0 + kg * 8;
  const u16* kbase = qct + ((size_t)(b * 1024 + 256 + h * 32 + row)) * 4096 + n0 + kg * 8;
  f32x4 acc[2][2];
  #pragma unroll
  for (int qt = 0; qt < 2; ++qt)
    #pragma unroll
    for (int et = 0; et < 2; ++et) acc[qt][et] = (f32x4){0.f, 0.f, 0.f, 0.f};
  #pragma unroll
  for (int ki = 0; ki < 4; ++ki) {
    short8_t aq0 = *(const short8_t*)(qbase + ki * 32);
    short8_t aq1 = *(const short8_t*)(qbase + (size_t)16 * 4096 + ki * 32);
    short8_t bk0 = *(const short8_t*)(kbase + ki * 32);
    short8_t bk1 = *(const short8_t*)(kbase + (size_t)16 * 4096 + ki * 32);
    acc[0][0] = __builtin_amdgcn_mfma_f32_16x16x32_bf16(aq0, bk0, acc[0][0], 0, 0, 0);
    acc[0][1] = __builtin_amdgcn_mfma_f32_16x16x32_bf16(aq0, bk1, acc[0][1], 0, 0, 0);
    acc[1][0] = __builtin_amdgcn_mfma_f32_16x16x32_bf16(aq1, bk0, acc[1][0], 0, 0, 0);
    acc[1][1] = __builtin_amdgcn_mfma_f32_16x16x32_bf16(aq1, bk1, acc[1][1], 0, 0, 0);
  }
  // partials -> LDS: ld[w][q = qt*16 + kg*4 + reg][e = et*16 + row]
  #pragma unroll
  for (int qt = 0; qt < 2; ++qt)
    #pragma unroll
    for (int et = 0; et < 2; ++et)
      #pragma unroll
      for (int r = 0; r < 4; ++r)
        ld[w * 1056 + (qt * 16 + kg * 4 + r) * 33 + et * 16 + row] = acc[qt][et][r];
  __syncthreads();
  // 4-wave reduce + coalesced float4 write (same Spp layout as before)
  {
    int idx4 = tid * 4;
    int qq = idx4 >> 5, e0 = idx4 & 31;
    float s0 = 0.f, s1 = 0.f, s2 = 0.f, s3 = 0.f;
    #pragma unroll
    for (int ww = 0; ww < 4; ++ww) {
      const float* p = &ld[ww * 1056 + qq * 33 + e0];
      s0 += p[0]; s1 += p[1]; s2 += p[2]; s3 += p[3];
    }
    float4 o4 = {s0, s1, s2, s3};
    *(float4*)&Spp[(size_t)ns * 32768 + (size_t)bh * 1024 + idx4] = o4;
  }
}

// ---------------- x_ca = softmax(S) @ v_ca -> xca_b bf16 CL (casm fused) ----------------
__global__ __launch_bounds__(256) void k_xca(const u16* __restrict__ qct,
                                             const float* __restrict__ Spp,
                                             const float* __restrict__ sbuf,
                                             const float* __restrict__ temp,
                                             u16* __restrict__ xca_b) {
  __shared__ float A[32][33];
  __shared__ float vt[32][129];
  int n0 = blockIdx.x * 128;
  int h = blockIdx.y, b = blockIdx.z;
  int bh = b * 8 + h;
  int tid = threadIdx.x;
  if (tid < 32) {
    float qiv = 1.f / fmaxf(sqrtf(sbuf[b * 256 + h * 32 + tid]), 1e-12f);
    float tmp = temp[h];
    float vals[32];
    #pragma unroll
    for (int e = 0; e < 32; ++e) vals[e] = 0.f;
    for (int ns = 0; ns < 8; ++ns) {
      const float* sp = Spp + (size_t)ns * 32768 + (size_t)bh * 1024 + tid * 32;
      #pragma unroll
      for (int e4 = 0; e4 < 32; e4 += 4) {
        float4 v4 = *(const float4*)&sp[e4];
        vals[e4] += v4.x; vals[e4 + 1] += v4.y;
        vals[e4 + 2] += v4.z; vals[e4 + 3] += v4.w;
      }
    }
    float mx = -1e30f;
    #pragma unroll
    for (int e = 0; e < 32; ++e) {
      float kiv = 1.f / fmaxf(sqrtf(sbuf[1024 + b * 256 + h * 32 + e]), 1e-12f);
      float s = vals[e] * qiv * kiv * tmp;
      vals[e] = s;
      mx = fmaxf(mx, s);
    }
    float ssum = 0.f;
    #pragma unroll
    for (int e = 0; e < 32; ++e) { vals[e] = __expf(vals[e] - mx); ssum += vals[e]; }
    float is = 1.f / ssum;
    #pragma unroll
    for (int e = 0; e < 32; ++e) A[tid][e] = vals[e] * is;
  }
  int e = tid >> 3, ns = (tid & 7) * 16;
  const u16* src = qct + ((size_t)(b * 1024 + 512 + h * 32 + e)) * 4096 + n0 + ns;
  #pragma unroll
  for (int j4 = 0; j4 < 16; j4 += 4) {
    ushort4 u = *(const ushort4*)&src[j4];
    vt[e][ns + j4] = bf2f(u.x);
    vt[e][ns + j4 + 1] = bf2f(u.y);
    vt[e][ns + j4 + 2] = bf2f(u.z);
    vt[e][ns + j4 + 3] = bf2f(u.w);
  }
  __syncthreads();
  int nl = tid & 127, dg = (tid >> 7) * 16;
  float acc[16] = {};
  for (int ee = 0; ee < 32; ++ee) {
    float v = vt[ee][nl];
    #pragma unroll
    for (int j = 0; j < 16; ++j) acc[j] += A[dg + j][ee] * v;
  }
  u16* outp = xca_b + ((size_t)(b * N_ + n0 + nl)) * 256 + h * 32 + dg;
  #pragma unroll
  for (int j = 0; j < 16; ++j) outp[j] = bf16r(acc[j]);
}

// ---------------- spatial attention -> xsa bf16 (kvred + rsq fused into staging) ----------------
__global__ __launch_bounds__(256) void k_attnsa(const u16* __restrict__ qct,
                                                const float* __restrict__ kvpart,
                                                const float* __restrict__ ef_b,
                                                const float* __restrict__ sbuf,
                                                const float* __restrict__ temp2,
                                                u16* __restrict__ xsa_b) {
  __shared__ float kp[32][64], vp[32][64], qi[32];
  __shared__ u16 qt[32][260];
  __shared__ float ot[32][257];
  int bx = blockIdx.x;
  int h = blockIdx.y, b = blockIdx.z;
  int bh = b * 8 + h;
  int tid = threadIdx.x;
  for (int idx = tid; idx < 2048; idx += 256) {
    float bias = ef_b[idx & 63];
    float kpv = bias, vpv = bias;
    size_t base = (size_t)bh * 2048 + idx;
    #pragma unroll
    for (int kz = 0; kz < 4; ++kz) {
      kpv += kvpart[(size_t)kz * 131072 + base];
      vpv += kvpart[524288 + (size_t)kz * 131072 + base];
    }
    kp[idx >> 6][idx & 63] = kpv;
    vp[idx >> 6][idx & 63] = vpv;
  }
  if (tid < 32) qi[tid] = 1.f / fmaxf(sqrtf(sbuf[b * 256 + h * 32 + tid]), 1e-12f);
  {
    int row = tid >> 3, ch = (tid & 7) * 32;
    const u16* src = qct + ((size_t)(b * 1024 + h * 32 + row)) * 4096 + bx * 256 + ch;
    *(int4*)&qt[row][ch] = *(const int4*)&src[0];
    *(int4*)&qt[row][ch + 8] = *(const int4*)&src[8];
    *(int4*)&qt[row][ch + 16] = *(const int4*)&src[16];
    *(int4*)&qt[row][ch + 24] = *(const int4*)&src[24];
  }
  __syncthreads();
  float q[32];
  #pragma unroll
  for (int d = 0; d < 32; ++d) q[d] = bf2f(qt[d][tid]) * qi[d];
  float t2 = temp2[h];
  float l[64];
  #pragma unroll
  for (int p = 0; p < 64; ++p) {
    float s = 0;
    #pragma unroll
    for (int d = 0; d < 32; ++d) s += q[d] * kp[d][p];
    l[p] = s * t2;
  }
  float m = -1e30f;
  #pragma unroll
  for (int p = 0; p < 64; ++p) m = fmaxf(m, l[p]);
  float ssum = 0;
  #pragma unroll
  for (int p = 0; p < 64; ++p) { l[p] = __expf(l[p] - m); ssum += l[p]; }
  float is = 1.f / ssum;
  float o[32] = {};
  #pragma unroll
  for (int p = 0; p < 64; ++p) {
    float wv = l[p] * is;
    #pragma unroll
    for (int d = 0; d < 32; ++d) o[d] += wv * vp[d][p];
  }
  #pragma unroll
  for (int d = 0; d < 32; ++d) ot[d][tid] = o[d];
  __syncthreads();
  #pragma unroll
  for (int i = 0; i < 4; ++i) {
    int s = i * 256 + tid;
    int d = s >> 5;
    int c0 = (s & 31) * 8;
    ushort4 u0, u1;
    u0.x = bf16r(ot[d][c0]);     u0.y = bf16r(ot[d][c0 + 1]);
    u0.z = bf16r(ot[d][c0 + 2]); u0.w = bf16r(ot[d][c0 + 3]);
    u1.x = bf16r(ot[d][c0 + 4]); u1.y = bf16r(ot[d][c0 + 5]);
    u1.z = bf16r(ot[d][c0 + 6]); u1.w = bf16r(ot[d][c0 + 7]);
    u16* dst = xsa_b + (size_t)b * N_ * 256 + (size_t)(d * 128 + h * 16 + bx) * 256 + c0;
    *(ushort4*)&dst[0] = u0;
    *(ushort4*)&dst[4] = u1;
  }
}

// ---------------- op1/op2 MFMA GEMM + gamma residual -> askip CF bf16 + xt1 CL bf16 ----------------
__global__ __launch_bounds__(256) void k_opcatm(const u16* __restrict__ xsa_b,
                                                const u16* __restrict__ xca_b,
                                                const float* __restrict__ x,
                                                const float* __restrict__ gamma,
                                                const u16* __restrict__ oppack,
                                                const float* __restrict__ op1_b,
                                                const float* __restrict__ op2_b,
                                                u16* __restrict__ attn_skip,
                                                u16* __restrict__ xt1) {
  __shared__ alignas(16) u16 At[4096];
  __shared__ alignas(16) u16 Bt[4096];
  __shared__ alignas(16) float Ttf[128 * 133];
  __shared__ alignas(16) u16 rb[128 * 136];
  int tid = threadIdx.x, l = tid & 63, w = tid >> 6;
  int wm = w >> 1, wn = w & 1;
  int kg = l >> 4;
  int tok0 = blockIdx.x * 128, oct = blockIdx.y;
  int b = tok0 >> 12;
  const u16* src = oct ? xca_b : xsa_b;
  int aoff[4], boff[4];
  #pragma unroll
  for (int r = 0; r < 4; ++r) {
    int m = wm * 64 + r * 16 + (l & 15);
    aoff[r] = m * 32 + ((kg ^ f4(m)) << 3);
    int o = wn * 64 + r * 16 + (l & 15);
    boff[r] = o * 32 + ((kg ^ f4(o)) << 3);
  }
  f32x4 acc[4][4];
  #pragma unroll
  for (int r = 0; r < 4; ++r)
    #pragma unroll
    for (int jt = 0; jt < 4; ++jt)
      acc[r][jt] = (f32x4){0.f, 0.f, 0.f, 0.f};
  for (int k0 = 0; k0 < 8; ++k0) {
    __syncthreads();
    #pragma unroll
    for (int it = 0; it < 2; ++it) {
      int slot = it * 256 + tid;
      int row = slot >> 2, cp = slot & 3;
      int cig = cp ^ f4(row);
      g2l16(src + ((size_t)(tok0 + row) * 256 + k0 * 32 + cig * 8),
            &At[(it * 256 + (tid & 192)) * 8]);
    }
    const u16* qb = oppack + ((size_t)(oct * 8 + k0) << 12);
    #pragma unroll
    for (int it = 0; it < 2; ++it)
      g2l16(qb + (it * 256 + tid) * 8, &Bt[(it * 256 + (tid & 192)) * 8]);
    __syncthreads();
    short8_t av[4], bv[4];
    #pragma unroll
    for (int r = 0; r < 4; ++r) av[r] = *(const short8_t*)&At[aoff[r]];
    #pragma unroll
    for (int jt = 0; jt < 4; ++jt) bv[jt] = *(const short8_t*)&Bt[boff[jt]];
    #pragma unroll
    for (int r = 0; r < 4; ++r)
      #pragma unroll
      for (int jt = 0; jt < 4; ++jt)
        acc[r][jt] = __builtin_amdgcn_mfma_f32_16x16x32_bf16(av[r], bv[jt], acc[r][jt], 0, 0, 0);
  }
  // epilogue 1: acc -> Ttf[ocl][tokl] (f32, stride 133)
  #pragma unroll
  for (int r = 0; r < 4; ++r) {
    int tokl = wm * 64 + r * 16 + ((l >> 4) << 2);
    #pragma unroll
    for (int jt = 0; jt < 4; ++jt) {
      int ocl = wn * 64 + jt * 16 + (l & 15);
      float* tp = &Ttf[ocl * 133 + tokl];
      tp[0] = acc[r][jt][0];
      tp[1] = acc[r][jt][1];
      tp[2] = acc[r][jt][2];
      tp[3] = acc[r][jt][3];
    }
  }
  __syncthreads();
  // epilogue 2a: coalesced x read + residual; bf16 askip write; store v back into Ttf
  {
    int n0l = tok0 & 4095;
    #pragma unroll
    for (int i = 0; i < 16; ++i) {
      int s = i * 256 + tid;
      int cl = s >> 5;
      int t4 = (s & 31) * 4;
      int c = oct * 128 + cl;
      float g = gamma[c];
      float bias = oct ? op2_b[cl] : op1_b[cl];
      size_t base = ((size_t)(b * 256 + c)) * 4096 + n0l + t4;
      float4 x4 = *(const float4*)&x[base];
      float* tp = &Ttf[cl * 133 + t4];
      float4 o4;
      o4.x = x4.x + g * (tp[0] + bias);
      o4.y = x4.y + g * (tp[1] + bias);
      o4.z = x4.z + g * (tp[2] + bias);
      o4.w = x4.w + g * (tp[3] + bias);
      ushort4 h4;
      h4.x = bf16r(o4.x); h4.y = bf16r(o4.y);
      h4.z = bf16r(o4.z); h4.w = bf16r(o4.w);
      *(ushort4*)&attn_skip[base] = h4;
      tp[0] = o4.x; tp[1] = o4.y; tp[2] = o4.z; tp[3] = o4.w;
    }
  }
  __syncthreads();
  // epilogue 2b: stage bf16 from Ttf -> rb
  {
    int cl = tid & 127, th = tid >> 7;
    const float* tp = &Ttf[cl * 133 + th * 64];
    #pragma unroll
    for (int t = 0; t < 64; ++t)
      rb[(th * 64 + t) * 136 + cl] = bf16r(tp[t]);
  }
  __syncthreads();
  // epilogue 3: xt1 coalesced int4
  {
    int n0l = tok0 & 4095;
    #pragma unroll
    for (int i = 0; i < 8; ++i) {
      int s = i * 256 + tid;
      int row = s >> 4;
      int c0 = (s & 15) * 8;
      *(int4*)&xt1[((size_t)(b * N_ + n0l + row)) * 256 + oct * 128 + c0] =
          *(const int4*)&rb[row * 136 + c0];
    }
  }
}

// ---------------- split-K MFMA conv 3x3x3 (channels-last output), deep-ring + dbuf ----------------
// Frozen structure: conflicts/ILP/occupancy-x2 all proven null; setprio kept (R6: removal +15%).
__global__ __launch_bounds__(256, 2) void k_conv3m(const u16* __restrict__ xt,
                                                   const u16* __restrict__ apack,
                                                   const u16* __restrict__ zg,
                                                   u16* __restrict__ out,
                                                   float* __restrict__ bnsum,
                                                   float* __restrict__ bnsq) {
  __shared__ alignas(16) u16 Xs[2][2][8192];   // [ks][dbuf][16KB]
  int tid = threadIdx.x, l = tid & 63, w = tid >> 6;
  int wm = w & 1, ks = w >> 1;
  int kg = l >> 4;
  int bid = blockIdx.x;
  int cot = bid & 1;
  int sb = (bid >> 1) & 63;
  int b = bid >> 7;
  int h0 = ((sb >> 4) & 3) << 2, w0 = ((sb >> 2) & 3) << 2, d0 = (sb & 3) << 2;

  int cellc[4];
  {
    int cl = l & 15;
    int wv = (cl >> 2) & 3, dv = cl & 3;
    #pragma unroll
    for (int jt = 0; jt < 4; ++jt)
      cellc[jt] = (jt + 1) * 168 + (wv + 1) * 28 + kg * 6 + (dv + 1);
  }
  const int alane = (wm * 64 + (l & 15)) * 32 + kg * 8;

  const u16* xp[4];
  unsigned okm = 0;
  #pragma unroll
  for (int i = 0; i < 4; ++i) {
    int slot = i * 256 + tid;
    int hh = slot / 168;
    int r = slot - hh * 168;
    int ww = r / 28;
    int r2 = r - ww * 28;
    int kk = r2 / 6;
    int dd = r2 - kk * 6;
    int gh = h0 + hh - 1, gw = w0 + ww - 1, gd = d0 + dd - 1;
    bool ok = (hh < 6) && (kk < 4) &&
              ((unsigned)gh < 16u) && ((unsigned)gw < 16u) && ((unsigned)gd < 16u);
    xp[i] = ok ? (xt + ((size_t)(b * N_ + gh * 256 + gw * 16 + gd)) * 256 + kk * 8) : zg;
    okm |= ((unsigned)ok) << i;
  }

  f32x4 acc[4][4];
  #pragma unroll
  for (int r = 0; r < 4; ++r)
    #pragma unroll
    for (int jt = 0; jt < 4; ++jt)
      acc[r][jt] = (f32x4){0.f, 0.f, 0.f, 0.f};

  #pragma unroll
  for (int bk = 0; bk < 2; ++bk)
    #pragma unroll
    for (int i = 0; i < 4; ++i) {
      const u16* p = ((okm >> i) & 1) ? (xp[i] + ((bk * 4) << 5)) : zg;
      g2l16(p, &Xs[bk][0][(i * 256 + (tid & 192)) * 8]);
    }
  __syncthreads();

  short8_t av[4][4], bv[3][4];

#define CONV_TAP(t)                                                                   \
  do {                                                                                \
    if ((t) < 24) {                                                                   \
      const int tnA = (t) + 3;                                                        \
      _Pragma("unroll")                                                               \
      for (int r = 0; r < 4; ++r)                                                     \
        av[tnA & 3][r] = *(const short8_t*)(at + tnA * 4096 + r * 512);               \
    }                                                                                 \
    if ((t) < 25) {                                                                   \
      const int tnB = (t) + 2;                                                        \
      const int dh = tnB / 9, rr_ = tnB - dh * 9, dw = rr_ / 3, dd2 = rr_ - dw * 3;   \
      const int OFF = (dh - 1) * 168 + (dw - 1) * 28 + (dd2 - 1);                     \
      _Pragma("unroll")                                                               \
      for (int jt = 0; jt < 4; ++jt)                                                  \
        bv[tnB % 3][jt] = *(const short8_t*)&Xb[(cellc[jt] + OFF) * 8];               \
    }                                                                                 \
    __builtin_amdgcn_s_setprio(1);                                                    \
    _Pragma("unroll")                                                                 \
    for (int r = 0; r < 4; ++r)                                                       \
      _Pragma("unroll")                                                               \
      for (int jt = 0; jt < 4; ++jt)                                                  \
        acc[r][jt] = __builtin_amdgcn_mfma_f32_16x16x32_bf16(av[(t) & 3][r],          \
                         bv[(t) % 3][jt], acc[r][jt], 0, 0, 0);                       \
    __builtin_amdgcn_s_setprio(0);                                                    \
  } while (0)

  #pragma unroll 1
  for (int step = 0; step < 4; ++step) {
    const int cur = step & 1;
    const u16* Xb = &Xs[ks][cur][0];
    const int ci0 = ks * 4 + step;
    const u16* at = apack + ((size_t)((cot * 8 + ci0) * 27)) * 4096 + alane;
    #pragma unroll
    for (int r = 0; r < 4; ++r) av[0][r] = *(const short8_t*)(at + r * 512);
    #pragma unroll
    for (int r = 0; r < 4; ++r) av[1][r] = *(const short8_t*)(at + 4096 + r * 512);
    #pragma unroll
    for (int r = 0; r < 4; ++r) av[2][r] = *(const short8_t*)(at + 8192 + r * 512);
    #pragma unroll
    for (int jt = 0; jt < 4; ++jt) {
      bv[0][jt] = *(const short8_t*)&Xb[(cellc[jt] - 197) * 8];
      bv[1][jt] = *(const short8_t*)&Xb[(cellc[jt] - 196) * 8];
    }
    #pragma unroll
    for (int t = 0; t < 4; ++t) CONV_TAP(t);
    if (step < 3) {
      const int nd = (step + 1) & 1;
      #pragma unroll
      for (int bk = 0; bk < 2; ++bk)
        #pragma unroll
        for (int i = 0; i < 4; ++i) {
          const u16* p = ((okm >> i) & 1) ? (xp[i] + ((bk * 4 + step + 1) << 5)) : zg;
          g2l16(p, &Xs[bk][nd][(i * 256 + (tid & 192)) * 8]);
        }
    }
    #pragma unroll
    for (int t = 4; t < 27; ++t) CONV_TAP(t);
    __syncthreads();
  }
#undef CONV_TAP

  f32x4* red = (f32x4*)&Xs[0][0][0];
  if (ks == 1) {
    #pragma unroll
    for (int r = 0; r < 4; ++r)
      #pragma unroll
      for (int jt = 0; jt < 4; ++jt)
        red[(r * 4 + jt) * 128 + wm * 64 + l] = acc[r][jt];
  }
  __syncthreads();
  if (ks == 0) {
    #pragma unroll
    for (int r = 0; r < 4; ++r)
      #pragma unroll
      for (int jt = 0; jt < 4; ++jt) {
        f32x4 o = red[(r * 4 + jt) * 128 + wm * 64 + l];
        acc[r][jt][0] += o[0]; acc[r][jt][1] += o[1];
        acc[r][jt][2] += o[2]; acc[r][jt][3] += o[3];
      }
    #pragma unroll
    for (int r = 0; r < 4; ++r) {
      int co = cot * 128 + wm * 64 + r * 16 + ((l >> 4) << 2);
      #pragma unroll
      for (int reg = 0; reg < 4; ++reg) {
        float sv = 0.f, qv = 0.f;
        #pragma unroll
        for (int jt = 0; jt < 4; ++jt) {
          float v = acc[r][jt][reg];
          sv += v; qv += v * v;
        }
        #pragma unroll
        for (int o = 1; o < 16; o <<= 1) {
          sv += __shfl_xor(sv, o);
          qv += __shfl_xor(qv, o);
        }
        if ((l & 15) == 0) {
          atomicAdd(&bnsum[co + reg], sv);
          atomicAdd(&bnsq[co + reg], qv);
        }
      }
      #pragma unroll
      for (int jt = 0; jt < 4; ++jt) {
        int c = jt * 16 + (l & 15);
        int n = (h0 + (c >> 4)) * 256 + (w0 + ((c >> 2) & 3)) * 16 + (d0 + (c & 3));
        ushort4 h4;
        h4.x = bf16r(acc[r][jt][0]);
        h4.y = bf16r(acc[r][jt][1]);
        h4.z = bf16r(acc[r][jt][2]);
        h4.w = bf16r(acc[r][jt][3]);
        *(ushort4*)&out[((size_t)(b * N_ + n)) * 256 + co] = h4;
      }
    }
  }
}

// ---------------- BN apply + LeakyReLU, CL elementwise (bnfin fused) ----------------
__global__ __launch_bounds__(256) void k_bnelt(const u16* __restrict__ src,
                                               const float* __restrict__ bnsum,
                                               const float* __restrict__ bnsq,
                                               const float* __restrict__ w,
                                               const float* __restrict__ bb,
                                               u16* __restrict__ dst) {
  __shared__ float sc[256], sh[256];
  int tid = threadIdx.x;
  float m = bnsum[tid] * (1.f / 16384.f);
  float var = bnsq[tid] * (1.f / 16384.f) - m * m;
  float rstd = rsqrtf(var + 1e-5f);
  float scv = rstd * w[tid];
  sc[tid] = scv;
  sh[tid] = bb[tid] - m * scv;
  __syncthreads();
  size_t base = (size_t)blockIdx.x * 64 * 256;
  #pragma unroll
  for (int i = 0; i < 8; ++i) {
    int s = i * 256 + tid;
    int c0 = (s & 31) * 8;
    size_t off = base + (size_t)(s >> 5) * 256 + c0;
    int4 v4 = *(const int4*)&src[off];
    u16* pu = (u16*)&v4;
    #pragma unroll
    for (int j = 0; j < 8; ++j) {
      float v = bf2f(pu[j]) * sc[c0 + j] + sh[c0 + j];
      pu[j] = bf16r(v >= 0.f ? v : 0.01f * v);
    }
    *(int4*)&dst[off] = v4;
  }
}

// ---------------- BN2 + skip + lrelu -> cvo bf16 CL (bnfin fused; bf16 askip staged) ----------------
__global__ __launch_bounds__(256) void k_bn2fuse(const u16* __restrict__ c2o,
                                                 const u16* __restrict__ askip,
                                                 const float* __restrict__ bnsum,
                                                 const float* __restrict__ bnsq,
                                                 const float* __restrict__ bnw,
                                                 const float* __restrict__ bnb,
                                                 u16* __restrict__ cvo) {
  __shared__ float sc[256], sh[256];
  __shared__ float at_[32][260];
  int n0 = blockIdx.x * 32, b = blockIdx.y, tid = threadIdx.x;
  float m = bnsum[tid] * (1.f / 16384.f);
  float var = bnsq[tid] * (1.f / 16384.f) - m * m;
  float rstd = rsqrtf(var + 1e-5f);
  float scv = rstd * bnw[tid];
  sc[tid] = scv;
  sh[tid] = bnb[tid] - m * scv;
  #pragma unroll
  for (int i = 0; i < 8; ++i) {
    int s = i * 256 + tid;
    int c = s >> 3;
    int t4 = (s & 7) * 4;
    ushort4 a4 = *(const ushort4*)&askip[((size_t)(b * 256 + c)) * 4096 + n0 + t4];
    at_[t4 + 0][c] = bf2f(a4.x);
    at_[t4 + 1][c] = bf2f(a4.y);
    at_[t4 + 2][c] = bf2f(a4.z);
    at_[t4 + 3][c] = bf2f(a4.w);
  }
  __syncthreads();
  #pragma unroll
  for (int i = 0; i < 4; ++i) {
    int s = i * 256 + tid;
    int row = s >> 5, c0 = (s & 31) * 8;
    size_t off = ((size_t)(b * N_ + n0 + row)) * 256 + c0;
    int4 v4 = *(const int4*)&c2o[off];
    u16* pu = (u16*)&v4;
    #pragma unroll
    for (int j = 0; j < 8; ++j) {
      int c = c0 + j;
      float v = bf2f(pu[j]) * sc[c] + sh[c] + at_[row][c];
      pu[j] = bf16r(v >= 0.f ? v : 0.01f * v);
    }
    *(int4*)&cvo[off] = v4;
  }
}

// ---------------- conv8 MFMA GEMM + bias + bf16 skip -> d_out CF, LDS-transposed epilogue ----------------
__global__ __launch_bounds__(256) void k_conv8m(const u16* __restrict__ cvo,
                                                const u16* __restrict__ w8p,
                                                const float* __restrict__ b8,
                                                const u16* __restrict__ skip,
                                                float* __restrict__ out) {
  __shared__ alignas(16) u16 At[4096];
  __shared__ alignas(16) u16 Bt[4096];
  __shared__ alignas(16) float Ts[128 * 132];
  int tid = threadIdx.x, l = tid & 63, w = tid >> 6;
  int wm = w >> 1, wn = w & 1;
  int kg = l >> 4;
  int tok0 = blockIdx.x * 128, oct = blockIdx.y;
  int b = tok0 >> 12;
  int aoff[4], boff[4];
  #pragma unroll
  for (int r = 0; r < 4; ++r) {
    int m = wm * 64 + r * 16 + (l & 15);
    aoff[r] = m * 32 + ((kg ^ f4(m)) << 3);
    int o = wn * 64 + r * 16 + (l & 15);
    boff[r] = o * 32 + ((kg ^ f4(o)) << 3);
  }
  f32x4 acc[4][4];
  #pragma unroll
  for (int r = 0; r < 4; ++r)
    #pragma unroll
    for (int jt = 0; jt < 4; ++jt)
      acc[r][jt] = (f32x4){0.f, 0.f, 0.f, 0.f};
  for (int k0 = 0; k0 < 8; ++k0) {
    __syncthreads();
    #pragma unroll
    for (int it = 0; it < 2; ++it) {
      int slot = it * 256 + tid;
      int row = slot >> 2, cp = slot & 3;
      int cig = cp ^ f4(row);
      g2l16(cvo + ((size_t)(tok0 + row) * 256 + k0 * 32 + cig * 8),
            &At[(it * 256 + (tid & 192)) * 8]);
    }
    const u16* qb = w8p + ((size_t)(oct * 8 + k0) << 12);
    #pragma unroll
    for (int it = 0; it < 2; ++it)
      g2l16(qb + (it * 256 + tid) * 8, &Bt[(it * 256 + (tid & 192)) * 8]);
    __syncthreads();
    short8_t av[4], bv[4];
    #pragma unroll
    for (int r = 0; r < 4; ++r) av[r] = *(const short8_t*)&At[aoff[r]];
    #pragma unroll
    for (int jt = 0; jt < 4; ++jt) bv[jt] = *(const short8_t*)&Bt[boff[jt]];
    #pragma unroll
    for (int r = 0; r < 4; ++r)
      #pragma unroll
      for (int jt = 0; jt < 4; ++jt)
        acc[r][jt] = __builtin_amdgcn_mfma_f32_16x16x32_bf16(av[r], bv[jt], acc[r][jt], 0, 0, 0);
  }
  #pragma unroll
  for (int r = 0; r < 4; ++r) {
    int tokl = wm * 64 + r * 16 + ((l >> 4) << 2);
    #pragma unroll
    for (int jt = 0; jt < 4; ++jt) {
      int ocl = wn * 64 + jt * 16 + (l & 15);
      *(float4*)&Ts[ocl * 132 + tokl] =
          (float4){acc[r][jt][0], acc[r][jt][1], acc[r][jt][2], acc[r][jt][3]};
    }
  }
  __syncthreads();
  int n0l = tok0 & 4095;
  #pragma unroll
  for (int i = 0; i < 16; ++i) {
    int s = i * 256 + tid;
    int row = s >> 5;
    int c4 = (s & 31) * 4;
    int oc = oct * 128 + row;
    size_t base = ((size_t)(b * 256 + oc)) * 4096 + n0l + c4;
    ushort4 s4 = *(const ushort4*)&skip[base];
    float bias = b8[oc];
    const float* tp = &Ts[row * 132 + c4];
    float4 o4;
    o4.x = bf2f(s4.x) + bias + tp[0];
    o4.y = bf2f(s4.y) + bias + tp[1];
    o4.z = bf2f(s4.z) + bias + tp[2];
    o4.w = bf2f(s4.w) + bias + tp[3];
    *(float4*)&out[base] = o4;
  }
}

extern "C" void kernel_launch(void* const* d_in, const int* in_sizes, int n_in,
                              void* d_out, int out_size, void* d_ws, size_t ws_size,
                              hipStream_t stream) {
  const float* x       = (const float*)d_in[0];
  const float* gamma   = (const float*)d_in[1];
  const float* ln_w    = (const float*)d_in[2];
  const float* ln_b    = (const float*)d_in[3];
  const float* qkvv_w  = (const float*)d_in[4];
  const float* ef_w    = (const float*)d_in[5];
  const float* ef_b    = (const float*)d_in[6];
  const float* temp    = (const float*)d_in[7];
  const float* temp2   = (const float*)d_in[8];
  const float* op1_w   = (const float*)d_in[9];
  const float* op1_b   = (const float*)d_in[10];
  const float* op2_w   = (const float*)d_in[11];
  const float* op2_b   = (const float*)d_in[12];
  const float* conv1_w = (const float*)d_in[13];
  const float* bn1_w   = (const float*)d_in[14];
  const float* bn1_b   = (const float*)d_in[15];
  const float* conv2_w = (const float*)d_in[16];
  const float* bn2_w   = (const float*)d_in[17];
  const float* bn2_b   = (const float*)d_in[18];
  const float* conv8_w = (const float*)d_in[19];
  const float* conv8_b = (const float*)d_in[20];

  float* ws = (float*)d_ws;
  const size_t M1 = 1u << 20;
  u16*   askip  = (u16*)ws;                  // bf16 CF (8 MB)
  u16*   apack1 = (u16*)(ws + 8 * M1);
  u16*   apack2 = (u16*)(ws + 10 * M1);
  u16*   xt1    = (u16*)(ws + 16 * M1);
  u16*   xnb    = (u16*)(ws + 18 * M1);      // ln..gemm (ends 20M)
  u16*   xsa_b  = (u16*)(ws + 18 * M1);      // attnsa..opcatm (aliases dead xnb)
  float* Spp    = ws + 19 * M1;              // attnca..xca
  float* kvpart = ws + 20 * M1;              // kvproj..attnsa (1M floats)
  u16*   xca_b  = (u16*)(ws + 22 * M1);
  u16*   cvo    = (u16*)(ws + 22 * M1);
  u16*   qct    = (u16*)(ws + 24 * M1);
  u16*   c1o    = (u16*)(ws + 26 * M1);
  u16*   ht     = (u16*)(ws + 28 * M1);
  u16*   c2o    = (u16*)(ws + 30 * M1);
  float* sm     = ws + 32 * M1;
  float* sbuf   = sm;                        // 2048 (zeroed)
  float* bnacc  = sm + 2048;                 // 1024 (zeroed)
  float* zgu_f  = sm + 3072;                 // 128 (zeroed)
  u16*   zgu    = (u16*)zgu_f;
  u16*   qpack  = (u16*)(sm + 3200);
  u16*   efpack = (u16*)(sm + 3200 + 131072);
  u16*   w8pack = (u16*)(sm + 3200 + 262144);
  u16*   oppack = (u16*)(sm + 3200 + 294912);

  k_pre_ln<<<dim3(1601), 256, 0, stream>>>(x, ln_w, ln_b, qkvv_w, conv8_w, op1_w, op2_w,
                                           ef_w, conv1_w, conv2_w,
                                           xnb, qpack, w8pack, oppack, efpack,
                                           apack1, apack2, sm);
  k_gemm<<<dim3(128, 8), 256, 0, stream>>>(xnb, qpack, qct, sbuf);
  k_kvproj_m<<<dim3(8, 4, 4), 256, 0, stream>>>(qct, efpack, kvpart);
  k_attnca_p<<<dim3(32, 8), 256, 0, stream>>>(qct, Spp);
  k_xca<<<dim3(32, 8, 4), 256, 0, stream>>>(qct, Spp, sbuf, temp, xca_b);
  k_attnsa<<<dim3(16, 8, 4), 256, 0, stream>>>(qct, kvpart, ef_b, sbuf, temp2, xsa_b);
  k_opcatm<<<dim3(128, 2), 256, 0, stream>>>(xsa_b, xca_b, x, gamma, oppack, op1_b, op2_b, askip, xt1);
  k_conv3m<<<dim3(512), 256, 0, stream>>>(xt1, apack1, zgu, c1o, bnacc, bnacc + 256);
  k_bnelt<<<dim3(256), 256, 0, stream>>>(c1o, bnacc, bnacc + 256, bn1_w, bn1_b, ht);
  k_conv3m<<<dim3(512), 256, 0, stream>>>(ht, apack2, zgu, c2o, bnacc + 512, bnacc + 768);
  k_bn2fuse<<<dim3(128, 4), 256, 0, stream>>>(c2o, askip, bnacc + 512, bnacc + 768, bn2_w, bn2_b, cvo);
  k_conv8m<<<dim3(128, 2), 256, 0, stream>>>(cvo, w8pack, conv8_b, askip, (float*)d_out);
}

// Round 15
// 303.001 us; speedup vs baseline: 1.1437x; 1.0156x over previous
//
#include <hip/hip_runtime.h>

#define B_ 4
#define C_ 256
#define N_ 4096

typedef unsigned short u16;
typedef __attribute__((ext_vector_type(8))) short short8_t;
typedef __attribute__((ext_vector_type(4))) float f32x4;

__device__ __forceinline__ u16 bf16r(float f) {
  unsigned u = __float_as_uint(f);
  return (u16)((u + 0x7FFFu + ((u >> 16) & 1u)) >> 16);
}
__device__ __forceinline__ float bf2f(u16 u) {
  return __uint_as_float(((unsigned)u) << 16);
}

__device__ __forceinline__ void g2l16(const u16* g, u16* l) {
  __builtin_amdgcn_global_load_lds((const __attribute__((address_space(1))) void*)g,
                                   (__attribute__((address_space(3))) void*)l, 16, 0, 0);
}

__device__ __forceinline__ int f4(int x) { return (x ^ (x >> 2)) & 3; }

// ---------------- merged: prepack (blocks 0..1087) + LayerNorm (1088..1599) + zerofill (1600) ----------------
__global__ __launch_bounds__(256) void k_pre_ln(const float* __restrict__ x,
                                                const float* __restrict__ ln_w,
                                                const float* __restrict__ ln_b,
                                                const float* __restrict__ qkvv_w,
                                                const float* __restrict__ conv8_w,
                                                const float* __restrict__ op1_w,
                                                const float* __restrict__ op2_w,
                                                const float* __restrict__ ef_w,
                                                const float* __restrict__ conv1_w,
                                                const float* __restrict__ conv2_w,
                                                u16* __restrict__ xnb,
                                                u16* __restrict__ qpack,
                                                u16* __restrict__ w8pack,
                                                u16* __restrict__ oppack,
                                                u16* __restrict__ efpack,
                                                u16* __restrict__ apack1,
                                                u16* __restrict__ apack2,
                                                float* __restrict__ zbuf) {
  __shared__ float tile[32][260];
  __shared__ float s_mu[32], s_rs[32];
  int bid = blockIdx.x, tid = threadIdx.x;
  if (bid < 96) {
    const float* w; u16* dst; int tile_;
    if (bid < 64)      { w = qkvv_w;  dst = qpack;          tile_ = bid; }
    else if (bid < 80) { w = conv8_w; dst = w8pack;         tile_ = bid - 64; }
    else if (bid < 88) { w = op1_w;   dst = oppack;         tile_ = bid - 80; }
    else               { w = op2_w;   dst = oppack + 32768; tile_ = bid - 88; }
    int k0 = tile_ & 7, ot = tile_ >> 3;
    u16* td = dst + (size_t)tile_ * 4096;
    int m = tid >> 1, kb = (tid & 1) * 16, fm = f4(m);
    #pragma unroll
    for (int j = 0; j < 16; ++j) {
      int k = kb + j;
      float v = w[(size_t)(ot * 128 + m) * 256 + k0 * 32 + k];
      td[m * 32 + (((k >> 3) ^ fm) << 3) + (k & 7)] = bf16r(v);
    }
  } else if (bid < 224) {
    int k0 = bid - 96;
    int m = tid & 63, kq = tid >> 6, fm = f4(m);
    u16* td = efpack + (size_t)k0 * 2048;
    #pragma unroll
    for (int kk = 0; kk < 8; ++kk) {
      int k = kq * 8 + kk;
      td[m * 32 + (((k >> 3) ^ fm) << 3) + (k & 7)] = bf16r(ef_w[(size_t)m * 4096 + k0 * 32 + k]);
    }
  } else if (bid < 1088) {
    int t = bid - 224;
    const float* w = (t < 432) ? conv1_w : conv2_w;
    u16* dst = (t < 432) ? apack1 : apack2;
    int tile_ = (t < 432) ? t : t - 432;
    int tap = tile_ % 27; int tmp = tile_ / 27;
    int k0 = tmp & 7; int ot = tmp >> 3;
    u16* td = dst + (size_t)tile_ * 4096;
    int m = tid >> 1, kb = (tid & 1) * 16;
    #pragma unroll
    for (int j = 0; j < 16; ++j) {
      int k = kb + j;
      float v = w[((size_t)(ot * 128 + m) * 256 + k0 * 32 + k) * 27 + tap];
      td[m * 32 + k] = bf16r(v);
    }
  } else if (bid < 1600) {
    int lb = bid - 1088;
    int b = lb >> 7, n0 = (lb & 127) * 32;
    for (int idx = tid; idx < 32 * 256; idx += 256) {
      int nl = idx & 31, c = idx >> 5;
      tile[nl][c] = x[((size_t)(b * C_ + c)) * N_ + n0 + nl];
    }
    __syncthreads();
    int token = tid >> 3, sub = tid & 7;
    float s = 0.f, sq = 0.f;
    for (int j = 0; j < 32; ++j) {
      float v = tile[token][sub + j * 8];
      s += v; sq += v * v;
    }
    for (int o = 1; o < 8; o <<= 1) { s += __shfl_xor(s, o); sq += __shfl_xor(sq, o); }
    if (sub == 0) {
      float mu = s * (1.f / 256.f);
      float var = sq * (1.f / 256.f) - mu * mu;
      s_mu[token] = mu;
      s_rs[token] = rsqrtf(var + 1e-5f);
    }
    __syncthreads();
    int c = tid;
    float lw = ln_w[c], lb2 = ln_b[c];
    for (int k = 0; k < 32; ++k) {
      float v = (tile[k][c] - s_mu[k]) * s_rs[k] * lw + lb2;
      xnb[((size_t)(b * N_ + n0 + k)) * 256 + c] = bf16r(v);
    }
  } else {
    for (int i = tid; i < 3200; i += 256) zbuf[i] = 0.f;
  }
}

// ---------------- qkvv GEMM -> qct bf16 [b][cc][n] (LDS-transposed write) + sumsq ----------------
__global__ __launch_bounds__(256) void k_gemm(const u16* __restrict__ xnb,
                                              const u16* __restrict__ qpack,
                                              u16* __restrict__ qct,
                                              float* __restrict__ sbuf) {
  __shared__ alignas(16) u16 At[4096];
  __shared__ alignas(16) u16 Bt[4096];
  __shared__ alignas(16) u16 Tt[128 * 136];  // transpose staging, 34.8 KB
  int tid = threadIdx.x, l = tid & 63, w = tid >> 6;
  int wm = w >> 1, wn = w & 1;
  int kg = l >> 4;
  int tok0 = blockIdx.x * 128, oct = blockIdx.y;
  int b = tok0 >> 12;
  int aoff[4], boff[4];
  #pragma unroll
  for (int r = 0; r < 4; ++r) {
    int m = wm * 64 + r * 16 + (l & 15);
    aoff[r] = m * 32 + ((kg ^ f4(m)) << 3);
    int o = wn * 64 + r * 16 + (l & 15);
    boff[r] = o * 32 + ((kg ^ f4(o)) << 3);
  }
  f32x4 acc[4][4];
  #pragma unroll
  for (int r = 0; r < 4; ++r)
    #pragma unroll
    for (int jt = 0; jt < 4; ++jt)
      acc[r][jt] = (f32x4){0.f, 0.f, 0.f, 0.f};
  for (int k0 = 0; k0 < 8; ++k0) {
    __syncthreads();
    #pragma unroll
    for (int it = 0; it < 2; ++it) {
      int slot = it * 256 + tid;
      int row = slot >> 2, cp = slot & 3;
      int cig = cp ^ f4(row);
      g2l16(xnb + ((size_t)(tok0 + row) * 256 + k0 * 32 + cig * 8),
            &At[(it * 256 + (tid & 192)) * 8]);
    }
    const u16* qb = qpack + ((size_t)(oct * 8 + k0) << 12);
    #pragma unroll
    for (int it = 0; it < 2; ++it)
      g2l16(qb + (it * 256 + tid) * 8, &Bt[(it * 256 + (tid & 192)) * 8]);
    __syncthreads();
    short8_t av[4], bv[4];
    #pragma unroll
    for (int r = 0; r < 4; ++r) av[r] = *(const short8_t*)&At[aoff[r]];
    #pragma unroll
    for (int jt = 0; jt < 4; ++jt) bv[jt] = *(const short8_t*)&Bt[boff[jt]];
    #pragma unroll
    for (int r = 0; r < 4; ++r)
      #pragma unroll
      for (int jt = 0; jt < 4; ++jt)
        acc[r][jt] = __builtin_amdgcn_mfma_f32_16x16x32_bf16(av[r], bv[jt], acc[r][jt], 0, 0, 0);
  }
  // sumsq for q,k (oct<4)
  if (oct < 4) {
    #pragma unroll
    for (int jt = 0; jt < 4; ++jt) {
      float ss = 0.f;
      #pragma unroll
      for (int r = 0; r < 4; ++r)
        #pragma unroll
        for (int reg = 0; reg < 4; ++reg)
          ss += acc[r][jt][reg] * acc[r][jt][reg];
      ss += __shfl_xor(ss, 16);
      ss += __shfl_xor(ss, 32);
      if ((l >> 4) == 0) {
        int oc = oct * 128 + wn * 64 + jt * 16 + (l & 15);
        atomicAdd(&sbuf[(oc >> 8) * 1024 + b * 256 + (oc & 255)], ss);
      }
    }
  }
  // transpose via LDS: Tt[ocl][tokl]
  #pragma unroll
  for (int r = 0; r < 4; ++r) {
    int tokl = wm * 64 + r * 16 + ((l >> 4) << 2);
    #pragma unroll
    for (int jt = 0; jt < 4; ++jt) {
      int ocl = wn * 64 + jt * 16 + (l & 15);
      ushort4 h4;
      h4.x = bf16r(acc[r][jt][0]);
      h4.y = bf16r(acc[r][jt][1]);
      h4.z = bf16r(acc[r][jt][2]);
      h4.w = bf16r(acc[r][jt][3]);
      *(ushort4*)&Tt[ocl * 136 + tokl] = h4;
    }
  }
  __syncthreads();
  int n0 = tok0 & 4095;
  #pragma unroll
  for (int i = 0; i < 8; ++i) {
    int s = i * 256 + tid;
    int row = s >> 4;
    int col = (s & 15) * 8;
    *(int4*)&qct[((size_t)(b * 1024 + oct * 128 + row)) * 4096 + n0 + col] =
        *(const int4*)&Tt[row * 136 + col];
  }
}

// ---------------- merged: channel-attn MFMA partials (blocks 0..255) + kvproj GEMM (256..383) ----------------
// Safe merge (R11/R12 rule): LDS union = 32 KB (kvproj's own footprint; attnca branch uses 16.9 KB);
// both branches low-VGPR. Both depend only on k_gemm; outputs feed k_xca / k_attnsa respectively.
__global__ __launch_bounds__(256) void k_ca_kv(const u16* __restrict__ qct,
                                               const u16* __restrict__ efp,
                                               float* __restrict__ kvpart,
                                               float* __restrict__ Spp) {
  __shared__ alignas(16) char smem[32768];
  int bid = blockIdx.x, tid = threadIdx.x;
  if (bid < 256) {
    // ---- attnca: S = Q.K^T partials via MFMA (fragment conventions as k_gemm, m89-verified) ----
    float* ld = (float*)smem;   // 4 waves x 32 x 33 = 16896 B
    int bh = bid & 31, ns = bid >> 5;
    int b = bh >> 3, h = bh & 7;
    int l = tid & 63, w = tid >> 6;
    int row = l & 15, kg = l >> 4;
    int n0 = ns * 512 + w * 128;
    const u16* qbase = qct + ((size_t)(b * 1024 + h * 32 + row)) * 4096 + n0 + kg * 8;
    const u16* kbase = qct + ((size_t)(b * 1024 + 256 + h * 32 + row)) * 4096 + n0 + kg * 8;
    f32x4 acc[2][2];
    #pragma unroll
    for (int qt = 0; qt < 2; ++qt)
      #pragma unroll
      for (int et = 0; et < 2; ++et) acc[qt][et] = (f32x4){0.f, 0.f, 0.f, 0.f};
    #pragma unroll
    for (int ki = 0; ki < 4; ++ki) {
      short8_t aq0 = *(const short8_t*)(qbase + ki * 32);
      short8_t aq1 = *(const short8_t*)(qbase + (size_t)16 * 4096 + ki * 32);
      short8_t bk0 = *(const short8_t*)(kbase + ki * 32);
      short8_t bk1 = *(const short8_t*)(kbase + (size_t)16 * 4096 + ki * 32);
      acc[0][0] = __builtin_amdgcn_mfma_f32_16x16x32_bf16(aq0, bk0, acc[0][0], 0, 0, 0);
      acc[0][1] = __builtin_amdgcn_mfma_f32_16x16x32_bf16(aq0, bk1, acc[0][1], 0, 0, 0);
      acc[1][0] = __builtin_amdgcn_mfma_f32_16x16x32_bf16(aq1, bk0, acc[1][0], 0, 0, 0);
      acc[1][1] = __builtin_amdgcn_mfma_f32_16x16x32_bf16(aq1, bk1, acc[1][1], 0, 0, 0);
    }
    #pragma unroll
    for (int qt = 0; qt < 2; ++qt)
      #pragma unroll
      for (int et = 0; et < 2; ++et)
        #pragma unroll
        for (int r = 0; r < 4; ++r)
          ld[w * 1056 + (qt * 16 + kg * 4 + r) * 33 + et * 16 + row] = acc[qt][et][r];
    __syncthreads();
    {
      int idx4 = tid * 4;
      int qq = idx4 >> 5, e0 = idx4 & 31;
      float s0 = 0.f, s1 = 0.f, s2 = 0.f, s3 = 0.f;
      #pragma unroll
      for (int ww = 0; ww < 4; ++ww) {
        const float* p = &ld[ww * 1056 + qq * 33 + e0];
        s0 += p[0]; s1 += p[1]; s2 += p[2]; s3 += p[3];
      }
      float4 o4 = {s0, s1, s2, s3};
      *(float4*)&Spp[(size_t)ns * 32768 + (size_t)bh * 1024 + idx4] = o4;
    }
  } else {
    // ---- kvproj: 64-row quarter GEMM (same body as R14's k_kvproj_m) ----
    u16* At = (u16*)smem;             // 16 KB
    u16* Bt = (u16*)(smem + 16384);   // 16 KB
    int t = bid - 256;
    int mt = t & 7, b = (t >> 3) & 3, kz = t >> 5;
    int l = tid & 63, w = tid >> 6;
    int kv = mt >> 2, q = mt & 3;
    int ccb = (kv ? 768 : 256) + q * 64;
    int kg = l >> 4;
    int aoff, boff[4];
    {
      int m = w * 16 + (l & 15);
      aoff = m * 32 + ((kg ^ f4(m)) << 3);
    }
    #pragma unroll
    for (int jt = 0; jt < 4; ++jt) {
      int o = jt * 16 + (l & 15);
      boff[jt] = o * 32 + ((kg ^ f4(o)) << 3);
    }
    f32x4 acc[4];
    #pragma unroll
    for (int jt = 0; jt < 4; ++jt) acc[jt] = (f32x4){0.f, 0.f, 0.f, 0.f};
    for (int k0 = kz * 8; k0 < kz * 8 + 8; ++k0) {
      __syncthreads();
      #pragma unroll
      for (int it = 0; it < 4; ++it) {
        int slot = it * 256 + tid;
        int sub = slot >> 8, r = (slot >> 2) & 63, cp = slot & 3;
        g2l16(qct + ((size_t)(b * 1024 + ccb + r)) * 4096 + k0 * 128 + sub * 32 + ((cp ^ f4(r)) << 3),
              &At[(it * 256 + (tid & 192)) * 8]);
      }
      #pragma unroll
      for (int it = 0; it < 4; ++it) {
        int slot = it * 256 + tid;
        g2l16(efp + (size_t)k0 * 8192 + slot * 8, &Bt[(it * 256 + (tid & 192)) * 8]);
      }
      __syncthreads();
      #pragma unroll
      for (int sub = 0; sub < 4; ++sub) {
        short8_t av = *(const short8_t*)&At[sub * 2048 + aoff];
        short8_t bv[4];
        #pragma unroll
        for (int jt = 0; jt < 4; ++jt) bv[jt] = *(const short8_t*)&Bt[sub * 2048 + boff[jt]];
        #pragma unroll
        for (int jt = 0; jt < 4; ++jt)
          acc[jt] = __builtin_amdgcn_mfma_f32_16x16x32_bf16(av, bv[jt], acc[jt], 0, 0, 0);
      }
    }
    float* outd = kvpart + (size_t)kv * 524288 + (size_t)kz * 131072;
    #pragma unroll
    for (int jt = 0; jt < 4; ++jt) {
      int p = jt * 16 + (l & 15);
      #pragma unroll
      for (int reg = 0; reg < 4; ++reg) {
        int cc = q * 64 + w * 16 + (kg << 2) + reg;
        outd[((size_t)(b * 8 + (cc >> 5))) * 2048 + (cc & 31) * 64 + p] = acc[jt][reg];
      }
    }
  }
}

// ---------------- x_ca = softmax(S) @ v_ca -> xca_b bf16 CL (casm fused) ----------------
__global__ __launch_bounds__(256) void k_xca(const u16* __restrict__ qct,
                                             const float* __restrict__ Spp,
                                             const float* __restrict__ sbuf,
                                             const float* __restrict__ temp,
                                             u16* __restrict__ xca_b) {
  __shared__ float A[32][33];
  __shared__ float vt[32][129];
  int n0 = blockIdx.x * 128;
  int h = blockIdx.y, b = blockIdx.z;
  int bh = b * 8 + h;
  int tid = threadIdx.x;
  if (tid < 32) {
    float qiv = 1.f / fmaxf(sqrtf(sbuf[b * 256 + h * 32 + tid]), 1e-12f);
    float tmp = temp[h];
    float vals[32];
    #pragma unroll
    for (int e = 0; e < 32; ++e) vals[e] = 0.f;
    for (int ns = 0; ns < 8; ++ns) {
      const float* sp = Spp + (size_t)ns * 32768 + (size_t)bh * 1024 + tid * 32;
      #pragma unroll
      for (int e4 = 0; e4 < 32; e4 += 4) {
        float4 v4 = *(const float4*)&sp[e4];
        vals[e4] += v4.x; vals[e4 + 1] += v4.y;
        vals[e4 + 2] += v4.z; vals[e4 + 3] += v4.w;
      }
    }
    float mx = -1e30f;
    #pragma unroll
    for (int e = 0; e < 32; ++e) {
      float kiv = 1.f / fmaxf(sqrtf(sbuf[1024 + b * 256 + h * 32 + e]), 1e-12f);
      float s = vals[e] * qiv * kiv * tmp;
      vals[e] = s;
      mx = fmaxf(mx, s);
    }
    float ssum = 0.f;
    #pragma unroll
    for (int e = 0; e < 32; ++e) { vals[e] = __expf(vals[e] - mx); ssum += vals[e]; }
    float is = 1.f / ssum;
    #pragma unroll
    for (int e = 0; e < 32; ++e) A[tid][e] = vals[e] * is;
  }
  int e = tid >> 3, ns = (tid & 7) * 16;
  const u16* src = qct + ((size_t)(b * 1024 + 512 + h * 32 + e)) * 4096 + n0 + ns;
  #pragma unroll
  for (int j4 = 0; j4 < 16; j4 += 4) {
    ushort4 u = *(const ushort4*)&src[j4];
    vt[e][ns + j4] = bf2f(u.x);
    vt[e][ns + j4 + 1] = bf2f(u.y);
    vt[e][ns + j4 + 2] = bf2f(u.z);
    vt[e][ns + j4 + 3] = bf2f(u.w);
  }
  __syncthreads();
  int nl = tid & 127, dg = (tid >> 7) * 16;
  float acc[16] = {};
  for (int ee = 0; ee < 32; ++ee) {
    float v = vt[ee][nl];
    #pragma unroll
    for (int j = 0; j < 16; ++j) acc[j] += A[dg + j][ee] * v;
  }
  u16* outp = xca_b + ((size_t)(b * N_ + n0 + nl)) * 256 + h * 32 + dg;
  #pragma unroll
  for (int j = 0; j < 16; ++j) outp[j] = bf16r(acc[j]);
}

// ---------------- spatial attention -> xsa bf16 (kvred + rsq fused; ot OVERLAYS dead kp/vp/qt) ----------------
// LDS 65.6 -> 33.2 KB: ot[32][257] reuses smem[0..32896) after kp/vp/qt are dead (barrier guards
// the transition). Occupancy 2 -> 4 blocks/CU for this latency-heavy kernel.
__global__ __launch_bounds__(256) void k_attnsa(const u16* __restrict__ qct,
                                                const float* __restrict__ kvpart,
                                                const float* __restrict__ ef_b,
                                                const float* __restrict__ sbuf,
                                                const float* __restrict__ temp2,
                                                u16* __restrict__ xsa_b) {
  __shared__ alignas(16) char smem[33152];
  float (*kp)[64] = (float(*)[64])smem;             // 8192 B
  float (*vp)[64] = (float(*)[64])(smem + 8192);    // 8192 B
  float* qi = (float*)(smem + 16384);               // 128 B
  u16 (*qt)[260] = (u16(*)[260])(smem + 16512);     // 16640 B -> ends 33152
  float (*ot)[257] = (float(*)[257])smem;           // 32896 B overlay (kp/vp/qi/qt dead by then)
  int bx = blockIdx.x;
  int h = blockIdx.y, b = blockIdx.z;
  int bh = b * 8 + h;
  int tid = threadIdx.x;
  for (int idx = tid; idx < 2048; idx += 256) {
    float bias = ef_b[idx & 63];
    float kpv = bias, vpv = bias;
    size_t base = (size_t)bh * 2048 + idx;
    #pragma unroll
    for (int kz = 0; kz < 4; ++kz) {
      kpv += kvpart[(size_t)kz * 131072 + base];
      vpv += kvpart[524288 + (size_t)kz * 131072 + base];
    }
    kp[idx >> 6][idx & 63] = kpv;
    vp[idx >> 6][idx & 63] = vpv;
  }
  if (tid < 32) qi[tid] = 1.f / fmaxf(sqrtf(sbuf[b * 256 + h * 32 + tid]), 1e-12f);
  {
    int row = tid >> 3, ch = (tid & 7) * 32;
    const u16* src = qct + ((size_t)(b * 1024 + h * 32 + row)) * 4096 + bx * 256 + ch;
    *(int4*)&qt[row][ch] = *(const int4*)&src[0];
    *(int4*)&qt[row][ch + 8] = *(const int4*)&src[8];
    *(int4*)&qt[row][ch + 16] = *(const int4*)&src[16];
    *(int4*)&qt[row][ch + 24] = *(const int4*)&src[24];
  }
  __syncthreads();
  float q[32];
  #pragma unroll
  for (int d = 0; d < 32; ++d) q[d] = bf2f(qt[d][tid]) * qi[d];
  float t2 = temp2[h];
  float l[64];
  #pragma unroll
  for (int p = 0; p < 64; ++p) {
    float s = 0;
    #pragma unroll
    for (int d = 0; d < 32; ++d) s += q[d] * kp[d][p];
    l[p] = s * t2;
  }
  float m = -1e30f;
  #pragma unroll
  for (int p = 0; p < 64; ++p) m = fmaxf(m, l[p]);
  float ssum = 0;
  #pragma unroll
  for (int p = 0; p < 64; ++p) { l[p] = __expf(l[p] - m); ssum += l[p]; }
  float is = 1.f / ssum;
  float o[32] = {};
  #pragma unroll
  for (int p = 0; p < 64; ++p) {
    float wv = l[p] * is;
    #pragma unroll
    for (int d = 0; d < 32; ++d) o[d] += wv * vp[d][p];
  }
  __syncthreads();   // all kp/vp/qt reads complete before ot overlay writes
  #pragma unroll
  for (int d = 0; d < 32; ++d) ot[d][tid] = o[d];
  __syncthreads();
  #pragma unroll
  for (int i = 0; i < 4; ++i) {
    int s = i * 256 + tid;
    int d = s >> 5;
    int c0 = (s & 31) * 8;
    ushort4 u0, u1;
    u0.x = bf16r(ot[d][c0]);     u0.y = bf16r(ot[d][c0 + 1]);
    u0.z = bf16r(ot[d][c0 + 2]); u0.w = bf16r(ot[d][c0 + 3]);
    u1.x = bf16r(ot[d][c0 + 4]); u1.y = bf16r(ot[d][c0 + 5]);
    u1.z = bf16r(ot[d][c0 + 6]); u1.w = bf16r(ot[d][c0 + 7]);
    u16* dst = xsa_b + (size_t)b * N_ * 256 + (size_t)(d * 128 + h * 16 + bx) * 256 + c0;
    *(ushort4*)&dst[0] = u0;
    *(ushort4*)&dst[4] = u1;
  }
}

// ---------------- op1/op2 MFMA GEMM + gamma residual -> askip CF bf16 + xt1 CL bf16 ----------------
__global__ __launch_bounds__(256) void k_opcatm(const u16* __restrict__ xsa_b,
                                                const u16* __restrict__ xca_b,
                                                const float* __restrict__ x,
                                                const float* __restrict__ gamma,
                                                const u16* __restrict__ oppack,
                                                const float* __restrict__ op1_b,
                                                const float* __restrict__ op2_b,
                                                u16* __restrict__ attn_skip,
                                                u16* __restrict__ xt1) {
  __shared__ alignas(16) u16 At[4096];
  __shared__ alignas(16) u16 Bt[4096];
  __shared__ alignas(16) float Ttf[128 * 133];
  __shared__ alignas(16) u16 rb[128 * 136];
  int tid = threadIdx.x, l = tid & 63, w = tid >> 6;
  int wm = w >> 1, wn = w & 1;
  int kg = l >> 4;
  int tok0 = blockIdx.x * 128, oct = blockIdx.y;
  int b = tok0 >> 12;
  const u16* src = oct ? xca_b : xsa_b;
  int aoff[4], boff[4];
  #pragma unroll
  for (int r = 0; r < 4; ++r) {
    int m = wm * 64 + r * 16 + (l & 15);
    aoff[r] = m * 32 + ((kg ^ f4(m)) << 3);
    int o = wn * 64 + r * 16 + (l & 15);
    boff[r] = o * 32 + ((kg ^ f4(o)) << 3);
  }
  f32x4 acc[4][4];
  #pragma unroll
  for (int r = 0; r < 4; ++r)
    #pragma unroll
    for (int jt = 0; jt < 4; ++jt)
      acc[r][jt] = (f32x4){0.f, 0.f, 0.f, 0.f};
  for (int k0 = 0; k0 < 8; ++k0) {
    __syncthreads();
    #pragma unroll
    for (int it = 0; it < 2; ++it) {
      int slot = it * 256 + tid;
      int row = slot >> 2, cp = slot & 3;
      int cig = cp ^ f4(row);
      g2l16(src + ((size_t)(tok0 + row) * 256 + k0 * 32 + cig * 8),
            &At[(it * 256 + (tid & 192)) * 8]);
    }
    const u16* qb = oppack + ((size_t)(oct * 8 + k0) << 12);
    #pragma unroll
    for (int it = 0; it < 2; ++it)
      g2l16(qb + (it * 256 + tid) * 8, &Bt[(it * 256 + (tid & 192)) * 8]);
    __syncthreads();
    short8_t av[4], bv[4];
    #pragma unroll
    for (int r = 0; r < 4; ++r) av[r] = *(const short8_t*)&At[aoff[r]];
    #pragma unroll
    for (int jt = 0; jt < 4; ++jt) bv[jt] = *(const short8_t*)&Bt[boff[jt]];
    #pragma unroll
    for (int r = 0; r < 4; ++r)
      #pragma unroll
      for (int jt = 0; jt < 4; ++jt)
        acc[r][jt] = __builtin_amdgcn_mfma_f32_16x16x32_bf16(av[r], bv[jt], acc[r][jt], 0, 0, 0);
  }
  // epilogue 1: acc -> Ttf[ocl][tokl] (f32, stride 133)
  #pragma unroll
  for (int r = 0; r < 4; ++r) {
    int tokl = wm * 64 + r * 16 + ((l >> 4) << 2);
    #pragma unroll
    for (int jt = 0; jt < 4; ++jt) {
      int ocl = wn * 64 + jt * 16 + (l & 15);
      float* tp = &Ttf[ocl * 133 + tokl];
      tp[0] = acc[r][jt][0];
      tp[1] = acc[r][jt][1];
      tp[2] = acc[r][jt][2];
      tp[3] = acc[r][jt][3];
    }
  }
  __syncthreads();
  // epilogue 2a: coalesced x read + residual; bf16 askip write; store v back into Ttf
  {
    int n0l = tok0 & 4095;
    #pragma unroll
    for (int i = 0; i < 16; ++i) {
      int s = i * 256 + tid;
      int cl = s >> 5;
      int t4 = (s & 31) * 4;
      int c = oct * 128 + cl;
      float g = gamma[c];
      float bias = oct ? op2_b[cl] : op1_b[cl];
      size_t base = ((size_t)(b * 256 + c)) * 4096 + n0l + t4;
      float4 x4 = *(const float4*)&x[base];
      float* tp = &Ttf[cl * 133 + t4];
      float4 o4;
      o4.x = x4.x + g * (tp[0] + bias);
      o4.y = x4.y + g * (tp[1] + bias);
      o4.z = x4.z + g * (tp[2] + bias);
      o4.w = x4.w + g * (tp[3] + bias);
      ushort4 h4;
      h4.x = bf16r(o4.x); h4.y = bf16r(o4.y);
      h4.z = bf16r(o4.z); h4.w = bf16r(o4.w);
      *(ushort4*)&attn_skip[base] = h4;
      tp[0] = o4.x; tp[1] = o4.y; tp[2] = o4.z; tp[3] = o4.w;
    }
  }
  __syncthreads();
  // epilogue 2b: stage bf16 from Ttf -> rb
  {
    int cl = tid & 127, th = tid >> 7;
    const float* tp = &Ttf[cl * 133 + th * 64];
    #pragma unroll
    for (int t = 0; t < 64; ++t)
      rb[(th * 64 + t) * 136 + cl] = bf16r(tp[t]);
  }
  __syncthreads();
  // epilogue 3: xt1 coalesced int4
  {
    int n0l = tok0 & 4095;
    #pragma unroll
    for (int i = 0; i < 8; ++i) {
      int s = i * 256 + tid;
      int row = s >> 4;
      int c0 = (s & 15) * 8;
      *(int4*)&xt1[((size_t)(b * N_ + n0l + row)) * 256 + oct * 128 + c0] =
          *(const int4*)&rb[row * 136 + c0];
    }
  }
}

// ---------------- split-K MFMA conv 3x3x3 (channels-last output), deep-ring + dbuf ----------------
// Frozen structure: conflicts/ILP/occupancy-x2 all proven null; setprio kept (R6: removal +15%).
__global__ __launch_bounds__(256, 2) void k_conv3m(const u16* __restrict__ xt,
                                                   const u16* __restrict__ apack,
                                                   const u16* __restrict__ zg,
                                                   u16* __restrict__ out,
                                                   float* __restrict__ bnsum,
                                                   float* __restrict__ bnsq) {
  __shared__ alignas(16) u16 Xs[2][2][8192];   // [ks][dbuf][16KB]
  int tid = threadIdx.x, l = tid & 63, w = tid >> 6;
  int wm = w & 1, ks = w >> 1;
  int kg = l >> 4;
  int bid = blockIdx.x;
  int cot = bid & 1;
  int sb = (bid >> 1) & 63;
  int b = bid >> 7;
  int h0 = ((sb >> 4) & 3) << 2, w0 = ((sb >> 2) & 3) << 2, d0 = (sb & 3) << 2;

  int cellc[4];
  {
    int cl = l & 15;
    int wv = (cl >> 2) & 3, dv = cl & 3;
    #pragma unroll
    for (int jt = 0; jt < 4; ++jt)
      cellc[jt] = (jt + 1) * 168 + (wv + 1) * 28 + kg * 6 + (dv + 1);
  }
  const int alane = (wm * 64 + (l & 15)) * 32 + kg * 8;

  const u16* xp[4];
  unsigned okm = 0;
  #pragma unroll
  for (int i = 0; i < 4; ++i) {
    int slot = i * 256 + tid;
    int hh = slot / 168;
    int r = slot - hh * 168;
    int ww = r / 28;
    int r2 = r - ww * 28;
    int kk = r2 / 6;
    int dd = r2 - kk * 6;
    int gh = h0 + hh - 1, gw = w0 + ww - 1, gd = d0 + dd - 1;
    bool ok = (hh < 6) && (kk < 4) &&
              ((unsigned)gh < 16u) && ((unsigned)gw < 16u) && ((unsigned)gd < 16u);
    xp[i] = ok ? (xt + ((size_t)(b * N_ + gh * 256 + gw * 16 + gd)) * 256 + kk * 8) : zg;
    okm |= ((unsigned)ok) << i;
  }

  f32x4 acc[4][4];
  #pragma unroll
  for (int r = 0; r < 4; ++r)
    #pragma unroll
    for (int jt = 0; jt < 4; ++jt)
      acc[r][jt] = (f32x4){0.f, 0.f, 0.f, 0.f};

  #pragma unroll
  for (int bk = 0; bk < 2; ++bk)
    #pragma unroll
    for (int i = 0; i < 4; ++i) {
      const u16* p = ((okm >> i) & 1) ? (xp[i] + ((bk * 4) << 5)) : zg;
      g2l16(p, &Xs[bk][0][(i * 256 + (tid & 192)) * 8]);
    }
  __syncthreads();

  short8_t av[4][4], bv[3][4];

#define CONV_TAP(t)                                                                   \
  do {                                                                                \
    if ((t) < 24) {                                                                   \
      const int tnA = (t) + 3;                                                        \
      _Pragma("unroll")                                                               \
      for (int r = 0; r < 4; ++r)                                                     \
        av[tnA & 3][r] = *(const short8_t*)(at + tnA * 4096 + r * 512);               \
    }                                                                                 \
    if ((t) < 25) {                                                                   \
      const int tnB = (t) + 2;                                                        \
      const int dh = tnB / 9, rr_ = tnB - dh * 9, dw = rr_ / 3, dd2 = rr_ - dw * 3;   \
      const int OFF = (dh - 1) * 168 + (dw - 1) * 28 + (dd2 - 1);                     \
      _Pragma("unroll")                                                               \
      for (int jt = 0; jt < 4; ++jt)                                                  \
        bv[tnB % 3][jt] = *(const short8_t*)&Xb[(cellc[jt] + OFF) * 8];               \
    }                                                                                 \
    __builtin_amdgcn_s_setprio(1);                                                    \
    _Pragma("unroll")                                                                 \
    for (int r = 0; r < 4; ++r)                                                       \
      _Pragma("unroll")                                                               \
      for (int jt = 0; jt < 4; ++jt)                                                  \
        acc[r][jt] = __builtin_amdgcn_mfma_f32_16x16x32_bf16(av[(t) & 3][r],          \
                         bv[(t) % 3][jt], acc[r][jt], 0, 0, 0);                       \
    __builtin_amdgcn_s_setprio(0);                                                    \
  } while (0)

  #pragma unroll 1
  for (int step = 0; step < 4; ++step) {
    const int cur = step & 1;
    const u16* Xb = &Xs[ks][cur][0];
    const int ci0 = ks * 4 + step;
    const u16* at = apack + ((size_t)((cot * 8 + ci0) * 27)) * 4096 + alane;
    #pragma unroll
    for (int r = 0; r < 4; ++r) av[0][r] = *(const short8_t*)(at + r * 512);
    #pragma unroll
    for (int r = 0; r < 4; ++r) av[1][r] = *(const short8_t*)(at + 4096 + r * 512);
    #pragma unroll
    for (int r = 0; r < 4; ++r) av[2][r] = *(const short8_t*)(at + 8192 + r * 512);
    #pragma unroll
    for (int jt = 0; jt < 4; ++jt) {
      bv[0][jt] = *(const short8_t*)&Xb[(cellc[jt] - 197) * 8];
      bv[1][jt] = *(const short8_t*)&Xb[(cellc[jt] - 196) * 8];
    }
    #pragma unroll
    for (int t = 0; t < 4; ++t) CONV_TAP(t);
    if (step < 3) {
      const int nd = (step + 1) & 1;
      #pragma unroll
      for (int bk = 0; bk < 2; ++bk)
        #pragma unroll
        for (int i = 0; i < 4; ++i) {
          const u16* p = ((okm >> i) & 1) ? (xp[i] + ((bk * 4 + step + 1) << 5)) : zg;
          g2l16(p, &Xs[bk][nd][(i * 256 + (tid & 192)) * 8]);
        }
    }
    #pragma unroll
    for (int t = 4; t < 27; ++t) CONV_TAP(t);
    __syncthreads();
  }
#undef CONV_TAP

  f32x4* red = (f32x4*)&Xs[0][0][0];
  if (ks == 1) {
    #pragma unroll
    for (int r = 0; r < 4; ++r)
      #pragma unroll
      for (int jt = 0; jt < 4; ++jt)
        red[(r * 4 + jt) * 128 + wm * 64 + l] = acc[r][jt];
  }
  __syncthreads();
  if (ks == 0) {
    #pragma unroll
    for (int r = 0; r < 4; ++r)
      #pragma unroll
      for (int jt = 0; jt < 4; ++jt) {
        f32x4 o = red[(r * 4 + jt) * 128 + wm * 64 + l];
        acc[r][jt][0] += o[0]; acc[r][jt][1] += o[1];
        acc[r][jt][2] += o[2]; acc[r][jt][3] += o[3];
      }
    #pragma unroll
    for (int r = 0; r < 4; ++r) {
      int co = cot * 128 + wm * 64 + r * 16 + ((l >> 4) << 2);
      #pragma unroll
      for (int reg = 0; reg < 4; ++reg) {
        float sv = 0.f, qv = 0.f;
        #pragma unroll
        for (int jt = 0; jt < 4; ++jt) {
          float v = acc[r][jt][reg];
          sv += v; qv += v * v;
        }
        #pragma unroll
        for (int o = 1; o < 16; o <<= 1) {
          sv += __shfl_xor(sv, o);
          qv += __shfl_xor(qv, o);
        }
        if ((l & 15) == 0) {
          atomicAdd(&bnsum[co + reg], sv);
          atomicAdd(&bnsq[co + reg], qv);
        }
      }
      #pragma unroll
      for (int jt = 0; jt < 4; ++jt) {
        int c = jt * 16 + (l & 15);
        int n = (h0 + (c >> 4)) * 256 + (w0 + ((c >> 2) & 3)) * 16 + (d0 + (c & 3));
        ushort4 h4;
        h4.x = bf16r(acc[r][jt][0]);
        h4.y = bf16r(acc[r][jt][1]);
        h4.z = bf16r(acc[r][jt][2]);
        h4.w = bf16r(acc[r][jt][3]);
        *(ushort4*)&out[((size_t)(b * N_ + n)) * 256 + co] = h4;
      }
    }
  }
}

// ---------------- BN apply + LeakyReLU, CL elementwise (bnfin fused) ----------------
__global__ __launch_bounds__(256) void k_bnelt(const u16* __restrict__ src,
                                               const float* __restrict__ bnsum,
                                               const float* __restrict__ bnsq,
                                               const float* __restrict__ w,
                                               const float* __restrict__ bb,
                                               u16* __restrict__ dst) {
  __shared__ float sc[256], sh[256];
  int tid = threadIdx.x;
  float m = bnsum[tid] * (1.f / 16384.f);
  float var = bnsq[tid] * (1.f / 16384.f) - m * m;
  float rstd = rsqrtf(var + 1e-5f);
  float scv = rstd * w[tid];
  sc[tid] = scv;
  sh[tid] = bb[tid] - m * scv;
  __syncthreads();
  size_t base = (size_t)blockIdx.x * 64 * 256;
  #pragma unroll
  for (int i = 0; i < 8; ++i) {
    int s = i * 256 + tid;
    int c0 = (s & 31) * 8;
    size_t off = base + (size_t)(s >> 5) * 256 + c0;
    int4 v4 = *(const int4*)&src[off];
    u16* pu = (u16*)&v4;
    #pragma unroll
    for (int j = 0; j < 8; ++j) {
      float v = bf2f(pu[j]) * sc[c0 + j] + sh[c0 + j];
      pu[j] = bf16r(v >= 0.f ? v : 0.01f * v);
    }
    *(int4*)&dst[off] = v4;
  }
}

// ---------------- BN2 + skip + lrelu -> cvo bf16 CL (bnfin fused; bf16 askip staged) ----------------
__global__ __launch_bounds__(256) void k_bn2fuse(const u16* __restrict__ c2o,
                                                 const u16* __restrict__ askip,
                                                 const float* __restrict__ bnsum,
                                                 const float* __restrict__ bnsq,
                                                 const float* __restrict__ bnw,
                                                 const float* __restrict__ bnb,
                                                 u16* __restrict__ cvo) {
  __shared__ float sc[256], sh[256];
  __shared__ float at_[32][260];
  int n0 = blockIdx.x * 32, b = blockIdx.y, tid = threadIdx.x;
  float m = bnsum[tid] * (1.f / 16384.f);
  float var = bnsq[tid] * (1.f / 16384.f) - m * m;
  float rstd = rsqrtf(var + 1e-5f);
  float scv = rstd * bnw[tid];
  sc[tid] = scv;
  sh[tid] = bnb[tid] - m * scv;
  #pragma unroll
  for (int i = 0; i < 8; ++i) {
    int s = i * 256 + tid;
    int c = s >> 3;
    int t4 = (s & 7) * 4;
    ushort4 a4 = *(const ushort4*)&askip[((size_t)(b * 256 + c)) * 4096 + n0 + t4];
    at_[t4 + 0][c] = bf2f(a4.x);
    at_[t4 + 1][c] = bf2f(a4.y);
    at_[t4 + 2][c] = bf2f(a4.z);
    at_[t4 + 3][c] = bf2f(a4.w);
  }
  __syncthreads();
  #pragma unroll
  for (int i = 0; i < 4; ++i) {
    int s = i * 256 + tid;
    int row = s >> 5, c0 = (s & 31) * 8;
    size_t off = ((size_t)(b * N_ + n0 + row)) * 256 + c0;
    int4 v4 = *(const int4*)&c2o[off];
    u16* pu = (u16*)&v4;
    #pragma unroll
    for (int j = 0; j < 8; ++j) {
      int c = c0 + j;
      float v = bf2f(pu[j]) * sc[c] + sh[c] + at_[row][c];
      pu[j] = bf16r(v >= 0.f ? v : 0.01f * v);
    }
    *(int4*)&cvo[off] = v4;
  }
}

// ---------------- conv8 MFMA GEMM + bias + bf16 skip -> d_out CF, LDS-transposed epilogue ----------------
__global__ __launch_bounds__(256) void k_conv8m(const u16* __restrict__ cvo,
                                                const u16* __restrict__ w8p,
                                                const float* __restrict__ b8,
                                                const u16* __restrict__ skip,
                                                float* __restrict__ out) {
  __shared__ alignas(16) u16 At[4096];
  __shared__ alignas(16) u16 Bt[4096];
  __shared__ alignas(16) float Ts[128 * 132];
  int tid = threadIdx.x, l = tid & 63, w = tid >> 6;
  int wm = w >> 1, wn = w & 1;
  int kg = l >> 4;
  int tok0 = blockIdx.x * 128, oct = blockIdx.y;
  int b = tok0 >> 12;
  int aoff[4], boff[4];
  #pragma unroll
  for (int r = 0; r < 4; ++r) {
    int m = wm * 64 + r * 16 + (l & 15);
    aoff[r] = m * 32 + ((kg ^ f4(m)) << 3);
    int o = wn * 64 + r * 16 + (l & 15);
    boff[r] = o * 32 + ((kg ^ f4(o)) << 3);
  }
  f32x4 acc[4][4];
  #pragma unroll
  for (int r = 0; r < 4; ++r)
    #pragma unroll
    for (int jt = 0; jt < 4; ++jt)
      acc[r][jt] = (f32x4){0.f, 0.f, 0.f, 0.f};
  for (int k0 = 0; k0 < 8; ++k0) {
    __syncthreads();
    #pragma unroll
    for (int it = 0; it < 2; ++it) {
      int slot = it * 256 + tid;
      int row = slot >> 2, cp = slot & 3;
      int cig = cp ^ f4(row);
      g2l16(cvo + ((size_t)(tok0 + row) * 256 + k0 * 32 + cig * 8),
            &At[(it * 256 + (tid & 192)) * 8]);
    }
    const u16* qb = w8p + ((size_t)(oct * 8 + k0) << 12);
    #pragma unroll
    for (int it = 0; it < 2; ++it)
      g2l16(qb + (it * 256 + tid) * 8, &Bt[(it * 256 + (tid & 192)) * 8]);
    __syncthreads();
    short8_t av[4], bv[4];
    #pragma unroll
    for (int r = 0; r < 4; ++r) av[r] = *(const short8_t*)&At[aoff[r]];
    #pragma unroll
    for (int jt = 0; jt < 4; ++jt) bv[jt] = *(const short8_t*)&Bt[boff[jt]];
    #pragma unroll
    for (int r = 0; r < 4; ++r)
      #pragma unroll
      for (int jt = 0; jt < 4; ++jt)
        acc[r][jt] = __builtin_amdgcn_mfma_f32_16x16x32_bf16(av[r], bv[jt], acc[r][jt], 0, 0, 0);
  }
  #pragma unroll
  for (int r = 0; r < 4; ++r) {
    int tokl = wm * 64 + r * 16 + ((l >> 4) << 2);
    #pragma unroll
    for (int jt = 0; jt < 4; ++jt) {
      int ocl = wn * 64 + jt * 16 + (l & 15);
      *(float4*)&Ts[ocl * 132 + tokl] =
          (float4){acc[r][jt][0], acc[r][jt][1], acc[r][jt][2], acc[r][jt][3]};
    }
  }
  __syncthreads();
  int n0l = tok0 & 4095;
  #pragma unroll
  for (int i = 0; i < 16; ++i) {
    int s = i * 256 + tid;
    int row = s >> 5;
    int c4 = (s & 31) * 4;
    int oc = oct * 128 + row;
    size_t base = ((size_t)(b * 256 + oc)) * 4096 + n0l + c4;
    ushort4 s4 = *(const ushort4*)&skip[base];
    float bias = b8[oc];
    const float* tp = &Ts[row * 132 + c4];
    float4 o4;
    o4.x = bf2f(s4.x) + bias + tp[0];
    o4.y = bf2f(s4.y) + bias + tp[1];
    o4.z = bf2f(s4.z) + bias + tp[2];
    o4.w = bf2f(s4.w) + bias + tp[3];
    *(float4*)&out[base] = o4;
  }
}

extern "C" void kernel_launch(void* const* d_in, const int* in_sizes, int n_in,
                              void* d_out, int out_size, void* d_ws, size_t ws_size,
                              hipStream_t stream) {
  const float* x       = (const float*)d_in[0];
  const float* gamma   = (const float*)d_in[1];
  const float* ln_w    = (const float*)d_in[2];
  const float* ln_b    = (const float*)d_in[3];
  const float* qkvv_w  = (const float*)d_in[4];
  const float* ef_w    = (const float*)d_in[5];
  const float* ef_b    = (const float*)d_in[6];
  const float* temp    = (const float*)d_in[7];
  const float* temp2   = (const float*)d_in[8];
  const float* op1_w   = (const float*)d_in[9];
  const float* op1_b   = (const float*)d_in[10];
  const float* op2_w   = (const float*)d_in[11];
  const float* op2_b   = (const float*)d_in[12];
  const float* conv1_w = (const float*)d_in[13];
  const float* bn1_w   = (const float*)d_in[14];
  const float* bn1_b   = (const float*)d_in[15];
  const float* conv2_w = (const float*)d_in[16];
  const float* bn2_w   = (const float*)d_in[17];
  const float* bn2_b   = (const float*)d_in[18];
  const float* conv8_w = (const float*)d_in[19];
  const float* conv8_b = (const float*)d_in[20];

  float* ws = (float*)d_ws;
  const size_t M1 = 1u << 20;
  u16*   askip  = (u16*)ws;                  // bf16 CF (8 MB)
  u16*   apack1 = (u16*)(ws + 8 * M1);
  u16*   apack2 = (u16*)(ws + 10 * M1);
  u16*   xt1    = (u16*)(ws + 16 * M1);
  u16*   xnb    = (u16*)(ws + 18 * M1);      // ln..gemm (ends 20M)
  u16*   xsa_b  = (u16*)(ws + 18 * M1);      // attnsa..opcatm (aliases dead xnb)
  float* Spp    = ws + 19 * M1;              // ca_kv..xca
  float* kvpart = ws + 20 * M1;              // ca_kv..attnsa (1M floats)
  u16*   xca_b  = (u16*)(ws + 22 * M1);
  u16*   cvo    = (u16*)(ws + 22 * M1);
  u16*   qct    = (u16*)(ws + 24 * M1);
  u16*   c1o    = (u16*)(ws + 26 * M1);
  u16*   ht     = (u16*)(ws + 28 * M1);
  u16*   c2o    = (u16*)(ws + 30 * M1);
  float* sm     = ws + 32 * M1;
  float* sbuf   = sm;                        // 2048 (zeroed)
  float* bnacc  = sm + 2048;                 // 1024 (zeroed)
  float* zgu_f  = sm + 3072;                 // 128 (zeroed)
  u16*   zgu    = (u16*)zgu_f;
  u16*   qpack  = (u16*)(sm + 3200);
  u16*   efpack = (u16*)(sm + 3200 + 131072);
  u16*   w8pack = (u16*)(sm + 3200 + 262144);
  u16*   oppack = (u16*)(sm + 3200 + 294912);

  k_pre_ln<<<dim3(1601), 256, 0, stream>>>(x, ln_w, ln_b, qkvv_w, conv8_w, op1_w, op2_w,
                                           ef_w, conv1_w, conv2_w,
                                           xnb, qpack, w8pack, oppack, efpack,
                                           apack1, apack2, sm);
  k_gemm<<<dim3(128, 8), 256, 0, stream>>>(xnb, qpack, qct, sbuf);
  k_ca_kv<<<dim3(384), 256, 0, stream>>>(qct, efpack, kvpart, Spp);
  k_xca<<<dim3(32, 8, 4), 256, 0, stream>>>(qct, Spp, sbuf, temp, xca_b);
  k_attnsa<<<dim3(16, 8, 4), 256, 0, stream>>>(qct, kvpart, ef_b, sbuf, temp2, xsa_b);
  k_opcatm<<<dim3(128, 2), 256, 0, stream>>>(xsa_b, xca_b, x, gamma, oppack, op1_b, op2_b, askip, xt1);
  k_conv3m<<<dim3(512), 256, 0, stream>>>(xt1, apack1, zgu, c1o, bnacc, bnacc + 256);
  k_bnelt<<<dim3(256), 256, 0, stream>>>(c1o, bnacc, bnacc + 256, bn1_w, bn1_b, ht);
  k_conv3m<<<dim3(512), 256, 0, stream>>>(ht, apack2, zgu, c2o, bnacc + 512, bnacc + 768);
  k_bn2fuse<<<dim3(128, 4), 256, 0, stream>>>(c2o, askip, bnacc + 512, bnacc + 768, bn2_w, bn2_b, cvo);
  k_conv8m<<<dim3(128, 2), 256, 0, stream>>>(cvo, w8pack, conv8_b, askip, (float*)d_out);
}